// Round 1
// baseline (1345.903 us; speedup 1.0000x reference)
//
#include <hip/hip_runtime.h>
#include <stdint.h>

#define N_NODES 100000
#define N_EDGES 1200000
#define N_GRAPH 512
#define HID 64

// ---- float ordered-int key for atomicMax on floats ----
__device__ __forceinline__ int fkey(float f) {
    int i = __float_as_int(f);
    return (i >= 0) ? i : (i ^ 0x7FFFFFFF);
}
__device__ __forceinline__ float funkey(int k) {
    return __int_as_float((k >= 0) ? k : (k ^ 0x7FFFFFFF));
}

// ---- init small per-graph buffers ----
__global__ __launch_bounds__(256) void k_init(float* graph, float* den, int* gmaxk) {
    int i = blockIdx.x * 256 + threadIdx.x;
    if (i < N_GRAPH * HID) graph[i] = 0.f;
    if (i < N_GRAPH) { den[i] = 0.f; gmaxk[i] = (int)0x80000000; }
}

// ---- precompute: per-table projected node-emb rows; per-layer edge-lin tables ----
// ptab[144][64]: table t row r projected through proj_w columns.
// elin[3][16][64]: lin_e(eemb[hash]) + bias.
__global__ __launch_bounds__(256) void k_pre(
    const float* emb0, const float* emb1, const float* emb2, const float* emb3, const float* emb4,
    const float* proj_w,
    const float* ee1, const float* lw1, const float* lb1,
    const float* ee2, const float* lw2, const float* lb2,
    const float* ee3, const float* lw3, const float* lb3,
    float* ptab, float* elin)
{
    int job = blockIdx.x * 256 + threadIdx.x;
    if (job < 144 * 64) {
        int row = job >> 6, c = job & 63;
        const float* emb; int lr, dim, off;
        if (row < 120)      { emb = emb0; lr = row;       dim = 64; off = 0;  }
        else if (row < 130) { emb = emb1; lr = row - 120; dim = 16; off = 64; }
        else if (row < 137) { emb = emb2; lr = row - 130; dim = 8;  off = 80; }
        else if (row < 142) { emb = emb3; lr = row - 137; dim = 8;  off = 88; }
        else                { emb = emb4; lr = row - 142; dim = 4;  off = 96; }
        float s = 0.f;
        for (int d = 0; d < dim; ++d)
            s += emb[lr * dim + d] * proj_w[c * 100 + off + d];
        ptab[row * 64 + c] = s;
    } else if (job < 144 * 64 + 3 * 1024) {
        int j = job - 144 * 64;
        int L = j >> 10; int r = (j >> 6) & 15; int c = j & 63;
        const float* ee = (L == 0) ? ee1 : (L == 1) ? ee2 : ee3;
        const float* lw = (L == 0) ? lw1 : (L == 1) ? lw2 : lw3;
        const float* lb = (L == 0) ? lb1 : (L == 1) ? lb2 : lb3;
        float s = lb[c];
        for (int d = 0; d < 8; ++d) s += ee[r * 8 + d] * lw[c * 8 + d];
        elin[j] = s;
    }
}

// ---- node embedding + projection: h[n][c] = proj_b[c] + sum_t ptab[row_t][c] ----
__global__ __launch_bounds__(256) void k_embed(const int* x, const float* ptab,
                                               const float* proj_b, float* h) {
    int id = blockIdx.x * 256 + threadIdx.x;
    if (id >= N_NODES * HID) return;
    int n = id >> 6, c = id & 63;
    const int* xr = x + n * 5;
    int r0 = min(max(xr[0], 0), 119);
    int r1 = 120 + min(max(xr[1], 0), 9);
    int r2 = 130 + min(max(xr[2], 0), 6);
    int r3 = 137 + min(max(xr[3], 0), 4);
    int r4 = 142 + min(max(xr[4], 0), 1);
    h[id] = proj_b[c] + ptab[r0 * 64 + c] + ptab[r1 * 64 + c] + ptab[r2 * 64 + c]
          + ptab[r3 * 64 + c] + ptab[r4 * 64 + c];
}

// ---- CSR build: degree histogram, 2-level exclusive scan, scatter packed edges ----
__global__ __launch_bounds__(256) void k_deg(const int* ei, int* deg) {
    int e = blockIdx.x * 256 + threadIdx.x;
    if (e < N_EDGES) atomicAdd(&deg[ei[N_EDGES + e]], 1);
}

__global__ __launch_bounds__(1024) void k_scan1(const int* deg, int* rowptr, int* bsum) {
    __shared__ int s[1024];
    int t = threadIdx.x, b = blockIdx.x;
    int i = b * 1024 + t;
    int v = (i < N_NODES) ? deg[i] : 0;
    s[t] = v;
    __syncthreads();
    for (int off = 1; off < 1024; off <<= 1) {
        int xv = (t >= off) ? s[t - off] : 0;
        __syncthreads();
        s[t] += xv;
        __syncthreads();
    }
    if (i < N_NODES) rowptr[i] = s[t] - v;   // exclusive within block
    if (t == 1023) bsum[b] = s[1023];
}

__global__ __launch_bounds__(128) void k_scan2(const int* bsum, int* bofs, int* rowptr, int nb) {
    __shared__ int s[128];
    int t = threadIdx.x;
    int v = (t < nb) ? bsum[t] : 0;
    s[t] = v;
    __syncthreads();
    for (int off = 1; off < 128; off <<= 1) {
        int xv = (t >= off) ? s[t - off] : 0;
        __syncthreads();
        s[t] += xv;
        __syncthreads();
    }
    bofs[t] = s[t] - v;
    if (t == 0) rowptr[N_NODES] = N_EDGES;
}

__global__ __launch_bounds__(256) void k_scan3(int* rowptr, const int* bofs) {
    int i = blockIdx.x * 256 + threadIdx.x;
    if (i < N_NODES) rowptr[i] += bofs[i >> 10];
}

__global__ __launch_bounds__(256) void k_csr(const int* ei, const int* ea,
                                             const int* rowptr, int* cursor, int* epk) {
    int e = blockIdx.x * 256 + threadIdx.x;
    if (e >= N_EDGES) return;
    int s = ei[e];
    int d = ei[N_EDGES + e];
    int a0 = ea[e * 3], a1 = ea[e * 3 + 1], a2 = ea[e * 3 + 2];
    int hsh = (a0 + 3 * a1 + 7 * a2) & 15;
    int pos = rowptr[d] + atomicAdd(&cursor[d], 1);
    epk[pos] = s | (hsh << 20);     // src in [0,100000) < 2^20
}

// ---- GINE aggregation, atomic-free gather: agg[n][c] = sum_in relu(h[src][c]+elin[hash][c])
__global__ __launch_bounds__(256) void k_gather(const float* __restrict__ h,
                                                const float* __restrict__ elinL,
                                                const int* __restrict__ rowptr,
                                                const int* __restrict__ epk,
                                                float* __restrict__ agg) {
    __shared__ float es[16 * 64];
    int t = threadIdx.x;
    ((float4*)es)[t] = ((const float4*)elinL)[t];   // 256 * float4 = 1024 floats
    __syncthreads();
    int n = blockIdx.x * 4 + (t >> 6);
    int c = t & 63;
    if (n >= N_NODES) return;
    int p0 = rowptr[n], p1 = rowptr[n + 1];
    float acc = 0.f;
    for (int p = p0; p < p1; ++p) {
        int pk = epk[p];
        float v = h[(pk & 0xFFFFF) * 64 + c] + es[(pk >> 20) * 64 + c];
        acc += fmaxf(v, 0.f);
    }
    agg[n * 64 + c] = acc;
}

// ---- fused MLP linear (+optional z=(1+eps)*in1+in2 input fuse) + relu ----
// out[r][c] = relu(bias[c] + sum_k z[r][k]*W[c][k]); 64-row tile per block.
__global__ __launch_bounds__(256) void k_mlp(const float* __restrict__ in1,
                                             const float* __restrict__ in2,
                                             const float* __restrict__ epsp,
                                             const float* __restrict__ W,
                                             const float* __restrict__ bias,
                                             float* __restrict__ out) {
    __shared__ float in_s[64 * 68];
    __shared__ float wt_s[64 * 68];
    int t = threadIdx.x;
    int row0 = blockIdx.x * 64;
    float epsv = 1.f;
    if (in2) epsv = 1.f + epsp[0];
    for (int idx = t; idx < 64 * 16; idx += 256) {
        int r = idx >> 4, c4 = (idx & 15) << 2;
        int gr = row0 + r;
        float4 v = make_float4(0.f, 0.f, 0.f, 0.f);
        if (gr < N_NODES) {
            v = *(const float4*)(in1 + gr * 64 + c4);
            if (in2) {
                float4 v2 = *(const float4*)(in2 + gr * 64 + c4);
                v.x = epsv * v.x + v2.x; v.y = epsv * v.y + v2.y;
                v.z = epsv * v.z + v2.z; v.w = epsv * v.w + v2.w;
            }
        }
        *(float4*)(in_s + r * 68 + c4) = v;
    }
    for (int idx = t; idx < 1024; idx += 256) {
        int c = idx >> 4, k4 = (idx & 15) << 2;
        float4 w = *(const float4*)(W + c * 64 + k4);
        wt_s[(k4 + 0) * 68 + c] = w.x;
        wt_s[(k4 + 1) * 68 + c] = w.y;
        wt_s[(k4 + 2) * 68 + c] = w.z;
        wt_s[(k4 + 3) * 68 + c] = w.w;
    }
    __syncthreads();
    int tc = t & 15, tr = t >> 4;       // cols tc*4..+3, rows tr+16*i
    float acc[4][4] = {};
    for (int k4 = 0; k4 < 16; ++k4) {
        float4 a[4], b[4];
        #pragma unroll
        for (int i = 0; i < 4; ++i) a[i] = *(float4*)(in_s + (tr + 16 * i) * 68 + k4 * 4);
        #pragma unroll
        for (int kk = 0; kk < 4; ++kk) b[kk] = *(float4*)(wt_s + (k4 * 4 + kk) * 68 + tc * 4);
        #pragma unroll
        for (int i = 0; i < 4; ++i) {
            float ax = a[i].x, ay = a[i].y, az = a[i].z, aw = a[i].w;
            acc[i][0] += ax * b[0].x + ay * b[1].x + az * b[2].x + aw * b[3].x;
            acc[i][1] += ax * b[0].y + ay * b[1].y + az * b[2].y + aw * b[3].y;
            acc[i][2] += ax * b[0].z + ay * b[1].z + az * b[2].z + aw * b[3].z;
            acc[i][3] += ax * b[0].w + ay * b[1].w + az * b[2].w + aw * b[3].w;
        }
    }
    float4 bb = *(const float4*)(bias + tc * 4);
    #pragma unroll
    for (int i = 0; i < 4; ++i) {
        int gr = row0 + tr + 16 * i;
        if (gr < N_NODES) {
            float4 o;
            o.x = fmaxf(acc[i][0] + bb.x, 0.f);
            o.y = fmaxf(acc[i][1] + bb.y, 0.f);
            o.z = fmaxf(acc[i][2] + bb.z, 0.f);
            o.w = fmaxf(acc[i][3] + bb.w, 0.f);
            *(float4*)(out + gr * 64 + tc * 4) = o;
        }
    }
}

// ---- BN (eval) + gate dot + segment max (ordered-int atomicMax) ----
__global__ __launch_bounds__(256) void k_gate(float* h, const float* bn_g, const float* bn_b,
                                              const float* bn_rm, const float* bn_rv,
                                              const float* gate_w, const float* gate_b,
                                              const int* batch, float* gate, int* gmaxk) {
    int id = blockIdx.x * 256 + threadIdx.x;
    int n = id >> 6, c = id & 63;
    if (n >= N_NODES) return;
    float scale = bn_g[c] / sqrtf(bn_rv[c] + 1e-5f);
    float shift = bn_b[c] - bn_rm[c] * scale;
    float v = h[id] * scale + shift;
    h[id] = v;                      // overwrite with normalized value
    float p = v * gate_w[c];
    #pragma unroll
    for (int off = 32; off > 0; off >>= 1) p += __shfl_down(p, off, 64);
    if (c == 0) {
        float g = p + gate_b[0];
        gate[n] = g;
        atomicMax(&gmaxk[batch[n]], fkey(g));
    }
}

__global__ __launch_bounds__(256) void k_expw(const float* gate, const int* batch,
                                              const int* gmaxk, float* wexp, float* den) {
    int n = blockIdx.x * 256 + threadIdx.x;
    if (n >= N_NODES) return;
    int g = batch[n];
    float w = expf(gate[n] - funkey(gmaxk[g]));
    wexp[n] = w;
    atomicAdd(&den[g], w);
}

__global__ __launch_bounds__(256) void k_aggr(const float* h, const float* wexp,
                                              const float* den, const int* batch, float* graph) {
    int id = blockIdx.x * 256 + threadIdx.x;
    if (id >= N_NODES * HID) return;
    int n = id >> 6, c = id & 63;
    int g = batch[n];
    float alpha = wexp[n] / (den[g] + 1e-16f);
    atomicAdd(&graph[g * 64 + c], alpha * h[id]);
}

// ---- readout head: per-graph block, hidden=128 ----
__global__ __launch_bounds__(128) void k_head(const float* graph, const float* w1, const float* b1,
                                              const float* w2, const float* b2, float* out) {
    __shared__ float w1s[128 * 65];
    __shared__ float gs[64];
    __shared__ float red[2];
    int t = threadIdx.x, g = blockIdx.x;
    for (int idx = t; idx < 128 * 16; idx += 128) {
        int r = idx >> 4, c4 = (idx & 15) << 2;
        float4 v = *(const float4*)(w1 + r * 64 + c4);
        w1s[r * 65 + c4 + 0] = v.x;
        w1s[r * 65 + c4 + 1] = v.y;
        w1s[r * 65 + c4 + 2] = v.z;
        w1s[r * 65 + c4 + 3] = v.w;
    }
    if (t < 64) gs[t] = graph[g * 64 + t];
    __syncthreads();
    float s = b1[t];
    #pragma unroll
    for (int k = 0; k < 64; ++k) s += gs[k] * w1s[t * 65 + k];
    float p = fmaxf(s, 0.f) * w2[t];
    #pragma unroll
    for (int off = 32; off > 0; off >>= 1) p += __shfl_down(p, off, 64);
    if ((t & 63) == 0) red[t >> 6] = p;
    __syncthreads();
    if (t == 0) out[g] = red[0] + red[1] + b2[0];
}

extern "C" void kernel_launch(void* const* d_in, const int* in_sizes, int n_in,
                              void* d_out, int out_size, void* d_ws, size_t ws_size,
                              hipStream_t stream) {
    const int* x    = (const int*)d_in[0];
    const int* ei   = (const int*)d_in[1];
    const int* ea   = (const int*)d_in[2];
    const int* bat  = (const int*)d_in[3];
    const float* emb0 = (const float*)d_in[4];
    const float* emb1 = (const float*)d_in[5];
    const float* emb2 = (const float*)d_in[6];
    const float* emb3 = (const float*)d_in[7];
    const float* emb4 = (const float*)d_in[8];
    const float* proj_w = (const float*)d_in[9];
    const float* proj_b = (const float*)d_in[10];
    const float* bn_g  = (const float*)d_in[35];
    const float* bn_b  = (const float*)d_in[36];
    const float* bn_rm = (const float*)d_in[37];
    const float* bn_rv = (const float*)d_in[38];
    const float* gate_w = (const float*)d_in[39];
    const float* gate_b = (const float*)d_in[40];
    const float* head_w1 = (const float*)d_in[41];
    const float* head_b1 = (const float*)d_in[42];
    const float* head_w2 = (const float*)d_in[43];
    const float* head_b2 = (const float*)d_in[44];

    char* wsb = (char*)d_ws;
    size_t o = 0;
    auto alloc = [&](size_t bytes) -> void* {
        void* p = wsb + o;
        o += (bytes + 255) & ~(size_t)255;
        return p;
    };
    float* ptab  = (float*)alloc(144 * 64 * 4);
    float* elin  = (float*)alloc(3 * 16 * 64 * 4);
    int* deg     = (int*)alloc((size_t)N_NODES * 4);
    int* rowptr  = (int*)alloc(((size_t)N_NODES + 1) * 4);
    int* cursor  = (int*)alloc((size_t)N_NODES * 4);
    int* bsum    = (int*)alloc(128 * 4);
    int* bofs    = (int*)alloc(128 * 4);
    int* epk     = (int*)alloc((size_t)N_EDGES * 4);
    float* h     = (float*)alloc((size_t)N_NODES * 64 * 4);
    float* agg   = (float*)alloc((size_t)N_NODES * 64 * 4);
    float* gate  = (float*)alloc((size_t)N_NODES * 4);
    float* wexp  = (float*)alloc((size_t)N_NODES * 4);
    int* gmaxk   = (int*)alloc(N_GRAPH * 4);
    float* den   = (float*)alloc(N_GRAPH * 4);
    float* graph = (float*)alloc((size_t)N_GRAPH * 64 * 4);

    hipMemsetAsync(deg, 0, (size_t)N_NODES * 4, stream);
    hipMemsetAsync(cursor, 0, (size_t)N_NODES * 4, stream);
    k_init<<<(N_GRAPH * 64 + 255) / 256, 256, 0, stream>>>(graph, den, gmaxk);
    k_pre<<<48, 256, 0, stream>>>(emb0, emb1, emb2, emb3, emb4, proj_w,
                                  (const float*)d_in[11], (const float*)d_in[12], (const float*)d_in[13],
                                  (const float*)d_in[19], (const float*)d_in[20], (const float*)d_in[21],
                                  (const float*)d_in[27], (const float*)d_in[28], (const float*)d_in[29],
                                  ptab, elin);
    k_embed<<<(N_NODES * 64 + 255) / 256, 256, 0, stream>>>(x, ptab, proj_b, h);
    k_deg<<<(N_EDGES + 255) / 256, 256, 0, stream>>>(ei, deg);
    k_scan1<<<98, 1024, 0, stream>>>(deg, rowptr, bsum);
    k_scan2<<<1, 128, 0, stream>>>(bsum, bofs, rowptr, 98);
    k_scan3<<<(N_NODES + 255) / 256, 256, 0, stream>>>(rowptr, bofs);
    k_csr<<<(N_EDGES + 255) / 256, 256, 0, stream>>>(ei, ea, rowptr, cursor, epk);

    for (int L = 0; L < 3; ++L) {
        const float* epsp = (const float*)d_in[14 + L * 8];
        const float* w1   = (const float*)d_in[15 + L * 8];
        const float* b1   = (const float*)d_in[16 + L * 8];
        const float* w2   = (const float*)d_in[17 + L * 8];
        const float* b2   = (const float*)d_in[18 + L * 8];
        k_gather<<<(N_NODES + 3) / 4, 256, 0, stream>>>(h, elin + L * 1024, rowptr, epk, agg);
        // z = (1+eps)*h + agg; hidden = relu(z @ w1^T + b1)  (in-place into agg)
        k_mlp<<<(N_NODES + 63) / 64, 256, 0, stream>>>(h, agg, epsp, w1, b1, agg);
        // h = relu(hidden @ w2^T + b2)   (outer relu fused)
        k_mlp<<<(N_NODES + 63) / 64, 256, 0, stream>>>(agg, nullptr, nullptr, w2, b2, h);
    }

    k_gate<<<(N_NODES * 64 + 255) / 256, 256, 0, stream>>>(h, bn_g, bn_b, bn_rm, bn_rv,
                                                           gate_w, gate_b, bat, gate, gmaxk);
    k_expw<<<(N_NODES + 255) / 256, 256, 0, stream>>>(gate, bat, gmaxk, wexp, den);
    k_aggr<<<(N_NODES * 64 + 255) / 256, 256, 0, stream>>>(h, wexp, den, bat, graph);
    k_head<<<N_GRAPH, 128, 0, stream>>>(graph, head_w1, head_b1, head_w2, head_b2, (float*)d_out);
}

// Round 2
// 1053.122 us; speedup vs baseline: 1.2780x; 1.2780x over previous
//
#include <hip/hip_runtime.h>
#include <stdint.h>

#define N_NODES 100000
#define N_EDGES 1200000
#define N_GRAPH 512
#define HID 64

// ---- precompute: per-table projected node-emb rows; per-layer edge-lin tables;
//      folded BN scale/shift ----
// ptab[144][64]: table t row r projected through proj_w columns.
// elin[3][16][64]: lin_e(eemb[hash]) + bias.
// bnsc/bnsh[64]: y = x*bnsc + bnsh  (BatchNorm eval folded)
__global__ __launch_bounds__(256) void k_pre(
    const float* emb0, const float* emb1, const float* emb2, const float* emb3, const float* emb4,
    const float* proj_w,
    const float* ee1, const float* lw1, const float* lb1,
    const float* ee2, const float* lw2, const float* lb2,
    const float* ee3, const float* lw3, const float* lb3,
    const float* bn_g, const float* bn_b, const float* bn_rm, const float* bn_rv,
    float* ptab, float* elin, float* bnsc, float* bnsh)
{
    int job = blockIdx.x * 256 + threadIdx.x;
    if (job < 144 * 64) {
        int row = job >> 6, c = job & 63;
        const float* emb; int lr, dim, off;
        if (row < 120)      { emb = emb0; lr = row;       dim = 64; off = 0;  }
        else if (row < 130) { emb = emb1; lr = row - 120; dim = 16; off = 64; }
        else if (row < 137) { emb = emb2; lr = row - 130; dim = 8;  off = 80; }
        else if (row < 142) { emb = emb3; lr = row - 137; dim = 8;  off = 88; }
        else                { emb = emb4; lr = row - 142; dim = 4;  off = 96; }
        float s = 0.f;
        for (int d = 0; d < dim; ++d)
            s += emb[lr * dim + d] * proj_w[c * 100 + off + d];
        ptab[row * 64 + c] = s;
    } else if (job < 144 * 64 + 3 * 1024) {
        int j = job - 144 * 64;
        int L = j >> 10; int r = (j >> 6) & 15; int c = j & 63;
        const float* ee = (L == 0) ? ee1 : (L == 1) ? ee2 : ee3;
        const float* lw = (L == 0) ? lw1 : (L == 1) ? lw2 : lw3;
        const float* lb = (L == 0) ? lb1 : (L == 1) ? lb2 : lb3;
        float s = lb[c];
        for (int d = 0; d < 8; ++d) s += ee[r * 8 + d] * lw[c * 8 + d];
        elin[j] = s;
    } else if (job < 144 * 64 + 3 * 1024 + 64) {
        int c = job - (144 * 64 + 3 * 1024);
        float sc = bn_g[c] * rsqrtf(bn_rv[c] + 1e-5f);
        bnsc[c] = sc;
        bnsh[c] = bn_b[c] - bn_rm[c] * sc;
    }
}

// ---- node embedding + projection: h[n][c] = proj_b[c] + sum_t ptab[row_t][c] ----
__global__ __launch_bounds__(256) void k_embed(const int* x, const float* ptab,
                                               const float* proj_b, float* h) {
    int id = blockIdx.x * 256 + threadIdx.x;
    if (id >= N_NODES * HID) return;
    int n = id >> 6, c = id & 63;
    const int* xr = x + n * 5;
    int r0 = min(max(xr[0], 0), 119);
    int r1 = 120 + min(max(xr[1], 0), 9);
    int r2 = 130 + min(max(xr[2], 0), 6);
    int r3 = 137 + min(max(xr[3], 0), 4);
    int r4 = 142 + min(max(xr[4], 0), 1);
    h[id] = proj_b[c] + ptab[r0 * 64 + c] + ptab[r1 * 64 + c] + ptab[r2 * 64 + c]
          + ptab[r3 * 64 + c] + ptab[r4 * 64 + c];
}

// ---- CSR build: degree histogram, 2-level exclusive scan, scatter packed edges ----
__global__ __launch_bounds__(256) void k_deg(const int* ei, int* deg) {
    int e = blockIdx.x * 256 + threadIdx.x;
    if (e < N_EDGES) atomicAdd(&deg[ei[N_EDGES + e]], 1);
}

__global__ __launch_bounds__(1024) void k_scan1(const int* deg, int* rowptr, int* bsum) {
    __shared__ int s[1024];
    int t = threadIdx.x, b = blockIdx.x;
    int i = b * 1024 + t;
    int v = (i < N_NODES) ? deg[i] : 0;
    s[t] = v;
    __syncthreads();
    for (int off = 1; off < 1024; off <<= 1) {
        int xv = (t >= off) ? s[t - off] : 0;
        __syncthreads();
        s[t] += xv;
        __syncthreads();
    }
    if (i < N_NODES) rowptr[i] = s[t] - v;   // exclusive within block
    if (t == 1023) bsum[b] = s[1023];
}

__global__ __launch_bounds__(128) void k_scan2(const int* bsum, int* bofs, int* rowptr, int nb) {
    __shared__ int s[128];
    int t = threadIdx.x;
    int v = (t < nb) ? bsum[t] : 0;
    s[t] = v;
    __syncthreads();
    for (int off = 1; off < 128; off <<= 1) {
        int xv = (t >= off) ? s[t - off] : 0;
        __syncthreads();
        s[t] += xv;
        __syncthreads();
    }
    bofs[t] = s[t] - v;
    if (t == 0) rowptr[N_NODES] = N_EDGES;
}

__global__ __launch_bounds__(256) void k_scan3(int* rowptr, const int* bofs) {
    int i = blockIdx.x * 256 + threadIdx.x;
    if (i < N_NODES) rowptr[i] += bofs[i >> 10];
}

__global__ __launch_bounds__(256) void k_csr(const int* ei, const int* ea,
                                             const int* rowptr, int* cursor, int* epk) {
    int e = blockIdx.x * 256 + threadIdx.x;
    if (e >= N_EDGES) return;
    int s = ei[e];
    int d = ei[N_EDGES + e];
    int a0 = ea[e * 3], a1 = ea[e * 3 + 1], a2 = ea[e * 3 + 2];
    int hsh = (a0 + 3 * a1 + 7 * a2) & 15;
    int pos = rowptr[d] + atomicAdd(&cursor[d], 1);
    epk[pos] = s | (hsh << 20);     // src in [0,100000) < 2^20
}

// ---- graph boundaries from sorted batch: gptr[g] = first n with batch[n] >= g ----
__global__ __launch_bounds__(256) void k_gptr(const int* batch, int* gptr) {
    int n = blockIdx.x * 256 + threadIdx.x;
    if (n >= N_NODES) return;
    int b = batch[n];
    int bp = (n == 0) ? -1 : batch[n - 1];
    for (int g = bp + 1; g <= b; ++g) gptr[g] = n;
    if (n == N_NODES - 1) {
        for (int g = b + 1; g <= N_GRAPH; ++g) gptr[g] = N_NODES;
    }
}

// ---- GINE aggregation, atomic-free gather: agg[n][c] = sum_in relu(h[src][c]+elin[hash][c])
__global__ __launch_bounds__(256) void k_gather(const float* __restrict__ h,
                                                const float* __restrict__ elinL,
                                                const int* __restrict__ rowptr,
                                                const int* __restrict__ epk,
                                                float* __restrict__ agg) {
    __shared__ float es[16 * 64];
    int t = threadIdx.x;
    ((float4*)es)[t] = ((const float4*)elinL)[t];   // 256 * float4 = 1024 floats
    __syncthreads();
    int n = blockIdx.x * 4 + (t >> 6);
    int c = t & 63;
    if (n >= N_NODES) return;
    int p0 = rowptr[n], p1 = rowptr[n + 1];
    float acc = 0.f;
    for (int p = p0; p < p1; ++p) {
        int pk = epk[p];
        float v = h[(pk & 0xFFFFF) * 64 + c] + es[(pk >> 20) * 64 + c];
        acc += fmaxf(v, 0.f);
    }
    agg[n * 64 + c] = acc;
}

// ---- fused MLP linear (+optional z=(1+eps)*in1+in2 input fuse) + relu ----
// out[r][c] = relu(bias[c] + sum_k z[r][k]*W[c][k]); 64-row tile per block.
__global__ __launch_bounds__(256) void k_mlp(const float* __restrict__ in1,
                                             const float* __restrict__ in2,
                                             const float* __restrict__ epsp,
                                             const float* __restrict__ W,
                                             const float* __restrict__ bias,
                                             float* __restrict__ out) {
    __shared__ float in_s[64 * 68];
    __shared__ float wt_s[64 * 68];
    int t = threadIdx.x;
    int row0 = blockIdx.x * 64;
    float epsv = 1.f;
    if (in2) epsv = 1.f + epsp[0];
    for (int idx = t; idx < 64 * 16; idx += 256) {
        int r = idx >> 4, c4 = (idx & 15) << 2;
        int gr = row0 + r;
        float4 v = make_float4(0.f, 0.f, 0.f, 0.f);
        if (gr < N_NODES) {
            v = *(const float4*)(in1 + gr * 64 + c4);
            if (in2) {
                float4 v2 = *(const float4*)(in2 + gr * 64 + c4);
                v.x = epsv * v.x + v2.x; v.y = epsv * v.y + v2.y;
                v.z = epsv * v.z + v2.z; v.w = epsv * v.w + v2.w;
            }
        }
        *(float4*)(in_s + r * 68 + c4) = v;
    }
    for (int idx = t; idx < 1024; idx += 256) {
        int c = idx >> 4, k4 = (idx & 15) << 2;
        float4 w = *(const float4*)(W + c * 64 + k4);
        wt_s[(k4 + 0) * 68 + c] = w.x;
        wt_s[(k4 + 1) * 68 + c] = w.y;
        wt_s[(k4 + 2) * 68 + c] = w.z;
        wt_s[(k4 + 3) * 68 + c] = w.w;
    }
    __syncthreads();
    int tc = t & 15, tr = t >> 4;       // cols tc*4..+3, rows tr+16*i
    float acc[4][4] = {};
    for (int k4 = 0; k4 < 16; ++k4) {
        float4 a[4], b[4];
        #pragma unroll
        for (int i = 0; i < 4; ++i) a[i] = *(float4*)(in_s + (tr + 16 * i) * 68 + k4 * 4);
        #pragma unroll
        for (int kk = 0; kk < 4; ++kk) b[kk] = *(float4*)(wt_s + (k4 * 4 + kk) * 68 + tc * 4);
        #pragma unroll
        for (int i = 0; i < 4; ++i) {
            float ax = a[i].x, ay = a[i].y, az = a[i].z, aw = a[i].w;
            acc[i][0] += ax * b[0].x + ay * b[1].x + az * b[2].x + aw * b[3].x;
            acc[i][1] += ax * b[0].y + ay * b[1].y + az * b[2].y + aw * b[3].y;
            acc[i][2] += ax * b[0].z + ay * b[1].z + az * b[2].z + aw * b[3].z;
            acc[i][3] += ax * b[0].w + ay * b[1].w + az * b[2].w + aw * b[3].w;
        }
    }
    float4 bb = *(const float4*)(bias + tc * 4);
    #pragma unroll
    for (int i = 0; i < 4; ++i) {
        int gr = row0 + tr + 16 * i;
        if (gr < N_NODES) {
            float4 o;
            o.x = fmaxf(acc[i][0] + bb.x, 0.f);
            o.y = fmaxf(acc[i][1] + bb.y, 0.f);
            o.z = fmaxf(acc[i][2] + bb.z, 0.f);
            o.w = fmaxf(acc[i][3] + bb.w, 0.f);
            *(float4*)(out + gr * 64 + tc * 4) = o;
        }
    }
}

// ---- BN (folded) + gate dot, NO atomics: writes normalized h and gate[n] ----
__global__ __launch_bounds__(256) void k_bngate(float* __restrict__ h,
                                                const float* __restrict__ bnsc,
                                                const float* __restrict__ bnsh,
                                                const float* __restrict__ gate_w,
                                                const float* __restrict__ gate_b,
                                                float* __restrict__ gate) {
    int id = blockIdx.x * 256 + threadIdx.x;
    if (id >= N_NODES * HID) return;
    int n = id >> 6, c = id & 63;
    float v = h[id] * bnsc[c] + bnsh[c];
    h[id] = v;
    float p = v * gate_w[c];
    #pragma unroll
    for (int off = 32; off > 0; off >>= 1) p += __shfl_down(p, off, 64);
    if (c == 0) gate[n] = p + gate_b[0];
}

// ---- attention aggregation: one block per graph, atomic-free ----
__global__ __launch_bounds__(256) void k_att(const float* __restrict__ h,
                                             const float* __restrict__ gate,
                                             const int* __restrict__ gptr,
                                             float* __restrict__ graph) {
    __shared__ float red[4];
    __shared__ float acc_s[4][64];
    __shared__ float m_s, den_s;
    int t = threadIdx.x, g = blockIdx.x;
    int n0 = gptr[g], n1 = gptr[g + 1];
    // phase 1: segment max of gate
    float m = -INFINITY;
    for (int n = n0 + t; n < n1; n += 256) m = fmaxf(m, gate[n]);
    #pragma unroll
    for (int off = 32; off > 0; off >>= 1) m = fmaxf(m, __shfl_down(m, off, 64));
    if ((t & 63) == 0) red[t >> 6] = m;
    __syncthreads();
    if (t == 0) m_s = fmaxf(fmaxf(red[0], red[1]), fmaxf(red[2], red[3]));
    __syncthreads();
    m = m_s;
    // phase 2: sum of exp
    float s = 0.f;
    for (int n = n0 + t; n < n1; n += 256) s += expf(gate[n] - m);
    #pragma unroll
    for (int off = 32; off > 0; off >>= 1) s += __shfl_down(s, off, 64);
    if ((t & 63) == 0) red[t >> 6] = s;
    __syncthreads();
    if (t == 0) den_s = red[0] + red[1] + red[2] + red[3] + 1e-16f;
    __syncthreads();
    float invden = 1.f / den_s;
    // phase 3: weighted channel sums (wave w handles nodes n0+w, n0+w+4, ...)
    int c = t & 63, w = t >> 6;
    float acc = 0.f;
    for (int n = n0 + w; n < n1; n += 4) {
        float a = expf(gate[n] - m);
        acc += a * h[n * 64 + c];
    }
    acc_s[w][c] = acc;
    __syncthreads();
    if (w == 0)
        graph[g * 64 + c] = (acc_s[0][c] + acc_s[1][c] + acc_s[2][c] + acc_s[3][c]) * invden;
}

// ---- readout head: per-graph block, hidden=128 ----
__global__ __launch_bounds__(128) void k_head(const float* graph, const float* w1, const float* b1,
                                              const float* w2, const float* b2, float* out) {
    __shared__ float w1s[128 * 65];
    __shared__ float gs[64];
    __shared__ float red[2];
    int t = threadIdx.x, g = blockIdx.x;
    for (int idx = t; idx < 128 * 16; idx += 128) {
        int r = idx >> 4, c4 = (idx & 15) << 2;
        float4 v = *(const float4*)(w1 + r * 64 + c4);
        w1s[r * 65 + c4 + 0] = v.x;
        w1s[r * 65 + c4 + 1] = v.y;
        w1s[r * 65 + c4 + 2] = v.z;
        w1s[r * 65 + c4 + 3] = v.w;
    }
    if (t < 64) gs[t] = graph[g * 64 + t];
    __syncthreads();
    float s = b1[t];
    #pragma unroll
    for (int k = 0; k < 64; ++k) s += gs[k] * w1s[t * 65 + k];
    float p = fmaxf(s, 0.f) * w2[t];
    #pragma unroll
    for (int off = 32; off > 0; off >>= 1) p += __shfl_down(p, off, 64);
    if ((t & 63) == 0) red[t >> 6] = p;
    __syncthreads();
    if (t == 0) out[g] = red[0] + red[1] + b2[0];
}

extern "C" void kernel_launch(void* const* d_in, const int* in_sizes, int n_in,
                              void* d_out, int out_size, void* d_ws, size_t ws_size,
                              hipStream_t stream) {
    const int* x    = (const int*)d_in[0];
    const int* ei   = (const int*)d_in[1];
    const int* ea   = (const int*)d_in[2];
    const int* bat  = (const int*)d_in[3];
    const float* emb0 = (const float*)d_in[4];
    const float* emb1 = (const float*)d_in[5];
    const float* emb2 = (const float*)d_in[6];
    const float* emb3 = (const float*)d_in[7];
    const float* emb4 = (const float*)d_in[8];
    const float* proj_w = (const float*)d_in[9];
    const float* proj_b = (const float*)d_in[10];
    const float* bn_g  = (const float*)d_in[35];
    const float* bn_b  = (const float*)d_in[36];
    const float* bn_rm = (const float*)d_in[37];
    const float* bn_rv = (const float*)d_in[38];
    const float* gate_w = (const float*)d_in[39];
    const float* gate_b = (const float*)d_in[40];
    const float* head_w1 = (const float*)d_in[41];
    const float* head_b1 = (const float*)d_in[42];
    const float* head_w2 = (const float*)d_in[43];
    const float* head_b2 = (const float*)d_in[44];

    char* wsb = (char*)d_ws;
    size_t o = 0;
    auto alloc = [&](size_t bytes) -> void* {
        void* p = wsb + o;
        o += (bytes + 255) & ~(size_t)255;
        return p;
    };
    float* ptab  = (float*)alloc(144 * 64 * 4);
    float* elin  = (float*)alloc(3 * 16 * 64 * 4);
    float* bnsc  = (float*)alloc(64 * 4);
    float* bnsh  = (float*)alloc(64 * 4);
    int* deg     = (int*)alloc((size_t)N_NODES * 4);
    int* rowptr  = (int*)alloc(((size_t)N_NODES + 1) * 4);
    int* cursor  = (int*)alloc((size_t)N_NODES * 4);
    int* bsum    = (int*)alloc(128 * 4);
    int* bofs    = (int*)alloc(128 * 4);
    int* gptr    = (int*)alloc((N_GRAPH + 1) * 4);
    int* epk     = (int*)alloc((size_t)N_EDGES * 4);
    float* h     = (float*)alloc((size_t)N_NODES * 64 * 4);
    float* agg   = (float*)alloc((size_t)N_NODES * 64 * 4);
    float* gate  = (float*)alloc((size_t)N_NODES * 4);
    float* graph = (float*)alloc((size_t)N_GRAPH * 64 * 4);

    hipMemsetAsync(deg, 0, (size_t)N_NODES * 4, stream);
    hipMemsetAsync(cursor, 0, (size_t)N_NODES * 4, stream);
    k_pre<<<49, 256, 0, stream>>>(emb0, emb1, emb2, emb3, emb4, proj_w,
                                  (const float*)d_in[11], (const float*)d_in[12], (const float*)d_in[13],
                                  (const float*)d_in[19], (const float*)d_in[20], (const float*)d_in[21],
                                  (const float*)d_in[27], (const float*)d_in[28], (const float*)d_in[29],
                                  bn_g, bn_b, bn_rm, bn_rv,
                                  ptab, elin, bnsc, bnsh);
    k_embed<<<(N_NODES * 64 + 255) / 256, 256, 0, stream>>>(x, ptab, proj_b, h);
    k_deg<<<(N_EDGES + 255) / 256, 256, 0, stream>>>(ei, deg);
    k_gptr<<<(N_NODES + 255) / 256, 256, 0, stream>>>(bat, gptr);
    k_scan1<<<98, 1024, 0, stream>>>(deg, rowptr, bsum);
    k_scan2<<<1, 128, 0, stream>>>(bsum, bofs, rowptr, 98);
    k_scan3<<<(N_NODES + 255) / 256, 256, 0, stream>>>(rowptr, bofs);
    k_csr<<<(N_EDGES + 255) / 256, 256, 0, stream>>>(ei, ea, rowptr, cursor, epk);

    for (int L = 0; L < 3; ++L) {
        const float* epsp = (const float*)d_in[14 + L * 8];
        const float* w1   = (const float*)d_in[15 + L * 8];
        const float* b1   = (const float*)d_in[16 + L * 8];
        const float* w2   = (const float*)d_in[17 + L * 8];
        const float* b2   = (const float*)d_in[18 + L * 8];
        k_gather<<<(N_NODES + 3) / 4, 256, 0, stream>>>(h, elin + L * 1024, rowptr, epk, agg);
        // z = (1+eps)*h + agg; hidden = relu(z @ w1^T + b1)  (in-place into agg)
        k_mlp<<<(N_NODES + 63) / 64, 256, 0, stream>>>(h, agg, epsp, w1, b1, agg);
        // h = relu(hidden @ w2^T + b2)   (outer relu fused)
        k_mlp<<<(N_NODES + 63) / 64, 256, 0, stream>>>(agg, nullptr, nullptr, w2, b2, h);
    }

    k_bngate<<<(N_NODES * 64 + 255) / 256, 256, 0, stream>>>(h, bnsc, bnsh, gate_w,
                                                             gate_b, gate);
    k_att<<<N_GRAPH, 256, 0, stream>>>(h, gate, gptr, graph);
    k_head<<<N_GRAPH, 128, 0, stream>>>(graph, head_w1, head_b1, head_w2, head_b2, (float*)d_out);
}

// Round 3
// 591.773 us; speedup vs baseline: 2.2744x; 1.7796x over previous
//
#include <hip/hip_runtime.h>
#include <stdint.h>

#define N_NODES 100000
#define N_EDGES 1200000
#define N_GRAPH 512
#define HID 64

// ---- precompute: per-table projected node-emb rows; per-layer edge-lin tables;
//      folded BN scale/shift ----
__global__ __launch_bounds__(256) void k_pre(
    const float* emb0, const float* emb1, const float* emb2, const float* emb3, const float* emb4,
    const float* proj_w,
    const float* ee1, const float* lw1, const float* lb1,
    const float* ee2, const float* lw2, const float* lb2,
    const float* ee3, const float* lw3, const float* lb3,
    const float* bn_g, const float* bn_b, const float* bn_rm, const float* bn_rv,
    float* ptab, float* elin, float* bnsc, float* bnsh)
{
    int job = blockIdx.x * 256 + threadIdx.x;
    if (job < 144 * 64) {
        int row = job >> 6, c = job & 63;
        const float* emb; int lr, dim, off;
        if (row < 120)      { emb = emb0; lr = row;       dim = 64; off = 0;  }
        else if (row < 130) { emb = emb1; lr = row - 120; dim = 16; off = 64; }
        else if (row < 137) { emb = emb2; lr = row - 130; dim = 8;  off = 80; }
        else if (row < 142) { emb = emb3; lr = row - 137; dim = 8;  off = 88; }
        else                { emb = emb4; lr = row - 142; dim = 4;  off = 96; }
        float s = 0.f;
        for (int d = 0; d < dim; ++d)
            s += emb[lr * dim + d] * proj_w[c * 100 + off + d];
        ptab[row * 64 + c] = s;
    } else if (job < 144 * 64 + 3 * 1024) {
        int j = job - 144 * 64;
        int L = j >> 10; int r = (j >> 6) & 15; int c = j & 63;
        const float* ee = (L == 0) ? ee1 : (L == 1) ? ee2 : ee3;
        const float* lw = (L == 0) ? lw1 : (L == 1) ? lw2 : lw3;
        const float* lb = (L == 0) ? lb1 : (L == 1) ? lb2 : lb3;
        float s = lb[c];
        for (int d = 0; d < 8; ++d) s += ee[r * 8 + d] * lw[c * 8 + d];
        elin[j] = s;
    } else if (job < 144 * 64 + 3 * 1024 + 64) {
        int c = job - (144 * 64 + 3 * 1024);
        float sc = bn_g[c] * rsqrtf(bn_rv[c] + 1e-5f);
        bnsc[c] = sc;
        bnsh[c] = bn_b[c] - bn_rm[c] * sc;
    }
}

// ---- node embedding + projection ----
__global__ __launch_bounds__(256) void k_embed(const int* x, const float* ptab,
                                               const float* proj_b, float* h) {
    int id = blockIdx.x * 256 + threadIdx.x;
    if (id >= N_NODES * HID) return;
    int n = id >> 6, c = id & 63;
    const int* xr = x + n * 5;
    int r0 = min(max(xr[0], 0), 119);
    int r1 = 120 + min(max(xr[1], 0), 9);
    int r2 = 130 + min(max(xr[2], 0), 6);
    int r3 = 137 + min(max(xr[3], 0), 4);
    int r4 = 142 + min(max(xr[4], 0), 1);
    h[id] = proj_b[c] + ptab[r0 * 64 + c] + ptab[r1 * 64 + c] + ptab[r2 * 64 + c]
          + ptab[r3 * 64 + c] + ptab[r4 * 64 + c];
}

// ---- CSR build ----
__global__ __launch_bounds__(256) void k_deg(const int* ei, int* deg) {
    int e = blockIdx.x * 256 + threadIdx.x;
    if (e < N_EDGES) atomicAdd(&deg[ei[N_EDGES + e]], 1);
}

__global__ __launch_bounds__(1024) void k_scan1(const int* deg, int* rowptr, int* bsum) {
    __shared__ int s[1024];
    int t = threadIdx.x, b = blockIdx.x;
    int i = b * 1024 + t;
    int v = (i < N_NODES) ? deg[i] : 0;
    s[t] = v;
    __syncthreads();
    for (int off = 1; off < 1024; off <<= 1) {
        int xv = (t >= off) ? s[t - off] : 0;
        __syncthreads();
        s[t] += xv;
        __syncthreads();
    }
    if (i < N_NODES) rowptr[i] = s[t] - v;
    if (t == 1023) bsum[b] = s[1023];
}

__global__ __launch_bounds__(128) void k_scan2(const int* bsum, int* bofs, int* rowptr, int nb) {
    __shared__ int s[128];
    int t = threadIdx.x;
    int v = (t < nb) ? bsum[t] : 0;
    s[t] = v;
    __syncthreads();
    for (int off = 1; off < 128; off <<= 1) {
        int xv = (t >= off) ? s[t - off] : 0;
        __syncthreads();
        s[t] += xv;
        __syncthreads();
    }
    bofs[t] = s[t] - v;
    if (t == 0) rowptr[N_NODES] = N_EDGES;
}

__global__ __launch_bounds__(256) void k_scan3(int* rowptr, const int* bofs) {
    int i = blockIdx.x * 256 + threadIdx.x;
    if (i < N_NODES) rowptr[i] += bofs[i >> 10];
}

__global__ __launch_bounds__(256) void k_csr(const int* ei, const int* ea,
                                             const int* rowptr, int* cursor, int* epk) {
    int e = blockIdx.x * 256 + threadIdx.x;
    if (e >= N_EDGES) return;
    int s = ei[e];
    int d = ei[N_EDGES + e];
    int a0 = ea[e * 3], a1 = ea[e * 3 + 1], a2 = ea[e * 3 + 2];
    int hsh = (a0 + 3 * a1 + 7 * a2) & 15;
    int pos = rowptr[d] + atomicAdd(&cursor[d], 1);
    epk[pos] = s | (hsh << 20);     // src in [0,100000) < 2^20
}

// ---- graph boundaries from sorted batch ----
__global__ __launch_bounds__(256) void k_gptr(const int* batch, int* gptr) {
    int n = blockIdx.x * 256 + threadIdx.x;
    if (n >= N_NODES) return;
    int b = batch[n];
    int bp = (n == 0) ? -1 : batch[n - 1];
    for (int g = bp + 1; g <= b; ++g) gptr[g] = n;
    if (n == N_NODES - 1) {
        for (int g = b + 1; g <= N_GRAPH; ++g) gptr[g] = N_NODES;
    }
}

// ---- GINE aggregation, MLP-parallel gather ----
// One wave per node. 4 edge-groups x 16 lanes x float4: 4 edges in flight,
// x2 with manual unroll = 8 outstanding gather lines per wave.
__global__ __launch_bounds__(256) void k_gather(const float* __restrict__ h,
                                                const float* __restrict__ elinL,
                                                const int* __restrict__ rowptr,
                                                const int* __restrict__ epk,
                                                float* __restrict__ agg) {
    __shared__ float es[16 * 64];
    int t = threadIdx.x;
    ((float4*)es)[t] = ((const float4*)elinL)[t];   // 256 * float4 = 1024 floats
    __syncthreads();
    int n = blockIdx.x * 4 + (t >> 6);
    if (n >= N_NODES) return;
    int lane = t & 63;
    int grp = lane >> 4;            // edge subgroup 0..3
    int c4 = (lane & 15) << 2;      // channel base
    int p0 = rowptr[n], p1 = rowptr[n + 1];
    float4 acc = make_float4(0.f, 0.f, 0.f, 0.f);
    int p = p0 + grp;
    while (p + 4 < p1) {            // two edges for this group
        int pk0 = epk[p];
        int pk1 = epk[p + 4];
        float4 h0 = *(const float4*)(h + (pk0 & 0xFFFFF) * 64 + c4);
        float4 h1 = *(const float4*)(h + (pk1 & 0xFFFFF) * 64 + c4);
        float4 e0 = *(const float4*)(es + (pk0 >> 20) * 64 + c4);
        float4 e1 = *(const float4*)(es + (pk1 >> 20) * 64 + c4);
        acc.x += fmaxf(h0.x + e0.x, 0.f) + fmaxf(h1.x + e1.x, 0.f);
        acc.y += fmaxf(h0.y + e0.y, 0.f) + fmaxf(h1.y + e1.y, 0.f);
        acc.z += fmaxf(h0.z + e0.z, 0.f) + fmaxf(h1.z + e1.z, 0.f);
        acc.w += fmaxf(h0.w + e0.w, 0.f) + fmaxf(h1.w + e1.w, 0.f);
        p += 8;
    }
    if (p < p1) {
        int pk0 = epk[p];
        float4 h0 = *(const float4*)(h + (pk0 & 0xFFFFF) * 64 + c4);
        float4 e0 = *(const float4*)(es + (pk0 >> 20) * 64 + c4);
        acc.x += fmaxf(h0.x + e0.x, 0.f);
        acc.y += fmaxf(h0.y + e0.y, 0.f);
        acc.z += fmaxf(h0.z + e0.z, 0.f);
        acc.w += fmaxf(h0.w + e0.w, 0.f);
    }
    // fold the 4 edge-groups: lanes {l, l+16, l+32, l+48} hold same channels
    acc.x += __shfl_down(acc.x, 32, 64);
    acc.y += __shfl_down(acc.y, 32, 64);
    acc.z += __shfl_down(acc.z, 32, 64);
    acc.w += __shfl_down(acc.w, 32, 64);
    acc.x += __shfl_down(acc.x, 16, 64);
    acc.y += __shfl_down(acc.y, 16, 64);
    acc.z += __shfl_down(acc.z, 16, 64);
    acc.w += __shfl_down(acc.w, 16, 64);
    if (grp == 0) *(float4*)(agg + n * 64 + c4) = acc;
}

// ---- fused GINE MLP: z=(1+eps)*h+agg; hid=relu(z@W1^T+b1); out=relu(hid@W2^T+b2)
// Optional epilogue (gate!=nullptr): BN-fold then gate dot (layer 3).
// In-place safe: each block reads only the rows it writes, staged before stores.
__global__ __launch_bounds__(256) void k_mlp2(const float* __restrict__ hin,
                                              const float* __restrict__ agg,
                                              const float* __restrict__ epsp,
                                              const float* __restrict__ W1,
                                              const float* __restrict__ b1,
                                              const float* __restrict__ W2,
                                              const float* __restrict__ b2,
                                              float* __restrict__ out,
                                              const float* __restrict__ bnsc,
                                              const float* __restrict__ bnsh,
                                              const float* __restrict__ gate_w,
                                              const float* __restrict__ gate_b,
                                              float* __restrict__ gate) {
    __shared__ float in_s[64 * 68];
    __shared__ float wt_s[64 * 68];
    int t = threadIdx.x;
    int row0 = blockIdx.x * 64;
    float epsv = 1.f + epsp[0];
    for (int idx = t; idx < 1024; idx += 256) {
        int r = idx >> 4, cc4 = (idx & 15) << 2;
        int gr = row0 + r;
        float4 v = make_float4(0.f, 0.f, 0.f, 0.f);
        if (gr < N_NODES) {
            float4 a = *(const float4*)(hin + gr * 64 + cc4);
            float4 b = *(const float4*)(agg + gr * 64 + cc4);
            v.x = epsv * a.x + b.x; v.y = epsv * a.y + b.y;
            v.z = epsv * a.z + b.z; v.w = epsv * a.w + b.w;
        }
        *(float4*)(in_s + r * 68 + cc4) = v;
    }
    for (int idx = t; idx < 1024; idx += 256) {
        int cc = idx >> 4, k4 = (idx & 15) << 2;
        float4 w = *(const float4*)(W1 + cc * 64 + k4);
        wt_s[(k4 + 0) * 68 + cc] = w.x;
        wt_s[(k4 + 1) * 68 + cc] = w.y;
        wt_s[(k4 + 2) * 68 + cc] = w.z;
        wt_s[(k4 + 3) * 68 + cc] = w.w;
    }
    __syncthreads();
    int tc = t & 15, tr = t >> 4;       // cols tc*4..+3, rows tr+16*i
    float acc[4][4] = {};
    for (int k4 = 0; k4 < 16; ++k4) {
        float4 a[4], b[4];
        #pragma unroll
        for (int i = 0; i < 4; ++i) a[i] = *(float4*)(in_s + (tr + 16 * i) * 68 + k4 * 4);
        #pragma unroll
        for (int kk = 0; kk < 4; ++kk) b[kk] = *(float4*)(wt_s + (k4 * 4 + kk) * 68 + tc * 4);
        #pragma unroll
        for (int i = 0; i < 4; ++i) {
            float ax = a[i].x, ay = a[i].y, az = a[i].z, aw = a[i].w;
            acc[i][0] += ax * b[0].x + ay * b[1].x + az * b[2].x + aw * b[3].x;
            acc[i][1] += ax * b[0].y + ay * b[1].y + az * b[2].y + aw * b[3].y;
            acc[i][2] += ax * b[0].z + ay * b[1].z + az * b[2].z + aw * b[3].z;
            acc[i][3] += ax * b[0].w + ay * b[1].w + az * b[2].w + aw * b[3].w;
        }
    }
    __syncthreads();   // all reads of in_s / wt_s done
    // hidden = relu(acc + b1) -> in_s ; stage W2^T -> wt_s
    {
        float4 bb1 = *(const float4*)(b1 + tc * 4);
        #pragma unroll
        for (int i = 0; i < 4; ++i) {
            float* row = in_s + (tr + 16 * i) * 68 + tc * 4;
            row[0] = fmaxf(acc[i][0] + bb1.x, 0.f);
            row[1] = fmaxf(acc[i][1] + bb1.y, 0.f);
            row[2] = fmaxf(acc[i][2] + bb1.z, 0.f);
            row[3] = fmaxf(acc[i][3] + bb1.w, 0.f);
        }
    }
    for (int idx = t; idx < 1024; idx += 256) {
        int cc = idx >> 4, k4 = (idx & 15) << 2;
        float4 w = *(const float4*)(W2 + cc * 64 + k4);
        wt_s[(k4 + 0) * 68 + cc] = w.x;
        wt_s[(k4 + 1) * 68 + cc] = w.y;
        wt_s[(k4 + 2) * 68 + cc] = w.z;
        wt_s[(k4 + 3) * 68 + cc] = w.w;
    }
    __syncthreads();
    float acc2[4][4] = {};
    for (int k4 = 0; k4 < 16; ++k4) {
        float4 a[4], b[4];
        #pragma unroll
        for (int i = 0; i < 4; ++i) a[i] = *(float4*)(in_s + (tr + 16 * i) * 68 + k4 * 4);
        #pragma unroll
        for (int kk = 0; kk < 4; ++kk) b[kk] = *(float4*)(wt_s + (k4 * 4 + kk) * 68 + tc * 4);
        #pragma unroll
        for (int i = 0; i < 4; ++i) {
            float ax = a[i].x, ay = a[i].y, az = a[i].z, aw = a[i].w;
            acc2[i][0] += ax * b[0].x + ay * b[1].x + az * b[2].x + aw * b[3].x;
            acc2[i][1] += ax * b[0].y + ay * b[1].y + az * b[2].y + aw * b[3].y;
            acc2[i][2] += ax * b[0].z + ay * b[1].z + az * b[2].z + aw * b[3].z;
            acc2[i][3] += ax * b[0].w + ay * b[1].w + az * b[2].w + aw * b[3].w;
        }
    }
    float4 bb2 = *(const float4*)(b2 + tc * 4);
    if (gate == nullptr) {
        #pragma unroll
        for (int i = 0; i < 4; ++i) {
            int gr = row0 + tr + 16 * i;
            if (gr < N_NODES) {
                float4 o;
                o.x = fmaxf(acc2[i][0] + bb2.x, 0.f);
                o.y = fmaxf(acc2[i][1] + bb2.y, 0.f);
                o.z = fmaxf(acc2[i][2] + bb2.z, 0.f);
                o.w = fmaxf(acc2[i][3] + bb2.w, 0.f);
                *(float4*)(out + gr * 64 + tc * 4) = o;
            }
        }
    } else {
        // layer-3 epilogue: relu -> BN fold -> store normalized h, gate dot
        float4 sc = *(const float4*)(bnsc + tc * 4);
        float4 sh = *(const float4*)(bnsh + tc * 4);
        float4 gw = *(const float4*)(gate_w + tc * 4);
        float gb = gate_b[0];
        #pragma unroll
        for (int i = 0; i < 4; ++i) {
            int gr = row0 + tr + 16 * i;
            float4 o;
            o.x = fmaxf(acc2[i][0] + bb2.x, 0.f) * sc.x + sh.x;
            o.y = fmaxf(acc2[i][1] + bb2.y, 0.f) * sc.y + sh.y;
            o.z = fmaxf(acc2[i][2] + bb2.z, 0.f) * sc.z + sh.z;
            o.w = fmaxf(acc2[i][3] + bb2.w, 0.f) * sc.w + sh.w;
            float p = o.x * gw.x + o.y * gw.y + o.z * gw.z + o.w * gw.w;
            // reduce across the 16 lanes sharing this row (tc = 0..15 contiguous)
            p += __shfl_down(p, 8, 16);
            p += __shfl_down(p, 4, 16);
            p += __shfl_down(p, 2, 16);
            p += __shfl_down(p, 1, 16);
            if (gr < N_NODES) {
                *(float4*)(out + gr * 64 + tc * 4) = o;
                if (tc == 0) gate[gr] = p + gb;
            }
        }
    }
}

// ---- attention aggregation: one block per graph, atomic-free ----
__global__ __launch_bounds__(256) void k_att(const float* __restrict__ h,
                                             const float* __restrict__ gate,
                                             const int* __restrict__ gptr,
                                             float* __restrict__ graph) {
    __shared__ float red[4];
    __shared__ float acc_s[4][64];
    __shared__ float m_s, den_s;
    int t = threadIdx.x, g = blockIdx.x;
    int n0 = gptr[g], n1 = gptr[g + 1];
    float m = -INFINITY;
    for (int n = n0 + t; n < n1; n += 256) m = fmaxf(m, gate[n]);
    #pragma unroll
    for (int off = 32; off > 0; off >>= 1) m = fmaxf(m, __shfl_down(m, off, 64));
    if ((t & 63) == 0) red[t >> 6] = m;
    __syncthreads();
    if (t == 0) m_s = fmaxf(fmaxf(red[0], red[1]), fmaxf(red[2], red[3]));
    __syncthreads();
    m = m_s;
    float s = 0.f;
    for (int n = n0 + t; n < n1; n += 256) s += expf(gate[n] - m);
    #pragma unroll
    for (int off = 32; off > 0; off >>= 1) s += __shfl_down(s, off, 64);
    if ((t & 63) == 0) red[t >> 6] = s;
    __syncthreads();
    if (t == 0) den_s = red[0] + red[1] + red[2] + red[3] + 1e-16f;
    __syncthreads();
    float invden = 1.f / den_s;
    int c = t & 63, w = t >> 6;
    float acc = 0.f;
    for (int n = n0 + w; n < n1; n += 4) {
        float a = expf(gate[n] - m);
        acc += a * h[n * 64 + c];
    }
    acc_s[w][c] = acc;
    __syncthreads();
    if (w == 0)
        graph[g * 64 + c] = (acc_s[0][c] + acc_s[1][c] + acc_s[2][c] + acc_s[3][c]) * invden;
}

// ---- readout head ----
__global__ __launch_bounds__(128) void k_head(const float* graph, const float* w1, const float* b1,
                                              const float* w2, const float* b2, float* out) {
    __shared__ float w1s[128 * 65];
    __shared__ float gs[64];
    __shared__ float red[2];
    int t = threadIdx.x, g = blockIdx.x;
    for (int idx = t; idx < 128 * 16; idx += 128) {
        int r = idx >> 4, c4 = (idx & 15) << 2;
        float4 v = *(const float4*)(w1 + r * 64 + c4);
        w1s[r * 65 + c4 + 0] = v.x;
        w1s[r * 65 + c4 + 1] = v.y;
        w1s[r * 65 + c4 + 2] = v.z;
        w1s[r * 65 + c4 + 3] = v.w;
    }
    if (t < 64) gs[t] = graph[g * 64 + t];
    __syncthreads();
    float s = b1[t];
    #pragma unroll
    for (int k = 0; k < 64; ++k) s += gs[k] * w1s[t * 65 + k];
    float p = fmaxf(s, 0.f) * w2[t];
    #pragma unroll
    for (int off = 32; off > 0; off >>= 1) p += __shfl_down(p, off, 64);
    if ((t & 63) == 0) red[t >> 6] = p;
    __syncthreads();
    if (t == 0) out[g] = red[0] + red[1] + b2[0];
}

extern "C" void kernel_launch(void* const* d_in, const int* in_sizes, int n_in,
                              void* d_out, int out_size, void* d_ws, size_t ws_size,
                              hipStream_t stream) {
    const int* x    = (const int*)d_in[0];
    const int* ei   = (const int*)d_in[1];
    const int* ea   = (const int*)d_in[2];
    const int* bat  = (const int*)d_in[3];
    const float* emb0 = (const float*)d_in[4];
    const float* emb1 = (const float*)d_in[5];
    const float* emb2 = (const float*)d_in[6];
    const float* emb3 = (const float*)d_in[7];
    const float* emb4 = (const float*)d_in[8];
    const float* proj_w = (const float*)d_in[9];
    const float* proj_b = (const float*)d_in[10];
    const float* bn_g  = (const float*)d_in[35];
    const float* bn_b  = (const float*)d_in[36];
    const float* bn_rm = (const float*)d_in[37];
    const float* bn_rv = (const float*)d_in[38];
    const float* gate_w = (const float*)d_in[39];
    const float* gate_b = (const float*)d_in[40];
    const float* head_w1 = (const float*)d_in[41];
    const float* head_b1 = (const float*)d_in[42];
    const float* head_w2 = (const float*)d_in[43];
    const float* head_b2 = (const float*)d_in[44];

    char* wsb = (char*)d_ws;
    size_t o = 0;
    auto alloc = [&](size_t bytes) -> void* {
        void* p = wsb + o;
        o += (bytes + 255) & ~(size_t)255;
        return p;
    };
    float* ptab  = (float*)alloc(144 * 64 * 4);
    float* elin  = (float*)alloc(3 * 16 * 64 * 4);
    float* bnsc  = (float*)alloc(64 * 4);
    float* bnsh  = (float*)alloc(64 * 4);
    int* deg     = (int*)alloc((size_t)N_NODES * 4);
    int* rowptr  = (int*)alloc(((size_t)N_NODES + 1) * 4);
    int* cursor  = (int*)alloc((size_t)N_NODES * 4);
    int* bsum    = (int*)alloc(128 * 4);
    int* bofs    = (int*)alloc(128 * 4);
    int* gptr    = (int*)alloc((N_GRAPH + 1) * 4);
    int* epk     = (int*)alloc((size_t)N_EDGES * 4);
    float* h     = (float*)alloc((size_t)N_NODES * 64 * 4);
    float* agg   = (float*)alloc((size_t)N_NODES * 64 * 4);
    float* gate  = (float*)alloc((size_t)N_NODES * 4);
    float* graph = (float*)alloc((size_t)N_GRAPH * 64 * 4);

    hipMemsetAsync(deg, 0, (size_t)N_NODES * 4, stream);
    hipMemsetAsync(cursor, 0, (size_t)N_NODES * 4, stream);
    k_pre<<<49, 256, 0, stream>>>(emb0, emb1, emb2, emb3, emb4, proj_w,
                                  (const float*)d_in[11], (const float*)d_in[12], (const float*)d_in[13],
                                  (const float*)d_in[19], (const float*)d_in[20], (const float*)d_in[21],
                                  (const float*)d_in[27], (const float*)d_in[28], (const float*)d_in[29],
                                  bn_g, bn_b, bn_rm, bn_rv,
                                  ptab, elin, bnsc, bnsh);
    k_embed<<<(N_NODES * 64 + 255) / 256, 256, 0, stream>>>(x, ptab, proj_b, h);
    k_deg<<<(N_EDGES + 255) / 256, 256, 0, stream>>>(ei, deg);
    k_gptr<<<(N_NODES + 255) / 256, 256, 0, stream>>>(bat, gptr);
    k_scan1<<<98, 1024, 0, stream>>>(deg, rowptr, bsum);
    k_scan2<<<1, 128, 0, stream>>>(bsum, bofs, rowptr, 98);
    k_scan3<<<(N_NODES + 255) / 256, 256, 0, stream>>>(rowptr, bofs);
    k_csr<<<(N_EDGES + 255) / 256, 256, 0, stream>>>(ei, ea, rowptr, cursor, epk);

    for (int L = 0; L < 3; ++L) {
        const float* epsp = (const float*)d_in[14 + L * 8];
        const float* w1   = (const float*)d_in[15 + L * 8];
        const float* b1   = (const float*)d_in[16 + L * 8];
        const float* w2   = (const float*)d_in[17 + L * 8];
        const float* b2   = (const float*)d_in[18 + L * 8];
        k_gather<<<(N_NODES + 3) / 4, 256, 0, stream>>>(h, elin + L * 1024, rowptr, epk, agg);
        if (L < 2) {
            k_mlp2<<<(N_NODES + 63) / 64, 256, 0, stream>>>(h, agg, epsp, w1, b1, w2, b2, h,
                                                            nullptr, nullptr, nullptr, nullptr,
                                                            nullptr);
        } else {
            k_mlp2<<<(N_NODES + 63) / 64, 256, 0, stream>>>(h, agg, epsp, w1, b1, w2, b2, h,
                                                            bnsc, bnsh, gate_w, gate_b, gate);
        }
    }

    k_att<<<N_GRAPH, 256, 0, stream>>>(h, gate, gptr, graph);
    k_head<<<N_GRAPH, 128, 0, stream>>>(graph, head_w1, head_b1, head_w2, head_b2, (float*)d_out);
}

// Round 5
// 491.055 us; speedup vs baseline: 2.7408x; 1.2051x over previous
//
#include <hip/hip_runtime.h>
#include <stdint.h>

#define N_NODES 100000
#define N_EDGES 1200000
#define N_GRAPH 512
#define HID 64

#define NBUCK 391      // ceil(100000/256) buckets of 256 nodes (dst >> 8)
#define BCAP  4096     // per-bucket region capacity (mean 3069, ~18 sigma margin)
#define CHUNK 4096     // edges per k_bin block

#define PRE_JOBS (144 * 64 + 3 * 1024 + 64 + NBUCK)   // 12743

// ---- precompute: projected node-emb rows; edge-lin tables; folded BN; zero cursors ----
__global__ __launch_bounds__(256) void k_pre(
    const float* emb0, const float* emb1, const float* emb2, const float* emb3, const float* emb4,
    const float* proj_w,
    const float* ee1, const float* lw1, const float* lb1,
    const float* ee2, const float* lw2, const float* lb2,
    const float* ee3, const float* lw3, const float* lb3,
    const float* bn_g, const float* bn_b, const float* bn_rm, const float* bn_rv,
    float* ptab, float* elin, float* bnsc, float* bnsh, int* cursor)
{
    int job = blockIdx.x * 256 + threadIdx.x;
    if (job < 144 * 64) {
        int row = job >> 6, c = job & 63;
        const float* emb; int lr, dim, off;
        if (row < 120)      { emb = emb0; lr = row;       dim = 64; off = 0;  }
        else if (row < 130) { emb = emb1; lr = row - 120; dim = 16; off = 64; }
        else if (row < 137) { emb = emb2; lr = row - 130; dim = 8;  off = 80; }
        else if (row < 142) { emb = emb3; lr = row - 137; dim = 8;  off = 88; }
        else                { emb = emb4; lr = row - 142; dim = 4;  off = 96; }
        float s = 0.f;
        for (int d = 0; d < dim; ++d)
            s += emb[lr * dim + d] * proj_w[c * 100 + off + d];
        ptab[row * 64 + c] = s;
    } else if (job < 144 * 64 + 3 * 1024) {
        int j = job - 144 * 64;
        int L = j >> 10; int r = (j >> 6) & 15; int c = j & 63;
        const float* ee = (L == 0) ? ee1 : (L == 1) ? ee2 : ee3;
        const float* lw = (L == 0) ? lw1 : (L == 1) ? lw2 : lw3;
        const float* lb = (L == 0) ? lb1 : (L == 1) ? lb2 : lb3;
        float s = lb[c];
        for (int d = 0; d < 8; ++d) s += ee[r * 8 + d] * lw[c * 8 + d];
        elin[j] = s;
    } else if (job < 144 * 64 + 3 * 1024 + 64) {
        int c = job - (144 * 64 + 3 * 1024);
        float sc = bn_g[c] * rsqrtf(bn_rv[c] + 1e-5f);
        bnsc[c] = sc;
        bnsh[c] = bn_b[c] - bn_rm[c] * sc;
    } else if (job < PRE_JOBS) {
        cursor[job - (144 * 64 + 3 * 1024 + 64)] = 0;
    }
}

// ---- node embedding + projection ----
__global__ __launch_bounds__(256) void k_embed(const int* x, const float* ptab,
                                               const float* proj_b, float* h) {
    int id = blockIdx.x * 256 + threadIdx.x;
    if (id >= N_NODES * HID) return;
    int n = id >> 6, c = id & 63;
    const int* xr = x + n * 5;
    int r0 = min(max(xr[0], 0), 119);
    int r1 = 120 + min(max(xr[1], 0), 9);
    int r2 = 130 + min(max(xr[2], 0), 6);
    int r3 = 137 + min(max(xr[3], 0), 4);
    int r4 = 142 + min(max(xr[4], 0), 1);
    h[id] = proj_b[c] + ptab[r0 * 64 + c] + ptab[r1 * 64 + c] + ptab[r2 * 64 + c]
          + ptab[r3 * 64 + c] + ptab[r4 * 64 + c];
}

// ---- graph boundaries from sorted batch ----
__global__ __launch_bounds__(256) void k_gptr(const int* batch, int* gptr) {
    int n = blockIdx.x * 256 + threadIdx.x;
    if (n >= N_NODES) return;
    int b = batch[n];
    int bp = (n == 0) ? -1 : batch[n - 1];
    for (int g = bp + 1; g <= b; ++g) gptr[g] = n;
    if (n == N_NODES - 1) {
        for (int g = b + 1; g <= N_GRAPH; ++g) gptr[g] = N_NODES;
    }
}

// ---- CSR pass 1: LDS counting-sort chunks into bucket regions (coalesced runs) ----
// payload: src(17b) | hash<<17 (4b) | dst_local<<21 (8b)
__global__ __launch_bounds__(256) void k_bin(const int* __restrict__ ei,
                                             const int* __restrict__ ea,
                                             int* __restrict__ cursor,
                                             int* __restrict__ binned) {
    __shared__ int pay[CHUNK];
    __shared__ unsigned short bkid[CHUNK];
    __shared__ int hist[NBUCK], inc[NBUCK], tmp[NBUCK], gdelta[NBUCK];
    int t = threadIdx.x;
    int e0 = blockIdx.x * CHUNK;
    for (int i = t; i < NBUCK; i += 256) hist[i] = 0;
    __syncthreads();
    int mypay[16], myrb[16];
    #pragma unroll
    for (int j = 0; j < 16; ++j) {
        int e = e0 + j * 256 + t;
        myrb[j] = -1;
        if (e < N_EDGES) {
            int s = ei[e];
            int d = ei[N_EDGES + e];
            int hsh = (ea[e * 3] + 3 * ea[e * 3 + 1] + 7 * ea[e * 3 + 2]) & 15;
            int b = d >> 8;
            mypay[j] = s | (hsh << 17) | ((d & 255) << 21);
            int r = atomicAdd(&hist[b], 1);      // rank < 4096 -> 12 bits
            myrb[j] = r | (b << 12);
        }
    }
    __syncthreads();
    for (int i = t; i < NBUCK; i += 256) inc[i] = hist[i];
    __syncthreads();
    for (int off = 1; off < NBUCK; off <<= 1) {
        for (int i = t; i < NBUCK; i += 256) tmp[i] = inc[i] + ((i >= off) ? inc[i - off] : 0);
        __syncthreads();
        for (int i = t; i < NBUCK; i += 256) inc[i] = tmp[i];
        __syncthreads();
    }
    // reserve global space per bucket, one atomic per (block,bucket)
    for (int i = t; i < NBUCK; i += 256) {
        int c = hist[i];
        int gp = c ? atomicAdd(&cursor[i], c) : 0;
        gdelta[i] = i * BCAP + gp - (inc[i] - c);   // slot -> global index offset
    }
    __syncthreads();
    // place payloads into LDS in bucket-sorted order
    #pragma unroll
    for (int j = 0; j < 16; ++j) {
        if (myrb[j] >= 0) {
            int b = myrb[j] >> 12, r = myrb[j] & 0xFFF;
            int slot = (inc[b] - hist[b]) + r;
            pay[slot] = mypay[j];
            bkid[slot] = (unsigned short)b;
        }
    }
    __syncthreads();
    int tot = inc[NBUCK - 1];
    for (int i = t; i < tot; i += 256)
        binned[gdelta[bkid[i]] + i] = pay[i];
}

// ---- CSR pass 1.5: scan bucket counts -> bucket bases ----
__global__ __launch_bounds__(512) void k_bscan(const int* cursor, int* bbase, int* rowptr) {
    __shared__ int s[512], tp[512];
    int t = threadIdx.x;
    int v = (t < NBUCK) ? cursor[t] : 0;
    s[t] = v;
    __syncthreads();
    for (int off = 1; off < 512; off <<= 1) {
        tp[t] = s[t] + ((t >= off) ? s[t - off] : 0);
        __syncthreads();
        s[t] = tp[t];
        __syncthreads();
    }
    if (t < NBUCK) bbase[t] = s[t] - v;
    if (t == 0) { bbase[NBUCK] = N_EDGES; rowptr[N_NODES] = N_EDGES; }
}

// ---- CSR pass 2: per-bucket local CSR; contiguous (L2-resident) scatter; rowptr direct ----
__global__ __launch_bounds__(256) void k_fin(const int* __restrict__ binned,
                                             const int* __restrict__ cursor,
                                             const int* __restrict__ bbase,
                                             int* __restrict__ rowptr,
                                             int* __restrict__ epk) {
    __shared__ int h2[256], sc[256], cur[256];
    int b = blockIdx.x, t = threadIdx.x;
    int cnt = cursor[b];
    int gb = bbase[b];
    int node0 = b << 8;
    h2[t] = 0;
    __syncthreads();
    const int* bp = binned + b * BCAP;
    for (int i = t; i < cnt; i += 256) atomicAdd(&h2[(bp[i] >> 21) & 255], 1);
    __syncthreads();
    sc[t] = h2[t];
    __syncthreads();
    for (int off = 1; off < 256; off <<= 1) {
        int v = (t >= off) ? sc[t - off] : 0;
        __syncthreads();
        sc[t] += v;
        __syncthreads();
    }
    int ex = sc[t] - h2[t];
    cur[t] = ex;
    int n = node0 + t;
    if (n < N_NODES) rowptr[n] = gb + ex;
    __syncthreads();
    for (int i = t; i < cnt; i += 256) {
        int p = bp[i];
        int pos = atomicAdd(&cur[(p >> 21) & 255], 1);
        epk[gb + pos] = p & 0x1FFFFF;          // src | hash<<17
    }
}

// ---- GINE aggregation, MLP-parallel gather ----
__global__ __launch_bounds__(256) void k_gather(const float* __restrict__ h,
                                                const float* __restrict__ elinL,
                                                const int* __restrict__ rowptr,
                                                const int* __restrict__ epk,
                                                float* __restrict__ agg) {
    __shared__ float es[16 * 64];
    int t = threadIdx.x;
    ((float4*)es)[t] = ((const float4*)elinL)[t];   // 256 * float4 = 1024 floats
    __syncthreads();
    int n = blockIdx.x * 4 + (t >> 6);
    if (n >= N_NODES) return;
    int lane = t & 63;
    int grp = lane >> 4;            // edge subgroup 0..3
    int c4 = (lane & 15) << 2;      // channel base
    int p0 = rowptr[n], p1 = rowptr[n + 1];
    float4 acc = make_float4(0.f, 0.f, 0.f, 0.f);
    int p = p0 + grp;
    while (p + 4 < p1) {            // two edges for this group
        int pk0 = epk[p];
        int pk1 = epk[p + 4];
        float4 h0 = *(const float4*)(h + (pk0 & 0x1FFFF) * 64 + c4);
        float4 h1 = *(const float4*)(h + (pk1 & 0x1FFFF) * 64 + c4);
        float4 e0 = *(const float4*)(es + ((pk0 >> 17) & 15) * 64 + c4);
        float4 e1 = *(const float4*)(es + ((pk1 >> 17) & 15) * 64 + c4);
        acc.x += fmaxf(h0.x + e0.x, 0.f) + fmaxf(h1.x + e1.x, 0.f);
        acc.y += fmaxf(h0.y + e0.y, 0.f) + fmaxf(h1.y + e1.y, 0.f);
        acc.z += fmaxf(h0.z + e0.z, 0.f) + fmaxf(h1.z + e1.z, 0.f);
        acc.w += fmaxf(h0.w + e0.w, 0.f) + fmaxf(h1.w + e1.w, 0.f);
        p += 8;
    }
    if (p < p1) {
        int pk0 = epk[p];
        float4 h0 = *(const float4*)(h + (pk0 & 0x1FFFF) * 64 + c4);
        float4 e0 = *(const float4*)(es + ((pk0 >> 17) & 15) * 64 + c4);
        acc.x += fmaxf(h0.x + e0.x, 0.f);
        acc.y += fmaxf(h0.y + e0.y, 0.f);
        acc.z += fmaxf(h0.z + e0.z, 0.f);
        acc.w += fmaxf(h0.w + e0.w, 0.f);
    }
    acc.x += __shfl_down(acc.x, 32, 64);
    acc.y += __shfl_down(acc.y, 32, 64);
    acc.z += __shfl_down(acc.z, 32, 64);
    acc.w += __shfl_down(acc.w, 32, 64);
    acc.x += __shfl_down(acc.x, 16, 64);
    acc.y += __shfl_down(acc.y, 16, 64);
    acc.z += __shfl_down(acc.z, 16, 64);
    acc.w += __shfl_down(acc.w, 16, 64);
    if (grp == 0) *(float4*)(agg + n * 64 + c4) = acc;
}

// ---- fused GINE MLP (two linears, relu, optional BN+gate epilogue) ----
__global__ __launch_bounds__(256) void k_mlp2(const float* __restrict__ hin,
                                              const float* __restrict__ agg,
                                              const float* __restrict__ epsp,
                                              const float* __restrict__ W1,
                                              const float* __restrict__ b1,
                                              const float* __restrict__ W2,
                                              const float* __restrict__ b2,
                                              float* __restrict__ out,
                                              const float* __restrict__ bnsc,
                                              const float* __restrict__ bnsh,
                                              const float* __restrict__ gate_w,
                                              const float* __restrict__ gate_b,
                                              float* __restrict__ gate) {
    __shared__ float in_s[64 * 68];
    __shared__ float wt_s[64 * 68];
    int t = threadIdx.x;
    int row0 = blockIdx.x * 64;
    float epsv = 1.f + epsp[0];
    for (int idx = t; idx < 1024; idx += 256) {
        int r = idx >> 4, cc4 = (idx & 15) << 2;
        int gr = row0 + r;
        float4 v = make_float4(0.f, 0.f, 0.f, 0.f);
        if (gr < N_NODES) {
            float4 a = *(const float4*)(hin + gr * 64 + cc4);
            float4 b = *(const float4*)(agg + gr * 64 + cc4);
            v.x = epsv * a.x + b.x; v.y = epsv * a.y + b.y;
            v.z = epsv * a.z + b.z; v.w = epsv * a.w + b.w;
        }
        *(float4*)(in_s + r * 68 + cc4) = v;
    }
    for (int idx = t; idx < 1024; idx += 256) {
        int cc = idx >> 4, k4 = (idx & 15) << 2;
        float4 w = *(const float4*)(W1 + cc * 64 + k4);
        wt_s[(k4 + 0) * 68 + cc] = w.x;
        wt_s[(k4 + 1) * 68 + cc] = w.y;
        wt_s[(k4 + 2) * 68 + cc] = w.z;
        wt_s[(k4 + 3) * 68 + cc] = w.w;
    }
    __syncthreads();
    int tc = t & 15, tr = t >> 4;
    float acc[4][4] = {};
    for (int k4 = 0; k4 < 16; ++k4) {
        float4 a[4], b[4];
        #pragma unroll
        for (int i = 0; i < 4; ++i) a[i] = *(float4*)(in_s + (tr + 16 * i) * 68 + k4 * 4);
        #pragma unroll
        for (int kk = 0; kk < 4; ++kk) b[kk] = *(float4*)(wt_s + (k4 * 4 + kk) * 68 + tc * 4);
        #pragma unroll
        for (int i = 0; i < 4; ++i) {
            float ax = a[i].x, ay = a[i].y, az = a[i].z, aw = a[i].w;
            acc[i][0] += ax * b[0].x + ay * b[1].x + az * b[2].x + aw * b[3].x;
            acc[i][1] += ax * b[0].y + ay * b[1].y + az * b[2].y + aw * b[3].y;
            acc[i][2] += ax * b[0].z + ay * b[1].z + az * b[2].z + aw * b[3].z;
            acc[i][3] += ax * b[0].w + ay * b[1].w + az * b[2].w + aw * b[3].w;
        }
    }
    __syncthreads();
    {
        float4 bb1 = *(const float4*)(b1 + tc * 4);
        #pragma unroll
        for (int i = 0; i < 4; ++i) {
            float* row = in_s + (tr + 16 * i) * 68 + tc * 4;
            row[0] = fmaxf(acc[i][0] + bb1.x, 0.f);
            row[1] = fmaxf(acc[i][1] + bb1.y, 0.f);
            row[2] = fmaxf(acc[i][2] + bb1.z, 0.f);
            row[3] = fmaxf(acc[i][3] + bb1.w, 0.f);
        }
    }
    for (int idx = t; idx < 1024; idx += 256) {
        int cc = idx >> 4, k4 = (idx & 15) << 2;
        float4 w = *(const float4*)(W2 + cc * 64 + k4);
        wt_s[(k4 + 0) * 68 + cc] = w.x;
        wt_s[(k4 + 1) * 68 + cc] = w.y;
        wt_s[(k4 + 2) * 68 + cc] = w.z;
        wt_s[(k4 + 3) * 68 + cc] = w.w;
    }
    __syncthreads();
    float acc2[4][4] = {};
    for (int k4 = 0; k4 < 16; ++k4) {
        float4 a[4], b[4];
        #pragma unroll
        for (int i = 0; i < 4; ++i) a[i] = *(float4*)(in_s + (tr + 16 * i) * 68 + k4 * 4);
        #pragma unroll
        for (int kk = 0; kk < 4; ++kk) b[kk] = *(float4*)(wt_s + (k4 * 4 + kk) * 68 + tc * 4);
        #pragma unroll
        for (int i = 0; i < 4; ++i) {
            float ax = a[i].x, ay = a[i].y, az = a[i].z, aw = a[i].w;
            acc2[i][0] += ax * b[0].x + ay * b[1].x + az * b[2].x + aw * b[3].x;
            acc2[i][1] += ax * b[0].y + ay * b[1].y + az * b[2].y + aw * b[3].y;
            acc2[i][2] += ax * b[0].z + ay * b[1].z + az * b[2].z + aw * b[3].z;
            acc2[i][3] += ax * b[0].w + ay * b[1].w + az * b[2].w + aw * b[3].w;
        }
    }
    float4 bb2 = *(const float4*)(b2 + tc * 4);
    if (gate == nullptr) {
        #pragma unroll
        for (int i = 0; i < 4; ++i) {
            int gr = row0 + tr + 16 * i;
            if (gr < N_NODES) {
                float4 o;
                o.x = fmaxf(acc2[i][0] + bb2.x, 0.f);
                o.y = fmaxf(acc2[i][1] + bb2.y, 0.f);
                o.z = fmaxf(acc2[i][2] + bb2.z, 0.f);
                o.w = fmaxf(acc2[i][3] + bb2.w, 0.f);
                *(float4*)(out + gr * 64 + tc * 4) = o;
            }
        }
    } else {
        float4 sc = *(const float4*)(bnsc + tc * 4);
        float4 sh = *(const float4*)(bnsh + tc * 4);
        float4 gw = *(const float4*)(gate_w + tc * 4);
        float gb = gate_b[0];
        #pragma unroll
        for (int i = 0; i < 4; ++i) {
            int gr = row0 + tr + 16 * i;
            float4 o;
            o.x = fmaxf(acc2[i][0] + bb2.x, 0.f) * sc.x + sh.x;
            o.y = fmaxf(acc2[i][1] + bb2.y, 0.f) * sc.y + sh.y;
            o.z = fmaxf(acc2[i][2] + bb2.z, 0.f) * sc.z + sh.z;
            o.w = fmaxf(acc2[i][3] + bb2.w, 0.f) * sc.w + sh.w;
            float p = o.x * gw.x + o.y * gw.y + o.z * gw.z + o.w * gw.w;
            p += __shfl_down(p, 8, 16);
            p += __shfl_down(p, 4, 16);
            p += __shfl_down(p, 2, 16);
            p += __shfl_down(p, 1, 16);
            if (gr < N_NODES) {
                *(float4*)(out + gr * 64 + tc * 4) = o;
                if (tc == 0) gate[gr] = p + gb;
            }
        }
    }
}

// ---- attention aggregation: one block per graph, atomic-free ----
__global__ __launch_bounds__(256) void k_att(const float* __restrict__ h,
                                             const float* __restrict__ gate,
                                             const int* __restrict__ gptr,
                                             float* __restrict__ graph) {
    __shared__ float red[4];
    __shared__ float acc_s[4][64];
    __shared__ float m_s, den_s;
    int t = threadIdx.x, g = blockIdx.x;
    int n0 = gptr[g], n1 = gptr[g + 1];
    float m = -INFINITY;
    for (int n = n0 + t; n < n1; n += 256) m = fmaxf(m, gate[n]);
    #pragma unroll
    for (int off = 32; off > 0; off >>= 1) m = fmaxf(m, __shfl_down(m, off, 64));
    if ((t & 63) == 0) red[t >> 6] = m;
    __syncthreads();
    if (t == 0) m_s = fmaxf(fmaxf(red[0], red[1]), fmaxf(red[2], red[3]));
    __syncthreads();
    m = m_s;
    float s = 0.f;
    for (int n = n0 + t; n < n1; n += 256) s += expf(gate[n] - m);
    #pragma unroll
    for (int off = 32; off > 0; off >>= 1) s += __shfl_down(s, off, 64);
    if ((t & 63) == 0) red[t >> 6] = s;
    __syncthreads();
    if (t == 0) den_s = red[0] + red[1] + red[2] + red[3] + 1e-16f;
    __syncthreads();
    float invden = 1.f / den_s;
    int c = t & 63, w = t >> 6;
    float acc = 0.f;
    for (int n = n0 + w; n < n1; n += 4) {
        float a = expf(gate[n] - m);
        acc += a * h[n * 64 + c];
    }
    acc_s[w][c] = acc;
    __syncthreads();
    if (w == 0)
        graph[g * 64 + c] = (acc_s[0][c] + acc_s[1][c] + acc_s[2][c] + acc_s[3][c]) * invden;
}

// ---- readout head ----
__global__ __launch_bounds__(128) void k_head(const float* graph, const float* w1, const float* b1,
                                              const float* w2, const float* b2, float* out) {
    __shared__ float w1s[128 * 65];
    __shared__ float gs[64];
    __shared__ float red[2];
    int t = threadIdx.x, g = blockIdx.x;
    for (int idx = t; idx < 128 * 16; idx += 128) {
        int r = idx >> 4, c4 = (idx & 15) << 2;
        float4 v = *(const float4*)(w1 + r * 64 + c4);
        w1s[r * 65 + c4 + 0] = v.x;
        w1s[r * 65 + c4 + 1] = v.y;
        w1s[r * 65 + c4 + 2] = v.z;
        w1s[r * 65 + c4 + 3] = v.w;
    }
    if (t < 64) gs[t] = graph[g * 64 + t];
    __syncthreads();
    float s = b1[t];
    #pragma unroll
    for (int k = 0; k < 64; ++k) s += gs[k] * w1s[t * 65 + k];
    float p = fmaxf(s, 0.f) * w2[t];
    #pragma unroll
    for (int off = 32; off > 0; off >>= 1) p += __shfl_down(p, off, 64);
    if ((t & 63) == 0) red[t >> 6] = p;
    __syncthreads();
    if (t == 0) out[g] = red[0] + red[1] + b2[0];
}

extern "C" void kernel_launch(void* const* d_in, const int* in_sizes, int n_in,
                              void* d_out, int out_size, void* d_ws, size_t ws_size,
                              hipStream_t stream) {
    const int* x    = (const int*)d_in[0];
    const int* ei   = (const int*)d_in[1];
    const int* ea   = (const int*)d_in[2];
    const int* bat  = (const int*)d_in[3];
    const float* emb0 = (const float*)d_in[4];
    const float* emb1 = (const float*)d_in[5];
    const float* emb2 = (const float*)d_in[6];
    const float* emb3 = (const float*)d_in[7];
    const float* emb4 = (const float*)d_in[8];
    const float* proj_w = (const float*)d_in[9];
    const float* proj_b = (const float*)d_in[10];
    const float* bn_g  = (const float*)d_in[35];
    const float* bn_b  = (const float*)d_in[36];
    const float* bn_rm = (const float*)d_in[37];
    const float* bn_rv = (const float*)d_in[38];
    const float* gate_w = (const float*)d_in[39];
    const float* gate_b = (const float*)d_in[40];
    const float* head_w1 = (const float*)d_in[41];
    const float* head_b1 = (const float*)d_in[42];
    const float* head_w2 = (const float*)d_in[43];
    const float* head_b2 = (const float*)d_in[44];

    char* wsb = (char*)d_ws;
    size_t o = 0;
    auto alloc = [&](size_t bytes) -> void* {
        void* p = wsb + o;
        o += (bytes + 255) & ~(size_t)255;
        return p;
    };
    float* ptab   = (float*)alloc(144 * 64 * 4);
    float* elin   = (float*)alloc(3 * 16 * 64 * 4);
    float* bnsc   = (float*)alloc(64 * 4);
    float* bnsh   = (float*)alloc(64 * 4);
    int* cursor   = (int*)alloc(NBUCK * 4);
    int* bbase    = (int*)alloc((NBUCK + 1) * 4);
    int* gptr     = (int*)alloc((N_GRAPH + 1) * 4);
    int* rowptr   = (int*)alloc(((size_t)N_NODES + 1) * 4);
    int* binned   = (int*)alloc((size_t)NBUCK * BCAP * 4);
    int* epk      = (int*)alloc((size_t)N_EDGES * 4);
    float* h      = (float*)alloc((size_t)N_NODES * 64 * 4);
    float* agg    = (float*)alloc((size_t)N_NODES * 64 * 4);
    float* gate   = (float*)alloc((size_t)N_NODES * 4);
    float* graph  = (float*)alloc((size_t)N_GRAPH * 64 * 4);

    k_pre<<<(PRE_JOBS + 255) / 256, 256, 0, stream>>>(
                                  emb0, emb1, emb2, emb3, emb4, proj_w,
                                  (const float*)d_in[11], (const float*)d_in[12], (const float*)d_in[13],
                                  (const float*)d_in[19], (const float*)d_in[20], (const float*)d_in[21],
                                  (const float*)d_in[27], (const float*)d_in[28], (const float*)d_in[29],
                                  bn_g, bn_b, bn_rm, bn_rv,
                                  ptab, elin, bnsc, bnsh, cursor);
    k_embed<<<(N_NODES * 64 + 255) / 256, 256, 0, stream>>>(x, ptab, proj_b, h);
    k_gptr<<<(N_NODES + 255) / 256, 256, 0, stream>>>(bat, gptr);
    k_bin<<<(N_EDGES + CHUNK - 1) / CHUNK, 256, 0, stream>>>(ei, ea, cursor, binned);
    k_bscan<<<1, 512, 0, stream>>>(cursor, bbase, rowptr);
    k_fin<<<NBUCK, 256, 0, stream>>>(binned, cursor, bbase, rowptr, epk);

    for (int L = 0; L < 3; ++L) {
        const float* epsp = (const float*)d_in[14 + L * 8];
        const float* w1   = (const float*)d_in[15 + L * 8];
        const float* b1   = (const float*)d_in[16 + L * 8];
        const float* w2   = (const float*)d_in[17 + L * 8];
        const float* b2   = (const float*)d_in[18 + L * 8];
        k_gather<<<(N_NODES + 3) / 4, 256, 0, stream>>>(h, elin + L * 1024, rowptr, epk, agg);
        if (L < 2) {
            k_mlp2<<<(N_NODES + 63) / 64, 256, 0, stream>>>(h, agg, epsp, w1, b1, w2, b2, h,
                                                            nullptr, nullptr, nullptr, nullptr,
                                                            nullptr);
        } else {
            k_mlp2<<<(N_NODES + 63) / 64, 256, 0, stream>>>(h, agg, epsp, w1, b1, w2, b2, h,
                                                            bnsc, bnsh, gate_w, gate_b, gate);
        }
    }

    k_att<<<N_GRAPH, 256, 0, stream>>>(h, gate, gptr, graph);
    k_head<<<N_GRAPH, 128, 0, stream>>>(graph, head_w1, head_b1, head_w2, head_b2, (float*)d_out);
}

// Round 6
// 474.399 us; speedup vs baseline: 2.8371x; 1.0351x over previous
//
#include <hip/hip_runtime.h>
#include <stdint.h>

#define N_NODES 100000
#define N_EDGES 1200000
#define N_GRAPH 512
#define HID 64

#define NBUCK 391      // ceil(100000/256) buckets of 256 nodes (dst >> 8)
#define BCAP  4096     // per-bucket region capacity (mean 3069, ~18 sigma margin)
#define CHUNK 4096     // edges per k_bin block

#define PRE_JOBS (144 * 64 + 3 * 1024 + 64 + NBUCK)   // 12743

// bf16 helpers (RNE pack, shift unpack)
__device__ __forceinline__ unsigned short f2bf(float f) {
    unsigned u = __float_as_uint(f);
    u += 0x7FFF + ((u >> 16) & 1);
    return (unsigned short)(u >> 16);
}
__device__ __forceinline__ float bf2f(unsigned short b) {
    return __uint_as_float((unsigned)b << 16);
}

// ---- precompute: projected node-emb rows; edge-lin tables; folded BN; zero cursors ----
__global__ __launch_bounds__(256) void k_pre(
    const float* emb0, const float* emb1, const float* emb2, const float* emb3, const float* emb4,
    const float* proj_w,
    const float* ee1, const float* lw1, const float* lb1,
    const float* ee2, const float* lw2, const float* lb2,
    const float* ee3, const float* lw3, const float* lb3,
    const float* bn_g, const float* bn_b, const float* bn_rm, const float* bn_rv,
    float* ptab, float* elin, float* bnsc, float* bnsh, int* cursor)
{
    int job = blockIdx.x * 256 + threadIdx.x;
    if (job < 144 * 64) {
        int row = job >> 6, c = job & 63;
        const float* emb; int lr, dim, off;
        if (row < 120)      { emb = emb0; lr = row;       dim = 64; off = 0;  }
        else if (row < 130) { emb = emb1; lr = row - 120; dim = 16; off = 64; }
        else if (row < 137) { emb = emb2; lr = row - 130; dim = 8;  off = 80; }
        else if (row < 142) { emb = emb3; lr = row - 137; dim = 8;  off = 88; }
        else                { emb = emb4; lr = row - 142; dim = 4;  off = 96; }
        float s = 0.f;
        for (int d = 0; d < dim; ++d)
            s += emb[lr * dim + d] * proj_w[c * 100 + off + d];
        ptab[row * 64 + c] = s;
    } else if (job < 144 * 64 + 3 * 1024) {
        int j = job - 144 * 64;
        int L = j >> 10; int r = (j >> 6) & 15; int c = j & 63;
        const float* ee = (L == 0) ? ee1 : (L == 1) ? ee2 : ee3;
        const float* lw = (L == 0) ? lw1 : (L == 1) ? lw2 : lw3;
        const float* lb = (L == 0) ? lb1 : (L == 1) ? lb2 : lb3;
        float s = lb[c];
        for (int d = 0; d < 8; ++d) s += ee[r * 8 + d] * lw[c * 8 + d];
        elin[j] = s;
    } else if (job < 144 * 64 + 3 * 1024 + 64) {
        int c = job - (144 * 64 + 3 * 1024);
        float sc = bn_g[c] * rsqrtf(bn_rv[c] + 1e-5f);
        bnsc[c] = sc;
        bnsh[c] = bn_b[c] - bn_rm[c] * sc;
    } else if (job < PRE_JOBS) {
        cursor[job - (144 * 64 + 3 * 1024 + 64)] = 0;
    }
}

// ---- node embedding + projection; writes fp32 h and bf16 shadow h2 ----
__global__ __launch_bounds__(256) void k_embed(const int* x, const float* ptab,
                                               const float* proj_b, float* h,
                                               unsigned short* h2) {
    int id = blockIdx.x * 256 + threadIdx.x;
    if (id >= N_NODES * HID) return;
    int n = id >> 6, c = id & 63;
    const int* xr = x + n * 5;
    int r0 = min(max(xr[0], 0), 119);
    int r1 = 120 + min(max(xr[1], 0), 9);
    int r2 = 130 + min(max(xr[2], 0), 6);
    int r3 = 137 + min(max(xr[3], 0), 4);
    int r4 = 142 + min(max(xr[4], 0), 1);
    float v = proj_b[c] + ptab[r0 * 64 + c] + ptab[r1 * 64 + c] + ptab[r2 * 64 + c]
            + ptab[r3 * 64 + c] + ptab[r4 * 64 + c];
    h[id] = v;
    h2[id] = f2bf(v);
}

// ---- graph boundaries from sorted batch ----
__global__ __launch_bounds__(256) void k_gptr(const int* batch, int* gptr) {
    int n = blockIdx.x * 256 + threadIdx.x;
    if (n >= N_NODES) return;
    int b = batch[n];
    int bp = (n == 0) ? -1 : batch[n - 1];
    for (int g = bp + 1; g <= b; ++g) gptr[g] = n;
    if (n == N_NODES - 1) {
        for (int g = b + 1; g <= N_GRAPH; ++g) gptr[g] = N_NODES;
    }
}

// ---- CSR pass 1: LDS counting-sort chunks into bucket regions (coalesced runs) ----
// payload: src(17b) | hash<<17 (4b) | dst_local<<21 (8b)
__global__ __launch_bounds__(256) void k_bin(const int* __restrict__ ei,
                                             const int* __restrict__ ea,
                                             int* __restrict__ cursor,
                                             int* __restrict__ binned) {
    __shared__ int pay[CHUNK];
    __shared__ unsigned short bkid[CHUNK];
    __shared__ int hist[NBUCK], inc[NBUCK], tmp[NBUCK], gdelta[NBUCK];
    int t = threadIdx.x;
    int e0 = blockIdx.x * CHUNK;
    for (int i = t; i < NBUCK; i += 256) hist[i] = 0;
    __syncthreads();
    int mypay[16], myrb[16];
    #pragma unroll
    for (int j = 0; j < 16; ++j) {
        int e = e0 + j * 256 + t;
        myrb[j] = -1;
        if (e < N_EDGES) {
            int s = ei[e];
            int d = ei[N_EDGES + e];
            int hsh = (ea[e * 3] + 3 * ea[e * 3 + 1] + 7 * ea[e * 3 + 2]) & 15;
            int b = d >> 8;
            mypay[j] = s | (hsh << 17) | ((d & 255) << 21);
            int r = atomicAdd(&hist[b], 1);      // rank < 4096 -> 12 bits
            myrb[j] = r | (b << 12);
        }
    }
    __syncthreads();
    for (int i = t; i < NBUCK; i += 256) inc[i] = hist[i];
    __syncthreads();
    for (int off = 1; off < NBUCK; off <<= 1) {
        for (int i = t; i < NBUCK; i += 256) tmp[i] = inc[i] + ((i >= off) ? inc[i - off] : 0);
        __syncthreads();
        for (int i = t; i < NBUCK; i += 256) inc[i] = tmp[i];
        __syncthreads();
    }
    // reserve global space per bucket, one atomic per (block,bucket)
    for (int i = t; i < NBUCK; i += 256) {
        int c = hist[i];
        int gp = c ? atomicAdd(&cursor[i], c) : 0;
        gdelta[i] = i * BCAP + gp - (inc[i] - c);   // slot -> global index offset
    }
    __syncthreads();
    // place payloads into LDS in bucket-sorted order
    #pragma unroll
    for (int j = 0; j < 16; ++j) {
        if (myrb[j] >= 0) {
            int b = myrb[j] >> 12, r = myrb[j] & 0xFFF;
            int slot = (inc[b] - hist[b]) + r;
            pay[slot] = mypay[j];
            bkid[slot] = (unsigned short)b;
        }
    }
    __syncthreads();
    int tot = inc[NBUCK - 1];
    for (int i = t; i < tot; i += 256)
        binned[gdelta[bkid[i]] + i] = pay[i];
}

// ---- CSR pass 1.5: scan bucket counts -> bucket bases ----
__global__ __launch_bounds__(512) void k_bscan(const int* cursor, int* bbase, int* rowptr) {
    __shared__ int s[512], tp[512];
    int t = threadIdx.x;
    int v = (t < NBUCK) ? cursor[t] : 0;
    s[t] = v;
    __syncthreads();
    for (int off = 1; off < 512; off <<= 1) {
        tp[t] = s[t] + ((t >= off) ? s[t - off] : 0);
        __syncthreads();
        s[t] = tp[t];
        __syncthreads();
    }
    if (t < NBUCK) bbase[t] = s[t] - v;
    if (t == 0) { bbase[NBUCK] = N_EDGES; rowptr[N_NODES] = N_EDGES; }
}

// ---- CSR pass 2: per-bucket local CSR; contiguous (L2-resident) scatter; rowptr direct ----
__global__ __launch_bounds__(256) void k_fin(const int* __restrict__ binned,
                                             const int* __restrict__ cursor,
                                             const int* __restrict__ bbase,
                                             int* __restrict__ rowptr,
                                             int* __restrict__ epk) {
    __shared__ int h2[256], sc[256], cur[256];
    int b = blockIdx.x, t = threadIdx.x;
    int cnt = cursor[b];
    int gb = bbase[b];
    int node0 = b << 8;
    h2[t] = 0;
    __syncthreads();
    const int* bp = binned + b * BCAP;
    for (int i = t; i < cnt; i += 256) atomicAdd(&h2[(bp[i] >> 21) & 255], 1);
    __syncthreads();
    sc[t] = h2[t];
    __syncthreads();
    for (int off = 1; off < 256; off <<= 1) {
        int v = (t >= off) ? sc[t - off] : 0;
        __syncthreads();
        sc[t] += v;
        __syncthreads();
    }
    int ex = sc[t] - h2[t];
    cur[t] = ex;
    int n = node0 + t;
    if (n < N_NODES) rowptr[n] = gb + ex;
    __syncthreads();
    for (int i = t; i < cnt; i += 256) {
        int p = bp[i];
        int pos = atomicAdd(&cur[(p >> 21) & 255], 1);
        epk[gb + pos] = p & 0x1FFFFF;          // src | hash<<17
    }
}

// ---- GINE aggregation: gather bf16 shadow h2 (128 B/row), fp32 accumulate ----
__global__ __launch_bounds__(256) void k_gather(const unsigned short* __restrict__ h2,
                                                const float* __restrict__ elinL,
                                                const int* __restrict__ rowptr,
                                                const int* __restrict__ epk,
                                                float* __restrict__ agg) {
    __shared__ float es[16 * 64];
    int t = threadIdx.x;
    ((float4*)es)[t] = ((const float4*)elinL)[t];   // 256 * float4 = 1024 floats
    __syncthreads();
    int n = blockIdx.x * 4 + (t >> 6);
    if (n >= N_NODES) return;
    int lane = t & 63;
    int grp = lane >> 4;            // edge subgroup 0..3
    int c4 = (lane & 15) << 2;      // channel base
    int p0 = rowptr[n], p1 = rowptr[n + 1];
    float4 acc = make_float4(0.f, 0.f, 0.f, 0.f);
    int p = p0 + grp;
    while (p + 4 < p1) {            // two edges for this group
        int pk0 = epk[p];
        int pk1 = epk[p + 4];
        ushort4 a0 = *(const ushort4*)(h2 + (pk0 & 0x1FFFF) * 64 + c4);
        ushort4 a1 = *(const ushort4*)(h2 + (pk1 & 0x1FFFF) * 64 + c4);
        float4 e0 = *(const float4*)(es + ((pk0 >> 17) & 15) * 64 + c4);
        float4 e1 = *(const float4*)(es + ((pk1 >> 17) & 15) * 64 + c4);
        acc.x += fmaxf(bf2f(a0.x) + e0.x, 0.f) + fmaxf(bf2f(a1.x) + e1.x, 0.f);
        acc.y += fmaxf(bf2f(a0.y) + e0.y, 0.f) + fmaxf(bf2f(a1.y) + e1.y, 0.f);
        acc.z += fmaxf(bf2f(a0.z) + e0.z, 0.f) + fmaxf(bf2f(a1.z) + e1.z, 0.f);
        acc.w += fmaxf(bf2f(a0.w) + e0.w, 0.f) + fmaxf(bf2f(a1.w) + e1.w, 0.f);
        p += 8;
    }
    if (p < p1) {
        int pk0 = epk[p];
        ushort4 a0 = *(const ushort4*)(h2 + (pk0 & 0x1FFFF) * 64 + c4);
        float4 e0 = *(const float4*)(es + ((pk0 >> 17) & 15) * 64 + c4);
        acc.x += fmaxf(bf2f(a0.x) + e0.x, 0.f);
        acc.y += fmaxf(bf2f(a0.y) + e0.y, 0.f);
        acc.z += fmaxf(bf2f(a0.z) + e0.z, 0.f);
        acc.w += fmaxf(bf2f(a0.w) + e0.w, 0.f);
    }
    acc.x += __shfl_down(acc.x, 32, 64);
    acc.y += __shfl_down(acc.y, 32, 64);
    acc.z += __shfl_down(acc.z, 32, 64);
    acc.w += __shfl_down(acc.w, 32, 64);
    acc.x += __shfl_down(acc.x, 16, 64);
    acc.y += __shfl_down(acc.y, 16, 64);
    acc.z += __shfl_down(acc.z, 16, 64);
    acc.w += __shfl_down(acc.w, 16, 64);
    if (grp == 0) *(float4*)(agg + n * 64 + c4) = acc;
}

// ---- fused GINE MLP (two linears, relu, optional BN+gate epilogue) ----
// h2out: bf16 shadow of the output (written when non-null, i.e. layers 1-2).
__global__ __launch_bounds__(256) void k_mlp2(const float* __restrict__ hin,
                                              const float* __restrict__ agg,
                                              const float* __restrict__ epsp,
                                              const float* __restrict__ W1,
                                              const float* __restrict__ b1,
                                              const float* __restrict__ W2,
                                              const float* __restrict__ b2,
                                              float* __restrict__ out,
                                              unsigned short* __restrict__ h2out,
                                              const float* __restrict__ bnsc,
                                              const float* __restrict__ bnsh,
                                              const float* __restrict__ gate_w,
                                              const float* __restrict__ gate_b,
                                              float* __restrict__ gate) {
    __shared__ float in_s[64 * 68];
    __shared__ float wt_s[64 * 68];
    int t = threadIdx.x;
    int row0 = blockIdx.x * 64;
    float epsv = 1.f + epsp[0];
    for (int idx = t; idx < 1024; idx += 256) {
        int r = idx >> 4, cc4 = (idx & 15) << 2;
        int gr = row0 + r;
        float4 v = make_float4(0.f, 0.f, 0.f, 0.f);
        if (gr < N_NODES) {
            float4 a = *(const float4*)(hin + gr * 64 + cc4);
            float4 b = *(const float4*)(agg + gr * 64 + cc4);
            v.x = epsv * a.x + b.x; v.y = epsv * a.y + b.y;
            v.z = epsv * a.z + b.z; v.w = epsv * a.w + b.w;
        }
        *(float4*)(in_s + r * 68 + cc4) = v;
    }
    for (int idx = t; idx < 1024; idx += 256) {
        int cc = idx >> 4, k4 = (idx & 15) << 2;
        float4 w = *(const float4*)(W1 + cc * 64 + k4);
        wt_s[(k4 + 0) * 68 + cc] = w.x;
        wt_s[(k4 + 1) * 68 + cc] = w.y;
        wt_s[(k4 + 2) * 68 + cc] = w.z;
        wt_s[(k4 + 3) * 68 + cc] = w.w;
    }
    __syncthreads();
    int tc = t & 15, tr = t >> 4;
    float acc[4][4] = {};
    for (int k4 = 0; k4 < 16; ++k4) {
        float4 a[4], b[4];
        #pragma unroll
        for (int i = 0; i < 4; ++i) a[i] = *(float4*)(in_s + (tr + 16 * i) * 68 + k4 * 4);
        #pragma unroll
        for (int kk = 0; kk < 4; ++kk) b[kk] = *(float4*)(wt_s + (k4 * 4 + kk) * 68 + tc * 4);
        #pragma unroll
        for (int i = 0; i < 4; ++i) {
            float ax = a[i].x, ay = a[i].y, az = a[i].z, aw = a[i].w;
            acc[i][0] += ax * b[0].x + ay * b[1].x + az * b[2].x + aw * b[3].x;
            acc[i][1] += ax * b[0].y + ay * b[1].y + az * b[2].y + aw * b[3].y;
            acc[i][2] += ax * b[0].z + ay * b[1].z + az * b[2].z + aw * b[3].z;
            acc[i][3] += ax * b[0].w + ay * b[1].w + az * b[2].w + aw * b[3].w;
        }
    }
    __syncthreads();
    {
        float4 bb1 = *(const float4*)(b1 + tc * 4);
        #pragma unroll
        for (int i = 0; i < 4; ++i) {
            float* row = in_s + (tr + 16 * i) * 68 + tc * 4;
            row[0] = fmaxf(acc[i][0] + bb1.x, 0.f);
            row[1] = fmaxf(acc[i][1] + bb1.y, 0.f);
            row[2] = fmaxf(acc[i][2] + bb1.z, 0.f);
            row[3] = fmaxf(acc[i][3] + bb1.w, 0.f);
        }
    }
    for (int idx = t; idx < 1024; idx += 256) {
        int cc = idx >> 4, k4 = (idx & 15) << 2;
        float4 w = *(const float4*)(W2 + cc * 64 + k4);
        wt_s[(k4 + 0) * 68 + cc] = w.x;
        wt_s[(k4 + 1) * 68 + cc] = w.y;
        wt_s[(k4 + 2) * 68 + cc] = w.z;
        wt_s[(k4 + 3) * 68 + cc] = w.w;
    }
    __syncthreads();
    float acc2[4][4] = {};
    for (int k4 = 0; k4 < 16; ++k4) {
        float4 a[4], b[4];
        #pragma unroll
        for (int i = 0; i < 4; ++i) a[i] = *(float4*)(in_s + (tr + 16 * i) * 68 + k4 * 4);
        #pragma unroll
        for (int kk = 0; kk < 4; ++kk) b[kk] = *(float4*)(wt_s + (k4 * 4 + kk) * 68 + tc * 4);
        #pragma unroll
        for (int i = 0; i < 4; ++i) {
            float ax = a[i].x, ay = a[i].y, az = a[i].z, aw = a[i].w;
            acc2[i][0] += ax * b[0].x + ay * b[1].x + az * b[2].x + aw * b[3].x;
            acc2[i][1] += ax * b[0].y + ay * b[1].y + az * b[2].y + aw * b[3].y;
            acc2[i][2] += ax * b[0].z + ay * b[1].z + az * b[2].z + aw * b[3].z;
            acc2[i][3] += ax * b[0].w + ay * b[1].w + az * b[2].w + aw * b[3].w;
        }
    }
    float4 bb2 = *(const float4*)(b2 + tc * 4);
    if (gate == nullptr) {
        #pragma unroll
        for (int i = 0; i < 4; ++i) {
            int gr = row0 + tr + 16 * i;
            if (gr < N_NODES) {
                float4 o;
                o.x = fmaxf(acc2[i][0] + bb2.x, 0.f);
                o.y = fmaxf(acc2[i][1] + bb2.y, 0.f);
                o.z = fmaxf(acc2[i][2] + bb2.z, 0.f);
                o.w = fmaxf(acc2[i][3] + bb2.w, 0.f);
                *(float4*)(out + gr * 64 + tc * 4) = o;
                ushort4 ob;
                ob.x = f2bf(o.x); ob.y = f2bf(o.y); ob.z = f2bf(o.z); ob.w = f2bf(o.w);
                *(ushort4*)(h2out + gr * 64 + tc * 4) = ob;
            }
        }
    } else {
        float4 sc = *(const float4*)(bnsc + tc * 4);
        float4 sh = *(const float4*)(bnsh + tc * 4);
        float4 gw = *(const float4*)(gate_w + tc * 4);
        float gb = gate_b[0];
        #pragma unroll
        for (int i = 0; i < 4; ++i) {
            int gr = row0 + tr + 16 * i;
            float4 o;
            o.x = fmaxf(acc2[i][0] + bb2.x, 0.f) * sc.x + sh.x;
            o.y = fmaxf(acc2[i][1] + bb2.y, 0.f) * sc.y + sh.y;
            o.z = fmaxf(acc2[i][2] + bb2.z, 0.f) * sc.z + sh.z;
            o.w = fmaxf(acc2[i][3] + bb2.w, 0.f) * sc.w + sh.w;
            float p = o.x * gw.x + o.y * gw.y + o.z * gw.z + o.w * gw.w;
            p += __shfl_down(p, 8, 16);
            p += __shfl_down(p, 4, 16);
            p += __shfl_down(p, 2, 16);
            p += __shfl_down(p, 1, 16);
            if (gr < N_NODES) {
                *(float4*)(out + gr * 64 + tc * 4) = o;
                if (tc == 0) gate[gr] = p + gb;
            }
        }
    }
}

// ---- attention aggregation: one block per graph, atomic-free ----
__global__ __launch_bounds__(256) void k_att(const float* __restrict__ h,
                                             const float* __restrict__ gate,
                                             const int* __restrict__ gptr,
                                             float* __restrict__ graph) {
    __shared__ float red[4];
    __shared__ float acc_s[4][64];
    __shared__ float m_s, den_s;
    int t = threadIdx.x, g = blockIdx.x;
    int n0 = gptr[g], n1 = gptr[g + 1];
    float m = -INFINITY;
    for (int n = n0 + t; n < n1; n += 256) m = fmaxf(m, gate[n]);
    #pragma unroll
    for (int off = 32; off > 0; off >>= 1) m = fmaxf(m, __shfl_down(m, off, 64));
    if ((t & 63) == 0) red[t >> 6] = m;
    __syncthreads();
    if (t == 0) m_s = fmaxf(fmaxf(red[0], red[1]), fmaxf(red[2], red[3]));
    __syncthreads();
    m = m_s;
    float s = 0.f;
    for (int n = n0 + t; n < n1; n += 256) s += expf(gate[n] - m);
    #pragma unroll
    for (int off = 32; off > 0; off >>= 1) s += __shfl_down(s, off, 64);
    if ((t & 63) == 0) red[t >> 6] = s;
    __syncthreads();
    if (t == 0) den_s = red[0] + red[1] + red[2] + red[3] + 1e-16f;
    __syncthreads();
    float invden = 1.f / den_s;
    int c = t & 63, w = t >> 6;
    float acc = 0.f;
    for (int n = n0 + w; n < n1; n += 4) {
        float a = expf(gate[n] - m);
        acc += a * h[n * 64 + c];
    }
    acc_s[w][c] = acc;
    __syncthreads();
    if (w == 0)
        graph[g * 64 + c] = (acc_s[0][c] + acc_s[1][c] + acc_s[2][c] + acc_s[3][c]) * invden;
}

// ---- readout head ----
__global__ __launch_bounds__(128) void k_head(const float* graph, const float* w1, const float* b1,
                                              const float* w2, const float* b2, float* out) {
    __shared__ float w1s[128 * 65];
    __shared__ float gs[64];
    __shared__ float red[2];
    int t = threadIdx.x, g = blockIdx.x;
    for (int idx = t; idx < 128 * 16; idx += 128) {
        int r = idx >> 4, c4 = (idx & 15) << 2;
        float4 v = *(const float4*)(w1 + r * 64 + c4);
        w1s[r * 65 + c4 + 0] = v.x;
        w1s[r * 65 + c4 + 1] = v.y;
        w1s[r * 65 + c4 + 2] = v.z;
        w1s[r * 65 + c4 + 3] = v.w;
    }
    if (t < 64) gs[t] = graph[g * 64 + t];
    __syncthreads();
    float s = b1[t];
    #pragma unroll
    for (int k = 0; k < 64; ++k) s += gs[k] * w1s[t * 65 + k];
    float p = fmaxf(s, 0.f) * w2[t];
    #pragma unroll
    for (int off = 32; off > 0; off >>= 1) p += __shfl_down(p, off, 64);
    if ((t & 63) == 0) red[t >> 6] = p;
    __syncthreads();
    if (t == 0) out[g] = red[0] + red[1] + b2[0];
}

extern "C" void kernel_launch(void* const* d_in, const int* in_sizes, int n_in,
                              void* d_out, int out_size, void* d_ws, size_t ws_size,
                              hipStream_t stream) {
    const int* x    = (const int*)d_in[0];
    const int* ei   = (const int*)d_in[1];
    const int* ea   = (const int*)d_in[2];
    const int* bat  = (const int*)d_in[3];
    const float* emb0 = (const float*)d_in[4];
    const float* emb1 = (const float*)d_in[5];
    const float* emb2 = (const float*)d_in[6];
    const float* emb3 = (const float*)d_in[7];
    const float* emb4 = (const float*)d_in[8];
    const float* proj_w = (const float*)d_in[9];
    const float* proj_b = (const float*)d_in[10];
    const float* bn_g  = (const float*)d_in[35];
    const float* bn_b  = (const float*)d_in[36];
    const float* bn_rm = (const float*)d_in[37];
    const float* bn_rv = (const float*)d_in[38];
    const float* gate_w = (const float*)d_in[39];
    const float* gate_b = (const float*)d_in[40];
    const float* head_w1 = (const float*)d_in[41];
    const float* head_b1 = (const float*)d_in[42];
    const float* head_w2 = (const float*)d_in[43];
    const float* head_b2 = (const float*)d_in[44];

    char* wsb = (char*)d_ws;
    size_t o = 0;
    auto alloc = [&](size_t bytes) -> void* {
        void* p = wsb + o;
        o += (bytes + 255) & ~(size_t)255;
        return p;
    };
    float* ptab   = (float*)alloc(144 * 64 * 4);
    float* elin   = (float*)alloc(3 * 16 * 64 * 4);
    float* bnsc   = (float*)alloc(64 * 4);
    float* bnsh   = (float*)alloc(64 * 4);
    int* cursor   = (int*)alloc(NBUCK * 4);
    int* bbase    = (int*)alloc((NBUCK + 1) * 4);
    int* gptr     = (int*)alloc((N_GRAPH + 1) * 4);
    int* rowptr   = (int*)alloc(((size_t)N_NODES + 1) * 4);
    int* binned   = (int*)alloc((size_t)NBUCK * BCAP * 4);
    int* epk      = (int*)alloc((size_t)N_EDGES * 4);
    float* h      = (float*)alloc((size_t)N_NODES * 64 * 4);
    unsigned short* h2 = (unsigned short*)alloc((size_t)N_NODES * 64 * 2);
    float* agg    = (float*)alloc((size_t)N_NODES * 64 * 4);
    float* gate   = (float*)alloc((size_t)N_NODES * 4);
    float* graph  = (float*)alloc((size_t)N_GRAPH * 64 * 4);

    k_pre<<<(PRE_JOBS + 255) / 256, 256, 0, stream>>>(
                                  emb0, emb1, emb2, emb3, emb4, proj_w,
                                  (const float*)d_in[11], (const float*)d_in[12], (const float*)d_in[13],
                                  (const float*)d_in[19], (const float*)d_in[20], (const float*)d_in[21],
                                  (const float*)d_in[27], (const float*)d_in[28], (const float*)d_in[29],
                                  bn_g, bn_b, bn_rm, bn_rv,
                                  ptab, elin, bnsc, bnsh, cursor);
    k_embed<<<(N_NODES * 64 + 255) / 256, 256, 0, stream>>>(x, ptab, proj_b, h, h2);
    k_gptr<<<(N_NODES + 255) / 256, 256, 0, stream>>>(bat, gptr);
    k_bin<<<(N_EDGES + CHUNK - 1) / CHUNK, 256, 0, stream>>>(ei, ea, cursor, binned);
    k_bscan<<<1, 512, 0, stream>>>(cursor, bbase, rowptr);
    k_fin<<<NBUCK, 256, 0, stream>>>(binned, cursor, bbase, rowptr, epk);

    for (int L = 0; L < 3; ++L) {
        const float* epsp = (const float*)d_in[14 + L * 8];
        const float* w1   = (const float*)d_in[15 + L * 8];
        const float* b1   = (const float*)d_in[16 + L * 8];
        const float* w2   = (const float*)d_in[17 + L * 8];
        const float* b2   = (const float*)d_in[18 + L * 8];
        k_gather<<<(N_NODES + 3) / 4, 256, 0, stream>>>(h2, elin + L * 1024, rowptr, epk, agg);
        if (L < 2) {
            k_mlp2<<<(N_NODES + 63) / 64, 256, 0, stream>>>(h, agg, epsp, w1, b1, w2, b2, h, h2,
                                                            nullptr, nullptr, nullptr, nullptr,
                                                            nullptr);
        } else {
            k_mlp2<<<(N_NODES + 63) / 64, 256, 0, stream>>>(h, agg, epsp, w1, b1, w2, b2, h, nullptr,
                                                            bnsc, bnsh, gate_w, gate_b, gate);
        }
    }

    k_att<<<N_GRAPH, 256, 0, stream>>>(h, gate, gptr, graph);
    k_head<<<N_GRAPH, 128, 0, stream>>>(graph, head_w1, head_b1, head_w2, head_b2, (float*)d_out);
}

// Round 7
// 445.309 us; speedup vs baseline: 3.0224x; 1.0653x over previous
//
#include <hip/hip_runtime.h>
#include <stdint.h>

#define N_NODES 100000
#define N_EDGES 1200000
#define N_GRAPH 512
#define HID 64

#define NBUCK 391      // ceil(100000/256) buckets of 256 nodes (dst >> 8)
#define BCAP  4096     // per-bucket region capacity (mean 3069, ~18 sigma margin)
#define CHUNK 4096     // edges per k_bin block

// pre jobs: ptab 9216 | elin 3072 | bn 64 | cursor NBUCK | weight-bf16 24576
#define PRE_W0  (144 * 64 + 3 * 1024 + 64 + NBUCK)
#define PRE_JOBS (PRE_W0 + 6 * 4096)

typedef __attribute__((ext_vector_type(8))) short bshort8;
typedef __attribute__((ext_vector_type(4))) float f32x4;

// bf16 helpers (RNE pack, shift unpack)
__device__ __forceinline__ unsigned short f2bf(float f) {
    unsigned u = __float_as_uint(f);
    u += 0x7FFF + ((u >> 16) & 1);
    return (unsigned short)(u >> 16);
}
__device__ __forceinline__ float bf2f(unsigned short b) {
    return __uint_as_float((unsigned)b << 16);
}

// ---- precompute: projected node-emb rows; edge-lin tables; folded BN; zero
//      cursors; bf16 copies of the 6 MLP weight matrices ----
__global__ __launch_bounds__(256) void k_pre(
    const float* emb0, const float* emb1, const float* emb2, const float* emb3, const float* emb4,
    const float* proj_w,
    const float* ee1, const float* lw1, const float* lb1,
    const float* ee2, const float* lw2, const float* lb2,
    const float* ee3, const float* lw3, const float* lb3,
    const float* bn_g, const float* bn_b, const float* bn_rm, const float* bn_rv,
    const float* w11, const float* w12, const float* w21, const float* w22,
    const float* w31, const float* w32,
    float* ptab, float* elin, float* bnsc, float* bnsh, int* cursor,
    unsigned short* wbf)
{
    int job = blockIdx.x * 256 + threadIdx.x;
    if (job < 144 * 64) {
        int row = job >> 6, c = job & 63;
        const float* emb; int lr, dim, off;
        if (row < 120)      { emb = emb0; lr = row;       dim = 64; off = 0;  }
        else if (row < 130) { emb = emb1; lr = row - 120; dim = 16; off = 64; }
        else if (row < 137) { emb = emb2; lr = row - 130; dim = 8;  off = 80; }
        else if (row < 142) { emb = emb3; lr = row - 137; dim = 8;  off = 88; }
        else                { emb = emb4; lr = row - 142; dim = 4;  off = 96; }
        float s = 0.f;
        for (int d = 0; d < dim; ++d)
            s += emb[lr * dim + d] * proj_w[c * 100 + off + d];
        ptab[row * 64 + c] = s;
    } else if (job < 144 * 64 + 3 * 1024) {
        int j = job - 144 * 64;
        int L = j >> 10; int r = (j >> 6) & 15; int c = j & 63;
        const float* ee = (L == 0) ? ee1 : (L == 1) ? ee2 : ee3;
        const float* lw = (L == 0) ? lw1 : (L == 1) ? lw2 : lw3;
        const float* lb = (L == 0) ? lb1 : (L == 1) ? lb2 : lb3;
        float s = lb[c];
        for (int d = 0; d < 8; ++d) s += ee[r * 8 + d] * lw[c * 8 + d];
        elin[j] = s;
    } else if (job < 144 * 64 + 3 * 1024 + 64) {
        int c = job - (144 * 64 + 3 * 1024);
        float sc = bn_g[c] * rsqrtf(bn_rv[c] + 1e-5f);
        bnsc[c] = sc;
        bnsh[c] = bn_b[c] - bn_rm[c] * sc;
    } else if (job < PRE_W0) {
        cursor[job - (144 * 64 + 3 * 1024 + 64)] = 0;
    } else if (job < PRE_JOBS) {
        int j2 = job - PRE_W0;
        int sel = j2 >> 12;          // 0..5 = L*2 + which
        const float* W = (sel == 0) ? w11 : (sel == 1) ? w12 : (sel == 2) ? w21
                       : (sel == 3) ? w22 : (sel == 4) ? w31 : w32;
        wbf[j2] = f2bf(W[j2 & 4095]);
    }
}

// ---- node embedding + projection; writes fp32 h and bf16 shadow h2 ----
__global__ __launch_bounds__(256) void k_embed(const int* x, const float* ptab,
                                               const float* proj_b, float* h,
                                               unsigned short* h2) {
    int id = blockIdx.x * 256 + threadIdx.x;
    if (id >= N_NODES * HID) return;
    int n = id >> 6, c = id & 63;
    const int* xr = x + n * 5;
    int r0 = min(max(xr[0], 0), 119);
    int r1 = 120 + min(max(xr[1], 0), 9);
    int r2 = 130 + min(max(xr[2], 0), 6);
    int r3 = 137 + min(max(xr[3], 0), 4);
    int r4 = 142 + min(max(xr[4], 0), 1);
    float v = proj_b[c] + ptab[r0 * 64 + c] + ptab[r1 * 64 + c] + ptab[r2 * 64 + c]
            + ptab[r3 * 64 + c] + ptab[r4 * 64 + c];
    h[id] = v;
    h2[id] = f2bf(v);
}

// ---- graph boundaries from sorted batch ----
__global__ __launch_bounds__(256) void k_gptr(const int* batch, int* gptr) {
    int n = blockIdx.x * 256 + threadIdx.x;
    if (n >= N_NODES) return;
    int b = batch[n];
    int bp = (n == 0) ? -1 : batch[n - 1];
    for (int g = bp + 1; g <= b; ++g) gptr[g] = n;
    if (n == N_NODES - 1) {
        for (int g = b + 1; g <= N_GRAPH; ++g) gptr[g] = N_NODES;
    }
}

// ---- CSR pass 1: LDS counting-sort chunks into bucket regions ----
// payload: src(17b) | hash<<17 (4b) | dst_local<<21 (8b)
__global__ __launch_bounds__(256) void k_bin(const int* __restrict__ ei,
                                             const int* __restrict__ ea,
                                             int* __restrict__ cursor,
                                             int* __restrict__ binned) {
    __shared__ int pay[CHUNK];
    __shared__ unsigned short bkid[CHUNK];
    __shared__ int hist[NBUCK], inc[NBUCK], tmp[NBUCK], gdelta[NBUCK];
    int t = threadIdx.x;
    int e0 = blockIdx.x * CHUNK;
    for (int i = t; i < NBUCK; i += 256) hist[i] = 0;
    __syncthreads();
    int mypay[16], myrb[16];
    #pragma unroll
    for (int j = 0; j < 16; ++j) {
        int e = e0 + j * 256 + t;
        myrb[j] = -1;
        if (e < N_EDGES) {
            int s = ei[e];
            int d = ei[N_EDGES + e];
            int hsh = (ea[e * 3] + 3 * ea[e * 3 + 1] + 7 * ea[e * 3 + 2]) & 15;
            int b = d >> 8;
            mypay[j] = s | (hsh << 17) | ((d & 255) << 21);
            int r = atomicAdd(&hist[b], 1);      // rank < 4096 -> 12 bits
            myrb[j] = r | (b << 12);
        }
    }
    __syncthreads();
    for (int i = t; i < NBUCK; i += 256) inc[i] = hist[i];
    __syncthreads();
    for (int off = 1; off < NBUCK; off <<= 1) {
        for (int i = t; i < NBUCK; i += 256) tmp[i] = inc[i] + ((i >= off) ? inc[i - off] : 0);
        __syncthreads();
        for (int i = t; i < NBUCK; i += 256) inc[i] = tmp[i];
        __syncthreads();
    }
    for (int i = t; i < NBUCK; i += 256) {
        int c = hist[i];
        int gp = c ? atomicAdd(&cursor[i], c) : 0;
        gdelta[i] = i * BCAP + gp - (inc[i] - c);
    }
    __syncthreads();
    #pragma unroll
    for (int j = 0; j < 16; ++j) {
        if (myrb[j] >= 0) {
            int b = myrb[j] >> 12, r = myrb[j] & 0xFFF;
            int slot = (inc[b] - hist[b]) + r;
            pay[slot] = mypay[j];
            bkid[slot] = (unsigned short)b;
        }
    }
    __syncthreads();
    int tot = inc[NBUCK - 1];
    for (int i = t; i < tot; i += 256)
        binned[gdelta[bkid[i]] + i] = pay[i];
}

// ---- CSR pass 1.5: scan bucket counts -> bucket bases ----
__global__ __launch_bounds__(512) void k_bscan(const int* cursor, int* bbase, int* rowptr) {
    __shared__ int s[512], tp[512];
    int t = threadIdx.x;
    int v = (t < NBUCK) ? cursor[t] : 0;
    s[t] = v;
    __syncthreads();
    for (int off = 1; off < 512; off <<= 1) {
        tp[t] = s[t] + ((t >= off) ? s[t - off] : 0);
        __syncthreads();
        s[t] = tp[t];
        __syncthreads();
    }
    if (t < NBUCK) bbase[t] = s[t] - v;
    if (t == 0) { bbase[NBUCK] = N_EDGES; rowptr[N_NODES] = N_EDGES; }
}

// ---- CSR pass 2: per-bucket local CSR ----
__global__ __launch_bounds__(256) void k_fin(const int* __restrict__ binned,
                                             const int* __restrict__ cursor,
                                             const int* __restrict__ bbase,
                                             int* __restrict__ rowptr,
                                             int* __restrict__ epk) {
    __shared__ int h2[256], sc[256], cur[256];
    int b = blockIdx.x, t = threadIdx.x;
    int cnt = cursor[b];
    int gb = bbase[b];
    int node0 = b << 8;
    h2[t] = 0;
    __syncthreads();
    const int* bp = binned + b * BCAP;
    for (int i = t; i < cnt; i += 256) atomicAdd(&h2[(bp[i] >> 21) & 255], 1);
    __syncthreads();
    sc[t] = h2[t];
    __syncthreads();
    for (int off = 1; off < 256; off <<= 1) {
        int v = (t >= off) ? sc[t - off] : 0;
        __syncthreads();
        sc[t] += v;
        __syncthreads();
    }
    int ex = sc[t] - h2[t];
    cur[t] = ex;
    int n = node0 + t;
    if (n < N_NODES) rowptr[n] = gb + ex;
    __syncthreads();
    for (int i = t; i < cnt; i += 256) {
        int p = bp[i];
        int pos = atomicAdd(&cur[(p >> 21) & 255], 1);
        epk[gb + pos] = p & 0x1FFFFF;          // src | hash<<17
    }
}

// ---- GINE aggregation: gather bf16 shadow h2 (128 B/row), fp32 accumulate ----
__global__ __launch_bounds__(256) void k_gather(const unsigned short* __restrict__ h2,
                                                const float* __restrict__ elinL,
                                                const int* __restrict__ rowptr,
                                                const int* __restrict__ epk,
                                                float* __restrict__ agg) {
    __shared__ float es[16 * 64];
    int t = threadIdx.x;
    ((float4*)es)[t] = ((const float4*)elinL)[t];
    __syncthreads();
    int n = blockIdx.x * 4 + (t >> 6);
    if (n >= N_NODES) return;
    int lane = t & 63;
    int grp = lane >> 4;
    int c4 = (lane & 15) << 2;
    int p0 = rowptr[n], p1 = rowptr[n + 1];
    float4 acc = make_float4(0.f, 0.f, 0.f, 0.f);
    int p = p0 + grp;
    while (p + 4 < p1) {
        int pk0 = epk[p];
        int pk1 = epk[p + 4];
        ushort4 a0 = *(const ushort4*)(h2 + (pk0 & 0x1FFFF) * 64 + c4);
        ushort4 a1 = *(const ushort4*)(h2 + (pk1 & 0x1FFFF) * 64 + c4);
        float4 e0 = *(const float4*)(es + ((pk0 >> 17) & 15) * 64 + c4);
        float4 e1 = *(const float4*)(es + ((pk1 >> 17) & 15) * 64 + c4);
        acc.x += fmaxf(bf2f(a0.x) + e0.x, 0.f) + fmaxf(bf2f(a1.x) + e1.x, 0.f);
        acc.y += fmaxf(bf2f(a0.y) + e0.y, 0.f) + fmaxf(bf2f(a1.y) + e1.y, 0.f);
        acc.z += fmaxf(bf2f(a0.z) + e0.z, 0.f) + fmaxf(bf2f(a1.z) + e1.z, 0.f);
        acc.w += fmaxf(bf2f(a0.w) + e0.w, 0.f) + fmaxf(bf2f(a1.w) + e1.w, 0.f);
        p += 8;
    }
    if (p < p1) {
        int pk0 = epk[p];
        ushort4 a0 = *(const ushort4*)(h2 + (pk0 & 0x1FFFF) * 64 + c4);
        float4 e0 = *(const float4*)(es + ((pk0 >> 17) & 15) * 64 + c4);
        acc.x += fmaxf(bf2f(a0.x) + e0.x, 0.f);
        acc.y += fmaxf(bf2f(a0.y) + e0.y, 0.f);
        acc.z += fmaxf(bf2f(a0.z) + e0.z, 0.f);
        acc.w += fmaxf(bf2f(a0.w) + e0.w, 0.f);
    }
    acc.x += __shfl_down(acc.x, 32, 64);
    acc.y += __shfl_down(acc.y, 32, 64);
    acc.z += __shfl_down(acc.z, 32, 64);
    acc.w += __shfl_down(acc.w, 32, 64);
    acc.x += __shfl_down(acc.x, 16, 64);
    acc.y += __shfl_down(acc.y, 16, 64);
    acc.z += __shfl_down(acc.z, 16, 64);
    acc.w += __shfl_down(acc.w, 16, 64);
    if (grp == 0) *(float4*)(agg + n * 64 + c4) = acc;
}

// ---- MFMA fused GINE MLP ----
// z = (1+eps)*h+agg staged bf16 in LDS; hidden = relu(z@W1^T+b1) relaid via LDS;
// out = relu(hid@W2^T+b2); optional BN+gate epilogue (layer 3).
// Wave wv owns rows [blk*64 + wv*16, +16): hidden stays wave-local -> 1 barrier.
__global__ __launch_bounds__(256) void k_mlpm(const float* __restrict__ hin,
                                              const float* __restrict__ agg,
                                              const float* __restrict__ epsp,
                                              const unsigned short* __restrict__ wbf1,
                                              const float* __restrict__ b1,
                                              const unsigned short* __restrict__ wbf2,
                                              const float* __restrict__ b2,
                                              float* __restrict__ out,
                                              unsigned short* __restrict__ h2out,
                                              const float* __restrict__ bnsc,
                                              const float* __restrict__ bnsh,
                                              const float* __restrict__ gate_w,
                                              const float* __restrict__ gate_b,
                                              float* __restrict__ gate) {
    __shared__ unsigned short zb[64 * 72];   // padded stride 72 (bf16)
    __shared__ unsigned short hb[64 * 72];
    int t = threadIdx.x;
    int row0 = blockIdx.x * 64;
    float epsv = 1.f + epsp[0];
    // stage z (bf16)
    for (int idx = t; idx < 1024; idx += 256) {
        int r = idx >> 4, c4 = (idx & 15) << 2;
        int gr = row0 + r;
        float4 v = make_float4(0.f, 0.f, 0.f, 0.f);
        if (gr < N_NODES) {
            float4 a = *(const float4*)(hin + gr * 64 + c4);
            float4 b = *(const float4*)(agg + gr * 64 + c4);
            v.x = epsv * a.x + b.x; v.y = epsv * a.y + b.y;
            v.z = epsv * a.z + b.z; v.w = epsv * a.w + b.w;
        }
        ushort4 zv;
        zv.x = f2bf(v.x); zv.y = f2bf(v.y); zv.z = f2bf(v.z); zv.w = f2bf(v.w);
        *(ushort4*)(zb + r * 72 + c4) = zv;
    }
    int lane = t & 63, wv = t >> 6;
    int quad = lane >> 4, lc = lane & 15;
    int m0 = wv * 16;
    // W1 fragments: B[k][n] with n=nt*16+lc, k=kt*32+quad*8+j  (row-major W[n][k])
    bshort8 w1f[4][2];
    #pragma unroll
    for (int nt = 0; nt < 4; ++nt)
        #pragma unroll
        for (int kt = 0; kt < 2; ++kt)
            w1f[nt][kt] = *(const bshort8*)(wbf1 + (nt * 16 + lc) * 64 + kt * 32 + quad * 8);
    bshort8 w2f[4][2];
    #pragma unroll
    for (int nt = 0; nt < 4; ++nt)
        #pragma unroll
        for (int kt = 0; kt < 2; ++kt)
            w2f[nt][kt] = *(const bshort8*)(wbf2 + (nt * 16 + lc) * 64 + kt * 32 + quad * 8);
    __syncthreads();
    // GEMM1
    bshort8 a0 = *(const bshort8*)(zb + (m0 + lc) * 72 + quad * 8);
    bshort8 a1 = *(const bshort8*)(zb + (m0 + lc) * 72 + 32 + quad * 8);
    f32x4 acc1[4];
    #pragma unroll
    for (int nt = 0; nt < 4; ++nt) {
        acc1[nt] = (f32x4){0.f, 0.f, 0.f, 0.f};
        acc1[nt] = __builtin_amdgcn_mfma_f32_16x16x32_bf16(a0, w1f[nt][0], acc1[nt], 0, 0, 0);
        acc1[nt] = __builtin_amdgcn_mfma_f32_16x16x32_bf16(a1, w1f[nt][1], acc1[nt], 0, 0, 0);
    }
    // hidden = relu(+b1) -> hb (bf16, A-layout rows m0..m0+15; wave-local)
    #pragma unroll
    for (int nt = 0; nt < 4; ++nt) {
        float bb = b1[nt * 16 + lc];
        #pragma unroll
        for (int reg = 0; reg < 4; ++reg) {
            float v = fmaxf(acc1[nt][reg] + bb, 0.f);
            hb[(m0 + quad * 4 + reg) * 72 + nt * 16 + lc] = f2bf(v);
        }
    }
    // GEMM2 (wave-local hb; compiler inserts lgkmcnt wait)
    bshort8 c0 = *(const bshort8*)(hb + (m0 + lc) * 72 + quad * 8);
    bshort8 c1 = *(const bshort8*)(hb + (m0 + lc) * 72 + 32 + quad * 8);
    f32x4 acc2[4];
    #pragma unroll
    for (int nt = 0; nt < 4; ++nt) {
        acc2[nt] = (f32x4){0.f, 0.f, 0.f, 0.f};
        acc2[nt] = __builtin_amdgcn_mfma_f32_16x16x32_bf16(c0, w2f[nt][0], acc2[nt], 0, 0, 0);
        acc2[nt] = __builtin_amdgcn_mfma_f32_16x16x32_bf16(c1, w2f[nt][1], acc2[nt], 0, 0, 0);
    }
    // epilogue: C layout row = row0+m0+quad*4+reg, col = nt*16+lc
    if (gate == nullptr) {
        #pragma unroll
        for (int reg = 0; reg < 4; ++reg) {
            int gr = row0 + m0 + quad * 4 + reg;
            if (gr < N_NODES) {
                #pragma unroll
                for (int nt = 0; nt < 4; ++nt) {
                    int col = nt * 16 + lc;
                    float v = fmaxf(acc2[nt][reg] + b2[col], 0.f);
                    out[gr * 64 + col] = v;
                    h2out[gr * 64 + col] = f2bf(v);
                }
            }
        }
    } else {
        float gb = gate_b[0];
        #pragma unroll
        for (int reg = 0; reg < 4; ++reg) {
            int gr = row0 + m0 + quad * 4 + reg;
            float p = 0.f;
            #pragma unroll
            for (int nt = 0; nt < 4; ++nt) {
                int col = nt * 16 + lc;
                float v = fmaxf(acc2[nt][reg] + b2[col], 0.f) * bnsc[col] + bnsh[col];
                p += v * gate_w[col];
                if (gr < N_NODES) out[gr * 64 + col] = v;
            }
            p += __shfl_down(p, 8, 16);
            p += __shfl_down(p, 4, 16);
            p += __shfl_down(p, 2, 16);
            p += __shfl_down(p, 1, 16);
            if (lc == 0 && gr < N_NODES) gate[gr] = p + gb;
        }
    }
}

// ---- attention aggregation + readout head, one block per graph ----
__global__ __launch_bounds__(256) void k_att(const float* __restrict__ h,
                                             const float* __restrict__ gate,
                                             const int* __restrict__ gptr,
                                             const float* __restrict__ hw1,
                                             const float* __restrict__ hb1,
                                             const float* __restrict__ hw2,
                                             const float* __restrict__ hb2,
                                             float* __restrict__ out) {
    __shared__ float red[4];
    __shared__ float acc_s[4][64];
    __shared__ float gvec[64];
    __shared__ float m_s, den_s;
    int t = threadIdx.x, g = blockIdx.x;
    int n0 = gptr[g], n1 = gptr[g + 1];
    float m = -INFINITY;
    for (int n = n0 + t; n < n1; n += 256) m = fmaxf(m, gate[n]);
    #pragma unroll
    for (int off = 32; off > 0; off >>= 1) m = fmaxf(m, __shfl_down(m, off, 64));
    if ((t & 63) == 0) red[t >> 6] = m;
    __syncthreads();
    if (t == 0) m_s = fmaxf(fmaxf(red[0], red[1]), fmaxf(red[2], red[3]));
    __syncthreads();
    m = m_s;
    float s = 0.f;
    for (int n = n0 + t; n < n1; n += 256) s += expf(gate[n] - m);
    #pragma unroll
    for (int off = 32; off > 0; off >>= 1) s += __shfl_down(s, off, 64);
    if ((t & 63) == 0) red[t >> 6] = s;
    __syncthreads();
    if (t == 0) den_s = red[0] + red[1] + red[2] + red[3] + 1e-16f;
    __syncthreads();
    float invden = 1.f / den_s;
    int c = t & 63, w = t >> 6;
    float acc = 0.f;
    for (int n = n0 + w; n < n1; n += 4) {
        float a = expf(gate[n] - m);
        acc += a * h[n * 64 + c];
    }
    acc_s[w][c] = acc;
    __syncthreads();
    if (w == 0)
        gvec[c] = (acc_s[0][c] + acc_s[1][c] + acc_s[2][c] + acc_s[3][c]) * invden;
    __syncthreads();
    // head: hidden=128, threads 0..127
    float p = 0.f;
    if (t < 128) {
        float sh = hb1[t];
        const float* wr = hw1 + t * 64;
        #pragma unroll
        for (int k = 0; k < 64; ++k) sh += gvec[k] * wr[k];
        p = fmaxf(sh, 0.f) * hw2[t];
    }
    #pragma unroll
    for (int off = 32; off > 0; off >>= 1) p += __shfl_down(p, off, 64);
    if (t == 0) red[0] = p;
    if (t == 64) red[1] = p;
    __syncthreads();
    if (t == 0) out[g] = red[0] + red[1] + hb2[0];
}

extern "C" void kernel_launch(void* const* d_in, const int* in_sizes, int n_in,
                              void* d_out, int out_size, void* d_ws, size_t ws_size,
                              hipStream_t stream) {
    const int* x    = (const int*)d_in[0];
    const int* ei   = (const int*)d_in[1];
    const int* ea   = (const int*)d_in[2];
    const int* bat  = (const int*)d_in[3];
    const float* emb0 = (const float*)d_in[4];
    const float* emb1 = (const float*)d_in[5];
    const float* emb2 = (const float*)d_in[6];
    const float* emb3 = (const float*)d_in[7];
    const float* emb4 = (const float*)d_in[8];
    const float* proj_w = (const float*)d_in[9];
    const float* proj_b = (const float*)d_in[10];
    const float* bn_g  = (const float*)d_in[35];
    const float* bn_b  = (const float*)d_in[36];
    const float* bn_rm = (const float*)d_in[37];
    const float* bn_rv = (const float*)d_in[38];
    const float* gate_w = (const float*)d_in[39];
    const float* gate_b = (const float*)d_in[40];
    const float* head_w1 = (const float*)d_in[41];
    const float* head_b1 = (const float*)d_in[42];
    const float* head_w2 = (const float*)d_in[43];
    const float* head_b2 = (const float*)d_in[44];

    char* wsb = (char*)d_ws;
    size_t o = 0;
    auto alloc = [&](size_t bytes) -> void* {
        void* p = wsb + o;
        o += (bytes + 255) & ~(size_t)255;
        return p;
    };
    float* ptab   = (float*)alloc(144 * 64 * 4);
    float* elin   = (float*)alloc(3 * 16 * 64 * 4);
    float* bnsc   = (float*)alloc(64 * 4);
    float* bnsh   = (float*)alloc(64 * 4);
    int* cursor   = (int*)alloc(NBUCK * 4);
    int* bbase    = (int*)alloc((NBUCK + 1) * 4);
    int* gptr     = (int*)alloc((N_GRAPH + 1) * 4);
    int* rowptr   = (int*)alloc(((size_t)N_NODES + 1) * 4);
    int* binned   = (int*)alloc((size_t)NBUCK * BCAP * 4);
    int* epk      = (int*)alloc((size_t)N_EDGES * 4);
    float* h      = (float*)alloc((size_t)N_NODES * 64 * 4);
    unsigned short* h2 = (unsigned short*)alloc((size_t)N_NODES * 64 * 2);
    float* agg    = (float*)alloc((size_t)N_NODES * 64 * 4);
    float* gate   = (float*)alloc((size_t)N_NODES * 4);
    unsigned short* wbf = (unsigned short*)alloc(6 * 4096 * 2);

    k_pre<<<(PRE_JOBS + 255) / 256, 256, 0, stream>>>(
                                  emb0, emb1, emb2, emb3, emb4, proj_w,
                                  (const float*)d_in[11], (const float*)d_in[12], (const float*)d_in[13],
                                  (const float*)d_in[19], (const float*)d_in[20], (const float*)d_in[21],
                                  (const float*)d_in[27], (const float*)d_in[28], (const float*)d_in[29],
                                  bn_g, bn_b, bn_rm, bn_rv,
                                  (const float*)d_in[15], (const float*)d_in[17],
                                  (const float*)d_in[23], (const float*)d_in[25],
                                  (const float*)d_in[31], (const float*)d_in[33],
                                  ptab, elin, bnsc, bnsh, cursor, wbf);
    k_embed<<<(N_NODES * 64 + 255) / 256, 256, 0, stream>>>(x, ptab, proj_b, h, h2);
    k_gptr<<<(N_NODES + 255) / 256, 256, 0, stream>>>(bat, gptr);
    k_bin<<<(N_EDGES + CHUNK - 1) / CHUNK, 256, 0, stream>>>(ei, ea, cursor, binned);
    k_bscan<<<1, 512, 0, stream>>>(cursor, bbase, rowptr);
    k_fin<<<NBUCK, 256, 0, stream>>>(binned, cursor, bbase, rowptr, epk);

    for (int L = 0; L < 3; ++L) {
        const float* epsp = (const float*)d_in[14 + L * 8];
        const float* b1   = (const float*)d_in[16 + L * 8];
        const float* b2   = (const float*)d_in[18 + L * 8];
        const unsigned short* wb1 = wbf + (L * 2 + 0) * 4096;
        const unsigned short* wb2 = wbf + (L * 2 + 1) * 4096;
        k_gather<<<(N_NODES + 3) / 4, 256, 0, stream>>>(h2, elin + L * 1024, rowptr, epk, agg);
        if (L < 2) {
            k_mlpm<<<(N_NODES + 63) / 64, 256, 0, stream>>>(h, agg, epsp, wb1, b1, wb2, b2, h, h2,
                                                            nullptr, nullptr, nullptr, nullptr,
                                                            nullptr);
        } else {
            k_mlpm<<<(N_NODES + 63) / 64, 256, 0, stream>>>(h, agg, epsp, wb1, b1, wb2, b2, h, nullptr,
                                                            bnsc, bnsh, gate_w, gate_b, gate);
        }
    }

    k_att<<<N_GRAPH, 256, 0, stream>>>(h, gate, gptr, head_w1, head_b1, head_w2, head_b2,
                                       (float*)d_out);
}

// Round 8
// 439.252 us; speedup vs baseline: 3.0641x; 1.0138x over previous
//
#include <hip/hip_runtime.h>
#include <stdint.h>

#define N_NODES 100000
#define N_EDGES 1200000
#define N_GRAPH 512
#define HID 64

#define NBUCK 391      // ceil(100000/256) buckets of 256 nodes (dst >> 8)
#define BCAP  4096     // per-bucket region capacity (mean 3069, ~18 sigma margin)
#define CHUNK 4096     // edges per k_bin block

// pre jobs: ptab 9216 | elin 3072 | bn 64 | cursor NBUCK | weight-bf16 24576
#define PRE_W0  (144 * 64 + 3 * 1024 + 64 + NBUCK)
#define PRE_JOBS (PRE_W0 + 6 * 4096)

typedef __attribute__((ext_vector_type(8))) short bshort8;
typedef __attribute__((ext_vector_type(4))) float f32x4;

// bf16 helpers (RNE pack, shift unpack)
__device__ __forceinline__ unsigned short f2bf(float f) {
    unsigned u = __float_as_uint(f);
    u += 0x7FFF + ((u >> 16) & 1);
    return (unsigned short)(u >> 16);
}
__device__ __forceinline__ float bf2f(unsigned short b) {
    return __uint_as_float((unsigned)b << 16);
}

// ---- precompute: projected node-emb rows; edge-lin tables; folded BN; zero
//      cursors; bf16 copies of the 6 MLP weight matrices ----
__global__ __launch_bounds__(256) void k_pre(
    const float* emb0, const float* emb1, const float* emb2, const float* emb3, const float* emb4,
    const float* proj_w,
    const float* ee1, const float* lw1, const float* lb1,
    const float* ee2, const float* lw2, const float* lb2,
    const float* ee3, const float* lw3, const float* lb3,
    const float* bn_g, const float* bn_b, const float* bn_rm, const float* bn_rv,
    const float* w11, const float* w12, const float* w21, const float* w22,
    const float* w31, const float* w32,
    float* ptab, float* elin, float* bnsc, float* bnsh, int* cursor,
    unsigned short* wbf)
{
    int job = blockIdx.x * 256 + threadIdx.x;
    if (job < 144 * 64) {
        int row = job >> 6, c = job & 63;
        const float* emb; int lr, dim, off;
        if (row < 120)      { emb = emb0; lr = row;       dim = 64; off = 0;  }
        else if (row < 130) { emb = emb1; lr = row - 120; dim = 16; off = 64; }
        else if (row < 137) { emb = emb2; lr = row - 130; dim = 8;  off = 80; }
        else if (row < 142) { emb = emb3; lr = row - 137; dim = 8;  off = 88; }
        else                { emb = emb4; lr = row - 142; dim = 4;  off = 96; }
        float s = 0.f;
        for (int d = 0; d < dim; ++d)
            s += emb[lr * dim + d] * proj_w[c * 100 + off + d];
        ptab[row * 64 + c] = s;
    } else if (job < 144 * 64 + 3 * 1024) {
        int j = job - 144 * 64;
        int L = j >> 10; int r = (j >> 6) & 15; int c = j & 63;
        const float* ee = (L == 0) ? ee1 : (L == 1) ? ee2 : ee3;
        const float* lw = (L == 0) ? lw1 : (L == 1) ? lw2 : lw3;
        const float* lb = (L == 0) ? lb1 : (L == 1) ? lb2 : lb3;
        float s = lb[c];
        for (int d = 0; d < 8; ++d) s += ee[r * 8 + d] * lw[c * 8 + d];
        elin[j] = s;
    } else if (job < 144 * 64 + 3 * 1024 + 64) {
        int c = job - (144 * 64 + 3 * 1024);
        float sc = bn_g[c] * rsqrtf(bn_rv[c] + 1e-5f);
        bnsc[c] = sc;
        bnsh[c] = bn_b[c] - bn_rm[c] * sc;
    } else if (job < PRE_W0) {
        cursor[job - (144 * 64 + 3 * 1024 + 64)] = 0;
    } else if (job < PRE_JOBS) {
        int j2 = job - PRE_W0;
        int sel = j2 >> 12;          // 0..5 = L*2 + which
        const float* W = (sel == 0) ? w11 : (sel == 1) ? w12 : (sel == 2) ? w21
                       : (sel == 3) ? w22 : (sel == 4) ? w31 : w32;
        wbf[j2] = f2bf(W[j2 & 4095]);
    }
}

// ---- node embedding + projection; bf16 h2 only (fp32 h eliminated) ----
__global__ __launch_bounds__(256) void k_embed(const int* x, const float* ptab,
                                               const float* proj_b, unsigned short* h2) {
    int id = blockIdx.x * 256 + threadIdx.x;
    if (id >= N_NODES * HID) return;
    int n = id >> 6, c = id & 63;
    const int* xr = x + n * 5;
    int r0 = min(max(xr[0], 0), 119);
    int r1 = 120 + min(max(xr[1], 0), 9);
    int r2 = 130 + min(max(xr[2], 0), 6);
    int r3 = 137 + min(max(xr[3], 0), 4);
    int r4 = 142 + min(max(xr[4], 0), 1);
    float v = proj_b[c] + ptab[r0 * 64 + c] + ptab[r1 * 64 + c] + ptab[r2 * 64 + c]
            + ptab[r3 * 64 + c] + ptab[r4 * 64 + c];
    h2[id] = f2bf(v);
}

// ---- graph boundaries from sorted batch ----
__global__ __launch_bounds__(256) void k_gptr(const int* batch, int* gptr) {
    int n = blockIdx.x * 256 + threadIdx.x;
    if (n >= N_NODES) return;
    int b = batch[n];
    int bp = (n == 0) ? -1 : batch[n - 1];
    for (int g = bp + 1; g <= b; ++g) gptr[g] = n;
    if (n == N_NODES - 1) {
        for (int g = b + 1; g <= N_GRAPH; ++g) gptr[g] = N_NODES;
    }
}

// ---- CSR pass 1: LDS counting-sort chunks into bucket regions ----
// payload: src(17b) | hash<<17 (4b) | dst_local<<21 (8b)
__global__ __launch_bounds__(256) void k_bin(const int* __restrict__ ei,
                                             const int* __restrict__ ea,
                                             int* __restrict__ cursor,
                                             int* __restrict__ binned) {
    __shared__ int pay[CHUNK];
    __shared__ unsigned short bkid[CHUNK];
    __shared__ int hist[NBUCK], inc[NBUCK], tmp[NBUCK], gdelta[NBUCK];
    int t = threadIdx.x;
    int e0 = blockIdx.x * CHUNK;
    for (int i = t; i < NBUCK; i += 256) hist[i] = 0;
    __syncthreads();
    int mypay[16], myrb[16];
    #pragma unroll
    for (int j = 0; j < 16; ++j) {
        int e = e0 + j * 256 + t;
        myrb[j] = -1;
        if (e < N_EDGES) {
            int s = ei[e];
            int d = ei[N_EDGES + e];
            int hsh = (ea[e * 3] + 3 * ea[e * 3 + 1] + 7 * ea[e * 3 + 2]) & 15;
            int b = d >> 8;
            mypay[j] = s | (hsh << 17) | ((d & 255) << 21);
            int r = atomicAdd(&hist[b], 1);      // rank < 4096 -> 12 bits
            myrb[j] = r | (b << 12);
        }
    }
    __syncthreads();
    for (int i = t; i < NBUCK; i += 256) inc[i] = hist[i];
    __syncthreads();
    for (int off = 1; off < NBUCK; off <<= 1) {
        for (int i = t; i < NBUCK; i += 256) tmp[i] = inc[i] + ((i >= off) ? inc[i - off] : 0);
        __syncthreads();
        for (int i = t; i < NBUCK; i += 256) inc[i] = tmp[i];
        __syncthreads();
    }
    for (int i = t; i < NBUCK; i += 256) {
        int c = hist[i];
        int gp = c ? atomicAdd(&cursor[i], c) : 0;
        gdelta[i] = i * BCAP + gp - (inc[i] - c);
    }
    __syncthreads();
    #pragma unroll
    for (int j = 0; j < 16; ++j) {
        if (myrb[j] >= 0) {
            int b = myrb[j] >> 12, r = myrb[j] & 0xFFF;
            int slot = (inc[b] - hist[b]) + r;
            pay[slot] = mypay[j];
            bkid[slot] = (unsigned short)b;
        }
    }
    __syncthreads();
    int tot = inc[NBUCK - 1];
    for (int i = t; i < tot; i += 256)
        binned[gdelta[bkid[i]] + i] = pay[i];
}

// ---- CSR pass 1.5: scan bucket counts -> bucket bases ----
__global__ __launch_bounds__(512) void k_bscan(const int* cursor, int* bbase, int* rowptr) {
    __shared__ int s[512], tp[512];
    int t = threadIdx.x;
    int v = (t < NBUCK) ? cursor[t] : 0;
    s[t] = v;
    __syncthreads();
    for (int off = 1; off < 512; off <<= 1) {
        tp[t] = s[t] + ((t >= off) ? s[t - off] : 0);
        __syncthreads();
        s[t] = tp[t];
        __syncthreads();
    }
    if (t < NBUCK) bbase[t] = s[t] - v;
    if (t == 0) { bbase[NBUCK] = N_EDGES; rowptr[N_NODES] = N_EDGES; }
}

// ---- CSR pass 2: per-bucket local CSR ----
__global__ __launch_bounds__(256) void k_fin(const int* __restrict__ binned,
                                             const int* __restrict__ cursor,
                                             const int* __restrict__ bbase,
                                             int* __restrict__ rowptr,
                                             int* __restrict__ epk) {
    __shared__ int h2[256], sc[256], cur[256];
    int b = blockIdx.x, t = threadIdx.x;
    int cnt = cursor[b];
    int gb = bbase[b];
    int node0 = b << 8;
    h2[t] = 0;
    __syncthreads();
    const int* bp = binned + b * BCAP;
    for (int i = t; i < cnt; i += 256) atomicAdd(&h2[(bp[i] >> 21) & 255], 1);
    __syncthreads();
    sc[t] = h2[t];
    __syncthreads();
    for (int off = 1; off < 256; off <<= 1) {
        int v = (t >= off) ? sc[t - off] : 0;
        __syncthreads();
        sc[t] += v;
        __syncthreads();
    }
    int ex = sc[t] - h2[t];
    cur[t] = ex;
    int n = node0 + t;
    if (n < N_NODES) rowptr[n] = gb + ex;
    __syncthreads();
    for (int i = t; i < cnt; i += 256) {
        int p = bp[i];
        int pos = atomicAdd(&cur[(p >> 21) & 255], 1);
        epk[gb + pos] = p & 0x1FFFFF;          // src | hash<<17
    }
}

// ---- GINE aggregation: epk prefetched via one coalesced load + shfl distribute,
//      up to 8 independent h2 gathers in flight per group ----
__global__ __launch_bounds__(256) void k_gather(const unsigned short* __restrict__ h2,
                                                const float* __restrict__ elinL,
                                                const int* __restrict__ rowptr,
                                                const int* __restrict__ epk,
                                                float* __restrict__ agg) {
    __shared__ float es[16 * 64];
    int t = threadIdx.x;
    ((float4*)es)[t] = ((const float4*)elinL)[t];
    __syncthreads();
    int n = blockIdx.x * 4 + (t >> 6);
    if (n >= N_NODES) return;
    int lane = t & 63;
    int grp = lane >> 4;
    int c4 = (lane & 15) << 2;
    int p0 = rowptr[n], p1 = rowptr[n + 1];
    int deg = p1 - p0;
    int nb = min(deg, 64);
    // one coalesced load covers this node's first 64 edge descriptors
    int pkv = (lane < deg) ? epk[p0 + lane] : 0;
    float4 acc = make_float4(0.f, 0.f, 0.f, 0.f);
    // 8 predicated slots: covers deg <= 32 fully, all loads independent
    #pragma unroll
    for (int j = 0; j < 8; ++j) {
        int e = grp + j * 4;
        if (e < nb) {
            int pk = __shfl(pkv, e, 64);
            ushort4 a = *(const ushort4*)(h2 + (pk & 0x1FFFF) * 64 + c4);
            float4 ev = *(const float4*)(es + ((pk >> 17) & 15) * 64 + c4);
            acc.x += fmaxf(bf2f(a.x) + ev.x, 0.f);
            acc.y += fmaxf(bf2f(a.y) + ev.y, 0.f);
            acc.z += fmaxf(bf2f(a.z) + ev.z, 0.f);
            acc.w += fmaxf(bf2f(a.w) + ev.w, 0.f);
        }
    }
    // rare: deg in (32, 64]
    for (int e = grp + 32; e < nb; e += 4) {
        int pk = __shfl(pkv, e, 64);
        ushort4 a = *(const ushort4*)(h2 + (pk & 0x1FFFF) * 64 + c4);
        float4 ev = *(const float4*)(es + ((pk >> 17) & 15) * 64 + c4);
        acc.x += fmaxf(bf2f(a.x) + ev.x, 0.f);
        acc.y += fmaxf(bf2f(a.y) + ev.y, 0.f);
        acc.z += fmaxf(bf2f(a.z) + ev.z, 0.f);
        acc.w += fmaxf(bf2f(a.w) + ev.w, 0.f);
    }
    // ultra-rare: deg > 64
    for (int p = p0 + 64 + grp; p < p1; p += 4) {
        int pk = epk[p];
        ushort4 a = *(const ushort4*)(h2 + (pk & 0x1FFFF) * 64 + c4);
        float4 ev = *(const float4*)(es + ((pk >> 17) & 15) * 64 + c4);
        acc.x += fmaxf(bf2f(a.x) + ev.x, 0.f);
        acc.y += fmaxf(bf2f(a.y) + ev.y, 0.f);
        acc.z += fmaxf(bf2f(a.z) + ev.z, 0.f);
        acc.w += fmaxf(bf2f(a.w) + ev.w, 0.f);
    }
    acc.x += __shfl_down(acc.x, 32, 64);
    acc.y += __shfl_down(acc.y, 32, 64);
    acc.z += __shfl_down(acc.z, 32, 64);
    acc.w += __shfl_down(acc.w, 32, 64);
    acc.x += __shfl_down(acc.x, 16, 64);
    acc.y += __shfl_down(acc.y, 16, 64);
    acc.z += __shfl_down(acc.z, 16, 64);
    acc.w += __shfl_down(acc.w, 16, 64);
    if (grp == 0) *(float4*)(agg + n * 64 + c4) = acc;
}

// ---- MFMA fused GINE MLP (bf16 h2 in/out, fp32 agg) ----
__global__ __launch_bounds__(256) void k_mlpm(const unsigned short* __restrict__ h2in,
                                              const float* __restrict__ agg,
                                              const float* __restrict__ epsp,
                                              const unsigned short* __restrict__ wbf1,
                                              const float* __restrict__ b1,
                                              const unsigned short* __restrict__ wbf2,
                                              const float* __restrict__ b2,
                                              unsigned short* __restrict__ h2out,
                                              const float* __restrict__ bnsc,
                                              const float* __restrict__ bnsh,
                                              const float* __restrict__ gate_w,
                                              const float* __restrict__ gate_b,
                                              float* __restrict__ gate) {
    __shared__ unsigned short zb[64 * 72];   // padded stride 72 (bf16)
    __shared__ unsigned short hb[64 * 72];
    int t = threadIdx.x;
    int row0 = blockIdx.x * 64;
    float epsv = 1.f + epsp[0];
    // stage z = (1+eps)*h + agg (bf16)
    for (int idx = t; idx < 1024; idx += 256) {
        int r = idx >> 4, c4 = (idx & 15) << 2;
        int gr = row0 + r;
        ushort4 zv = {0, 0, 0, 0};
        if (gr < N_NODES) {
            ushort4 a = *(const ushort4*)(h2in + gr * 64 + c4);
            float4 b = *(const float4*)(agg + gr * 64 + c4);
            zv.x = f2bf(epsv * bf2f(a.x) + b.x);
            zv.y = f2bf(epsv * bf2f(a.y) + b.y);
            zv.z = f2bf(epsv * bf2f(a.z) + b.z);
            zv.w = f2bf(epsv * bf2f(a.w) + b.w);
        }
        *(ushort4*)(zb + r * 72 + c4) = zv;
    }
    int lane = t & 63, wv = t >> 6;
    int quad = lane >> 4, lc = lane & 15;
    int m0 = wv * 16;
    // W fragments: B[k][n] with n=nt*16+lc, k=kt*32+quad*8+j  (row-major W[n][k])
    bshort8 w1f[4][2];
    #pragma unroll
    for (int nt = 0; nt < 4; ++nt)
        #pragma unroll
        for (int kt = 0; kt < 2; ++kt)
            w1f[nt][kt] = *(const bshort8*)(wbf1 + (nt * 16 + lc) * 64 + kt * 32 + quad * 8);
    bshort8 w2f[4][2];
    #pragma unroll
    for (int nt = 0; nt < 4; ++nt)
        #pragma unroll
        for (int kt = 0; kt < 2; ++kt)
            w2f[nt][kt] = *(const bshort8*)(wbf2 + (nt * 16 + lc) * 64 + kt * 32 + quad * 8);
    __syncthreads();
    // GEMM1
    bshort8 a0 = *(const bshort8*)(zb + (m0 + lc) * 72 + quad * 8);
    bshort8 a1 = *(const bshort8*)(zb + (m0 + lc) * 72 + 32 + quad * 8);
    f32x4 acc1[4];
    #pragma unroll
    for (int nt = 0; nt < 4; ++nt) {
        acc1[nt] = (f32x4){0.f, 0.f, 0.f, 0.f};
        acc1[nt] = __builtin_amdgcn_mfma_f32_16x16x32_bf16(a0, w1f[nt][0], acc1[nt], 0, 0, 0);
        acc1[nt] = __builtin_amdgcn_mfma_f32_16x16x32_bf16(a1, w1f[nt][1], acc1[nt], 0, 0, 0);
    }
    // hidden = relu(+b1) -> hb (bf16, A-layout rows m0..m0+15; wave-local)
    #pragma unroll
    for (int nt = 0; nt < 4; ++nt) {
        float bb = b1[nt * 16 + lc];
        #pragma unroll
        for (int reg = 0; reg < 4; ++reg) {
            float v = fmaxf(acc1[nt][reg] + bb, 0.f);
            hb[(m0 + quad * 4 + reg) * 72 + nt * 16 + lc] = f2bf(v);
        }
    }
    // GEMM2 (wave-local hb)
    bshort8 c0 = *(const bshort8*)(hb + (m0 + lc) * 72 + quad * 8);
    bshort8 c1 = *(const bshort8*)(hb + (m0 + lc) * 72 + 32 + quad * 8);
    f32x4 acc2[4];
    #pragma unroll
    for (int nt = 0; nt < 4; ++nt) {
        acc2[nt] = (f32x4){0.f, 0.f, 0.f, 0.f};
        acc2[nt] = __builtin_amdgcn_mfma_f32_16x16x32_bf16(c0, w2f[nt][0], acc2[nt], 0, 0, 0);
        acc2[nt] = __builtin_amdgcn_mfma_f32_16x16x32_bf16(c1, w2f[nt][1], acc2[nt], 0, 0, 0);
    }
    // epilogue: C layout row = row0+m0+quad*4+reg, col = nt*16+lc
    if (gate == nullptr) {
        #pragma unroll
        for (int reg = 0; reg < 4; ++reg) {
            int gr = row0 + m0 + quad * 4 + reg;
            if (gr < N_NODES) {
                #pragma unroll
                for (int nt = 0; nt < 4; ++nt) {
                    int col = nt * 16 + lc;
                    float v = fmaxf(acc2[nt][reg] + b2[col], 0.f);
                    h2out[gr * 64 + col] = f2bf(v);
                }
            }
        }
    } else {
        float gb = gate_b[0];
        #pragma unroll
        for (int reg = 0; reg < 4; ++reg) {
            int gr = row0 + m0 + quad * 4 + reg;
            float p = 0.f;
            #pragma unroll
            for (int nt = 0; nt < 4; ++nt) {
                int col = nt * 16 + lc;
                float v = fmaxf(acc2[nt][reg] + b2[col], 0.f) * bnsc[col] + bnsh[col];
                p += v * gate_w[col];
                if (gr < N_NODES) h2out[gr * 64 + col] = f2bf(v);
            }
            p += __shfl_down(p, 8, 16);
            p += __shfl_down(p, 4, 16);
            p += __shfl_down(p, 2, 16);
            p += __shfl_down(p, 1, 16);
            if (lc == 0 && gr < N_NODES) gate[gr] = p + gb;
        }
    }
}

// ---- attention aggregation + readout head, one block per graph ----
__global__ __launch_bounds__(256) void k_att(const unsigned short* __restrict__ h2,
                                             const float* __restrict__ gate,
                                             const int* __restrict__ gptr,
                                             const float* __restrict__ hw1,
                                             const float* __restrict__ hb1,
                                             const float* __restrict__ hw2,
                                             const float* __restrict__ hb2,
                                             float* __restrict__ out) {
    __shared__ float red[4];
    __shared__ float acc_s[4][64];
    __shared__ float gvec[64];
    __shared__ float m_s, den_s;
    int t = threadIdx.x, g = blockIdx.x;
    int n0 = gptr[g], n1 = gptr[g + 1];
    float m = -INFINITY;
    for (int n = n0 + t; n < n1; n += 256) m = fmaxf(m, gate[n]);
    #pragma unroll
    for (int off = 32; off > 0; off >>= 1) m = fmaxf(m, __shfl_down(m, off, 64));
    if ((t & 63) == 0) red[t >> 6] = m;
    __syncthreads();
    if (t == 0) m_s = fmaxf(fmaxf(red[0], red[1]), fmaxf(red[2], red[3]));
    __syncthreads();
    m = m_s;
    float s = 0.f;
    for (int n = n0 + t; n < n1; n += 256) s += expf(gate[n] - m);
    #pragma unroll
    for (int off = 32; off > 0; off >>= 1) s += __shfl_down(s, off, 64);
    if ((t & 63) == 0) red[t >> 6] = s;
    __syncthreads();
    if (t == 0) den_s = red[0] + red[1] + red[2] + red[3] + 1e-16f;
    __syncthreads();
    float invden = 1.f / den_s;
    int c = t & 63, w = t >> 6;
    float acc = 0.f;
    for (int n = n0 + w; n < n1; n += 4) {
        float a = expf(gate[n] - m);
        acc += a * bf2f(h2[n * 64 + c]);
    }
    acc_s[w][c] = acc;
    __syncthreads();
    if (w == 0)
        gvec[c] = (acc_s[0][c] + acc_s[1][c] + acc_s[2][c] + acc_s[3][c]) * invden;
    __syncthreads();
    // head: hidden=128, threads 0..127
    float p = 0.f;
    if (t < 128) {
        float sh = hb1[t];
        const float* wr = hw1 + t * 64;
        #pragma unroll
        for (int k = 0; k < 64; ++k) sh += gvec[k] * wr[k];
        p = fmaxf(sh, 0.f) * hw2[t];
    }
    #pragma unroll
    for (int off = 32; off > 0; off >>= 1) p += __shfl_down(p, off, 64);
    if (t == 0) red[0] = p;
    if (t == 64) red[1] = p;
    __syncthreads();
    if (t == 0) out[g] = red[0] + red[1] + hb2[0];
}

extern "C" void kernel_launch(void* const* d_in, const int* in_sizes, int n_in,
                              void* d_out, int out_size, void* d_ws, size_t ws_size,
                              hipStream_t stream) {
    const int* x    = (const int*)d_in[0];
    const int* ei   = (const int*)d_in[1];
    const int* ea   = (const int*)d_in[2];
    const int* bat  = (const int*)d_in[3];
    const float* emb0 = (const float*)d_in[4];
    const float* emb1 = (const float*)d_in[5];
    const float* emb2 = (const float*)d_in[6];
    const float* emb3 = (const float*)d_in[7];
    const float* emb4 = (const float*)d_in[8];
    const float* proj_w = (const float*)d_in[9];
    const float* proj_b = (const float*)d_in[10];
    const float* bn_g  = (const float*)d_in[35];
    const float* bn_b  = (const float*)d_in[36];
    const float* bn_rm = (const float*)d_in[37];
    const float* bn_rv = (const float*)d_in[38];
    const float* gate_w = (const float*)d_in[39];
    const float* gate_b = (const float*)d_in[40];
    const float* head_w1 = (const float*)d_in[41];
    const float* head_b1 = (const float*)d_in[42];
    const float* head_w2 = (const float*)d_in[43];
    const float* head_b2 = (const float*)d_in[44];

    char* wsb = (char*)d_ws;
    size_t o = 0;
    auto alloc = [&](size_t bytes) -> void* {
        void* p = wsb + o;
        o += (bytes + 255) & ~(size_t)255;
        return p;
    };
    float* ptab   = (float*)alloc(144 * 64 * 4);
    float* elin   = (float*)alloc(3 * 16 * 64 * 4);
    float* bnsc   = (float*)alloc(64 * 4);
    float* bnsh   = (float*)alloc(64 * 4);
    int* cursor   = (int*)alloc(NBUCK * 4);
    int* bbase    = (int*)alloc((NBUCK + 1) * 4);
    int* gptr     = (int*)alloc((N_GRAPH + 1) * 4);
    int* rowptr   = (int*)alloc(((size_t)N_NODES + 1) * 4);
    int* binned   = (int*)alloc((size_t)NBUCK * BCAP * 4);
    int* epk      = (int*)alloc((size_t)N_EDGES * 4);
    unsigned short* h2 = (unsigned short*)alloc((size_t)N_NODES * 64 * 2);
    float* agg    = (float*)alloc((size_t)N_NODES * 64 * 4);
    float* gate   = (float*)alloc((size_t)N_NODES * 4);
    unsigned short* wbf = (unsigned short*)alloc(6 * 4096 * 2);

    k_pre<<<(PRE_JOBS + 255) / 256, 256, 0, stream>>>(
                                  emb0, emb1, emb2, emb3, emb4, proj_w,
                                  (const float*)d_in[11], (const float*)d_in[12], (const float*)d_in[13],
                                  (const float*)d_in[19], (const float*)d_in[20], (const float*)d_in[21],
                                  (const float*)d_in[27], (const float*)d_in[28], (const float*)d_in[29],
                                  bn_g, bn_b, bn_rm, bn_rv,
                                  (const float*)d_in[15], (const float*)d_in[17],
                                  (const float*)d_in[23], (const float*)d_in[25],
                                  (const float*)d_in[31], (const float*)d_in[33],
                                  ptab, elin, bnsc, bnsh, cursor, wbf);
    k_embed<<<(N_NODES * 64 + 255) / 256, 256, 0, stream>>>(x, ptab, proj_b, h2);
    k_gptr<<<(N_NODES + 255) / 256, 256, 0, stream>>>(bat, gptr);
    k_bin<<<(N_EDGES + CHUNK - 1) / CHUNK, 256, 0, stream>>>(ei, ea, cursor, binned);
    k_bscan<<<1, 512, 0, stream>>>(cursor, bbase, rowptr);
    k_fin<<<NBUCK, 256, 0, stream>>>(binned, cursor, bbase, rowptr, epk);

    for (int L = 0; L < 3; ++L) {
        const float* epsp = (const float*)d_in[14 + L * 8];
        const float* b1   = (const float*)d_in[16 + L * 8];
        const float* b2   = (const float*)d_in[18 + L * 8];
        const unsigned short* wb1 = wbf + (L * 2 + 0) * 4096;
        const unsigned short* wb2 = wbf + (L * 2 + 1) * 4096;
        k_gather<<<(N_NODES + 3) / 4, 256, 0, stream>>>(h2, elin + L * 1024, rowptr, epk, agg);
        if (L < 2) {
            k_mlpm<<<(N_NODES + 63) / 64, 256, 0, stream>>>(h2, agg, epsp, wb1, b1, wb2, b2, h2,
                                                            nullptr, nullptr, nullptr, nullptr,
                                                            nullptr);
        } else {
            k_mlpm<<<(N_NODES + 63) / 64, 256, 0, stream>>>(h2, agg, epsp, wb1, b1, wb2, b2, h2,
                                                            bnsc, bnsh, gate_w, gate_b, gate);
        }
    }

    k_att<<<N_GRAPH, 256, 0, stream>>>(h2, gate, gptr, head_w1, head_b1, head_w2, head_b2,
                                       (float*)d_out);
}

// Round 9
// 394.928 us; speedup vs baseline: 3.4080x; 1.1122x over previous
//
#include <hip/hip_runtime.h>
#include <stdint.h>

#define N_NODES 100000
#define N_EDGES 1200000
#define N_GRAPH 512
#define HID 64

#define NBUCK 391      // ceil(100000/256) buckets of 256 nodes (dst >> 8)
#define BCAP  4096     // per-bucket region capacity (mean 3069, ~18 sigma margin)
#define CHUNK 4096     // edges per k_bin block

// pre jobs: ptab 9216 | elin 3072 | bn 64 | cursor NBUCK | weight-bf16 24576
#define PRE_W0  (144 * 64 + 3 * 1024 + 64 + NBUCK)
#define PRE_JOBS (PRE_W0 + 6 * 4096)

typedef __attribute__((ext_vector_type(8))) short bshort8;
typedef __attribute__((ext_vector_type(4))) float f32x4;

// bf16 helpers (RNE pack, shift unpack)
__device__ __forceinline__ unsigned short f2bf(float f) {
    unsigned u = __float_as_uint(f);
    u += 0x7FFF + ((u >> 16) & 1);
    return (unsigned short)(u >> 16);
}
__device__ __forceinline__ float bf2f(unsigned short b) {
    return __uint_as_float((unsigned)b << 16);
}

// ---- precompute: projected node-emb rows; edge-lin tables; folded BN; zero
//      cursors; bf16 copies of the 6 MLP weight matrices ----
__global__ __launch_bounds__(256) void k_pre(
    const float* emb0, const float* emb1, const float* emb2, const float* emb3, const float* emb4,
    const float* proj_w,
    const float* ee1, const float* lw1, const float* lb1,
    const float* ee2, const float* lw2, const float* lb2,
    const float* ee3, const float* lw3, const float* lb3,
    const float* bn_g, const float* bn_b, const float* bn_rm, const float* bn_rv,
    const float* w11, const float* w12, const float* w21, const float* w22,
    const float* w31, const float* w32,
    float* ptab, float* elin, float* bnsc, float* bnsh, int* cursor,
    unsigned short* wbf)
{
    int job = blockIdx.x * 256 + threadIdx.x;
    if (job < 144 * 64) {
        int row = job >> 6, c = job & 63;
        const float* emb; int lr, dim, off;
        if (row < 120)      { emb = emb0; lr = row;       dim = 64; off = 0;  }
        else if (row < 130) { emb = emb1; lr = row - 120; dim = 16; off = 64; }
        else if (row < 137) { emb = emb2; lr = row - 130; dim = 8;  off = 80; }
        else if (row < 142) { emb = emb3; lr = row - 137; dim = 8;  off = 88; }
        else                { emb = emb4; lr = row - 142; dim = 4;  off = 96; }
        float s = 0.f;
        for (int d = 0; d < dim; ++d)
            s += emb[lr * dim + d] * proj_w[c * 100 + off + d];
        ptab[row * 64 + c] = s;
    } else if (job < 144 * 64 + 3 * 1024) {
        int j = job - 144 * 64;
        int L = j >> 10; int r = (j >> 6) & 15; int c = j & 63;
        const float* ee = (L == 0) ? ee1 : (L == 1) ? ee2 : ee3;
        const float* lw = (L == 0) ? lw1 : (L == 1) ? lw2 : lw3;
        const float* lb = (L == 0) ? lb1 : (L == 1) ? lb2 : lb3;
        float s = lb[c];
        for (int d = 0; d < 8; ++d) s += ee[r * 8 + d] * lw[c * 8 + d];
        elin[j] = s;
    } else if (job < 144 * 64 + 3 * 1024 + 64) {
        int c = job - (144 * 64 + 3 * 1024);
        float sc = bn_g[c] * rsqrtf(bn_rv[c] + 1e-5f);
        bnsc[c] = sc;
        bnsh[c] = bn_b[c] - bn_rm[c] * sc;
    } else if (job < PRE_W0) {
        cursor[job - (144 * 64 + 3 * 1024 + 64)] = 0;
    } else if (job < PRE_JOBS) {
        int j2 = job - PRE_W0;
        int sel = j2 >> 12;          // 0..5 = L*2 + which
        const float* W = (sel == 0) ? w11 : (sel == 1) ? w12 : (sel == 2) ? w21
                       : (sel == 3) ? w22 : (sel == 4) ? w31 : w32;
        wbf[j2] = f2bf(W[j2 & 4095]);
    }
}

// ---- node embedding + projection; bf16 h2 ----
__global__ __launch_bounds__(256) void k_embed(const int* x, const float* ptab,
                                               const float* proj_b, unsigned short* h2) {
    int id = blockIdx.x * 256 + threadIdx.x;
    if (id >= N_NODES * HID) return;
    int n = id >> 6, c = id & 63;
    const int* xr = x + n * 5;
    int r0 = min(max(xr[0], 0), 119);
    int r1 = 120 + min(max(xr[1], 0), 9);
    int r2 = 130 + min(max(xr[2], 0), 6);
    int r3 = 137 + min(max(xr[3], 0), 4);
    int r4 = 142 + min(max(xr[4], 0), 1);
    float v = proj_b[c] + ptab[r0 * 64 + c] + ptab[r1 * 64 + c] + ptab[r2 * 64 + c]
            + ptab[r3 * 64 + c] + ptab[r4 * 64 + c];
    h2[id] = f2bf(v);
}

// ---- graph boundaries from sorted batch ----
__global__ __launch_bounds__(256) void k_gptr(const int* batch, int* gptr) {
    int n = blockIdx.x * 256 + threadIdx.x;
    if (n >= N_NODES) return;
    int b = batch[n];
    int bp = (n == 0) ? -1 : batch[n - 1];
    for (int g = bp + 1; g <= b; ++g) gptr[g] = n;
    if (n == N_NODES - 1) {
        for (int g = b + 1; g <= N_GRAPH; ++g) gptr[g] = N_NODES;
    }
}

// ---- CSR pass 1: LDS counting-sort chunks into bucket regions ----
// payload: src(17b) | hash<<17 (4b) | dst_local<<21 (8b)
__global__ __launch_bounds__(256) void k_bin(const int* __restrict__ ei,
                                             const int* __restrict__ ea,
                                             int* __restrict__ cursor,
                                             int* __restrict__ binned) {
    __shared__ int pay[CHUNK];
    __shared__ unsigned short bkid[CHUNK];
    __shared__ int hist[NBUCK], inc[NBUCK], tmp[NBUCK], gdelta[NBUCK];
    int t = threadIdx.x;
    int e0 = blockIdx.x * CHUNK;
    for (int i = t; i < NBUCK; i += 256) hist[i] = 0;
    __syncthreads();
    int mypay[16], myrb[16];
    #pragma unroll
    for (int j = 0; j < 16; ++j) {
        int e = e0 + j * 256 + t;
        myrb[j] = -1;
        if (e < N_EDGES) {
            int s = ei[e];
            int d = ei[N_EDGES + e];
            int hsh = (ea[e * 3] + 3 * ea[e * 3 + 1] + 7 * ea[e * 3 + 2]) & 15;
            int b = d >> 8;
            mypay[j] = s | (hsh << 17) | ((d & 255) << 21);
            int r = atomicAdd(&hist[b], 1);      // rank < 4096 -> 12 bits
            myrb[j] = r | (b << 12);
        }
    }
    __syncthreads();
    for (int i = t; i < NBUCK; i += 256) inc[i] = hist[i];
    __syncthreads();
    for (int off = 1; off < NBUCK; off <<= 1) {
        for (int i = t; i < NBUCK; i += 256) tmp[i] = inc[i] + ((i >= off) ? inc[i - off] : 0);
        __syncthreads();
        for (int i = t; i < NBUCK; i += 256) inc[i] = tmp[i];
        __syncthreads();
    }
    for (int i = t; i < NBUCK; i += 256) {
        int c = hist[i];
        int gp = c ? atomicAdd(&cursor[i], c) : 0;
        gdelta[i] = i * BCAP + gp - (inc[i] - c);
    }
    __syncthreads();
    #pragma unroll
    for (int j = 0; j < 16; ++j) {
        if (myrb[j] >= 0) {
            int b = myrb[j] >> 12, r = myrb[j] & 0xFFF;
            int slot = (inc[b] - hist[b]) + r;
            pay[slot] = mypay[j];
            bkid[slot] = (unsigned short)b;
        }
    }
    __syncthreads();
    int tot = inc[NBUCK - 1];
    for (int i = t; i < tot; i += 256)
        binned[gdelta[bkid[i]] + i] = pay[i];
}

// ---- CSR pass 1.5: scan bucket counts -> bucket bases ----
__global__ __launch_bounds__(512) void k_bscan(const int* cursor, int* bbase, int* rowptr) {
    __shared__ int s[512], tp[512];
    int t = threadIdx.x;
    int v = (t < NBUCK) ? cursor[t] : 0;
    s[t] = v;
    __syncthreads();
    for (int off = 1; off < 512; off <<= 1) {
        tp[t] = s[t] + ((t >= off) ? s[t - off] : 0);
        __syncthreads();
        s[t] = tp[t];
        __syncthreads();
    }
    if (t < NBUCK) bbase[t] = s[t] - v;
    if (t == 0) { bbase[NBUCK] = N_EDGES; rowptr[N_NODES] = N_EDGES; }
}

// ---- CSR pass 2: per-bucket local CSR ----
__global__ __launch_bounds__(256) void k_fin(const int* __restrict__ binned,
                                             const int* __restrict__ cursor,
                                             const int* __restrict__ bbase,
                                             int* __restrict__ rowptr,
                                             int* __restrict__ epk) {
    __shared__ int h2[256], sc[256], cur[256];
    int b = blockIdx.x, t = threadIdx.x;
    int cnt = cursor[b];
    int gb = bbase[b];
    int node0 = b << 8;
    h2[t] = 0;
    __syncthreads();
    const int* bp = binned + b * BCAP;
    for (int i = t; i < cnt; i += 256) atomicAdd(&h2[(bp[i] >> 21) & 255], 1);
    __syncthreads();
    sc[t] = h2[t];
    __syncthreads();
    for (int off = 1; off < 256; off <<= 1) {
        int v = (t >= off) ? sc[t - off] : 0;
        __syncthreads();
        sc[t] += v;
        __syncthreads();
    }
    int ex = sc[t] - h2[t];
    cur[t] = ex;
    int n = node0 + t;
    if (n < N_NODES) rowptr[n] = gb + ex;
    __syncthreads();
    for (int i = t; i < cnt; i += 256) {
        int p = bp[i];
        int pos = atomicAdd(&cur[(p >> 21) & 255], 1);
        epk[gb + pos] = p & 0x1FFFFF;          // src | hash<<17
    }
}

// ---- FUSED gather + MFMA MLP ----
// Block: 256 threads / 64 nodes. Wave wv gathers its own 16 nodes (rows
// m0..m0+15 of zb, wave-local -> no barrier), then MFMA MLP as before.
// h2 in/out are DIFFERENT buffers (ping-pong) to avoid cross-block races.
__global__ __launch_bounds__(256) void k_gmlp(const unsigned short* __restrict__ h2in,
                                              const float* __restrict__ elinL,
                                              const int* __restrict__ rowptr,
                                              const int* __restrict__ epk,
                                              const float* __restrict__ epsp,
                                              const unsigned short* __restrict__ wbf1,
                                              const float* __restrict__ b1,
                                              const unsigned short* __restrict__ wbf2,
                                              const float* __restrict__ b2,
                                              unsigned short* __restrict__ h2out,
                                              const float* __restrict__ bnsc,
                                              const float* __restrict__ bnsh,
                                              const float* __restrict__ gate_w,
                                              const float* __restrict__ gate_b,
                                              float* __restrict__ gate) {
    __shared__ float es[16 * 64];
    __shared__ unsigned short zb[64 * 72];   // padded stride 72 (bf16)
    __shared__ unsigned short hb[64 * 72];
    int t = threadIdx.x;
    ((float4*)es)[t] = ((const float4*)elinL)[t];
    __syncthreads();
    int row0 = blockIdx.x * 64;
    int lane = t & 63, wv = t >> 6;
    int grp = lane >> 4, lc = lane & 15;
    int c4 = lc << 2;
    int m0 = wv * 16;
    float epsv = 1.f + epsp[0];
    // ---- gather phase: 16 nodes per wave, z -> zb rows m0..m0+15 ----
    for (int i = 0; i < 16; ++i) {
        int n = row0 + m0 + i;
        float4 acc = make_float4(0.f, 0.f, 0.f, 0.f);
        ushort4 hs = {0, 0, 0, 0};
        if (n < N_NODES) {
            int p0 = rowptr[n], p1 = rowptr[n + 1];   // wave-uniform -> scalar
            int deg = p1 - p0;
            hs = *(const ushort4*)(h2in + n * 64 + c4);
            int nb = min(deg, 64);
            int pkv = (lane < deg) ? epk[p0 + lane] : 0;
            #pragma unroll
            for (int j = 0; j < 8; ++j) {
                int e = grp + j * 4;
                if (e < nb) {
                    int pk = __shfl(pkv, e, 64);
                    ushort4 a = *(const ushort4*)(h2in + (pk & 0x1FFFF) * 64 + c4);
                    float4 ev = *(const float4*)(es + ((pk >> 17) & 15) * 64 + c4);
                    acc.x += fmaxf(bf2f(a.x) + ev.x, 0.f);
                    acc.y += fmaxf(bf2f(a.y) + ev.y, 0.f);
                    acc.z += fmaxf(bf2f(a.z) + ev.z, 0.f);
                    acc.w += fmaxf(bf2f(a.w) + ev.w, 0.f);
                }
            }
            for (int e = grp + 32; e < nb; e += 4) {       // rare deg in (32,64]
                int pk = __shfl(pkv, e, 64);
                ushort4 a = *(const ushort4*)(h2in + (pk & 0x1FFFF) * 64 + c4);
                float4 ev = *(const float4*)(es + ((pk >> 17) & 15) * 64 + c4);
                acc.x += fmaxf(bf2f(a.x) + ev.x, 0.f);
                acc.y += fmaxf(bf2f(a.y) + ev.y, 0.f);
                acc.z += fmaxf(bf2f(a.z) + ev.z, 0.f);
                acc.w += fmaxf(bf2f(a.w) + ev.w, 0.f);
            }
            for (int p = p0 + 64 + grp; p < p1; p += 4) {  // ultra-rare deg > 64
                int pk = epk[p];
                ushort4 a = *(const ushort4*)(h2in + (pk & 0x1FFFF) * 64 + c4);
                float4 ev = *(const float4*)(es + ((pk >> 17) & 15) * 64 + c4);
                acc.x += fmaxf(bf2f(a.x) + ev.x, 0.f);
                acc.y += fmaxf(bf2f(a.y) + ev.y, 0.f);
                acc.z += fmaxf(bf2f(a.z) + ev.z, 0.f);
                acc.w += fmaxf(bf2f(a.w) + ev.w, 0.f);
            }
        }
        acc.x += __shfl_down(acc.x, 32, 64);
        acc.y += __shfl_down(acc.y, 32, 64);
        acc.z += __shfl_down(acc.z, 32, 64);
        acc.w += __shfl_down(acc.w, 32, 64);
        acc.x += __shfl_down(acc.x, 16, 64);
        acc.y += __shfl_down(acc.y, 16, 64);
        acc.z += __shfl_down(acc.z, 16, 64);
        acc.w += __shfl_down(acc.w, 16, 64);
        if (grp == 0) {
            ushort4 zv;
            zv.x = f2bf(epsv * bf2f(hs.x) + acc.x);
            zv.y = f2bf(epsv * bf2f(hs.y) + acc.y);
            zv.z = f2bf(epsv * bf2f(hs.z) + acc.z);
            zv.w = f2bf(epsv * bf2f(hs.w) + acc.w);
            *(ushort4*)(zb + (m0 + i) * 72 + c4) = zv;
        }
    }
    // ---- MFMA phase (wave-local zb/hb; W frags loaded now to keep gather-phase
    //      VGPRs low) ----
    int quad = grp;
    bshort8 w1f[4][2], w2f[4][2];
    #pragma unroll
    for (int nt = 0; nt < 4; ++nt)
        #pragma unroll
        for (int kt = 0; kt < 2; ++kt) {
            w1f[nt][kt] = *(const bshort8*)(wbf1 + (nt * 16 + lc) * 64 + kt * 32 + quad * 8);
            w2f[nt][kt] = *(const bshort8*)(wbf2 + (nt * 16 + lc) * 64 + kt * 32 + quad * 8);
        }
    bshort8 a0 = *(const bshort8*)(zb + (m0 + lc) * 72 + quad * 8);
    bshort8 a1 = *(const bshort8*)(zb + (m0 + lc) * 72 + 32 + quad * 8);
    f32x4 acc1[4];
    #pragma unroll
    for (int nt = 0; nt < 4; ++nt) {
        acc1[nt] = (f32x4){0.f, 0.f, 0.f, 0.f};
        acc1[nt] = __builtin_amdgcn_mfma_f32_16x16x32_bf16(a0, w1f[nt][0], acc1[nt], 0, 0, 0);
        acc1[nt] = __builtin_amdgcn_mfma_f32_16x16x32_bf16(a1, w1f[nt][1], acc1[nt], 0, 0, 0);
    }
    #pragma unroll
    for (int nt = 0; nt < 4; ++nt) {
        float bb = b1[nt * 16 + lc];
        #pragma unroll
        for (int reg = 0; reg < 4; ++reg) {
            float v = fmaxf(acc1[nt][reg] + bb, 0.f);
            hb[(m0 + quad * 4 + reg) * 72 + nt * 16 + lc] = f2bf(v);
        }
    }
    bshort8 c0 = *(const bshort8*)(hb + (m0 + lc) * 72 + quad * 8);
    bshort8 c1 = *(const bshort8*)(hb + (m0 + lc) * 72 + 32 + quad * 8);
    f32x4 acc2[4];
    #pragma unroll
    for (int nt = 0; nt < 4; ++nt) {
        acc2[nt] = (f32x4){0.f, 0.f, 0.f, 0.f};
        acc2[nt] = __builtin_amdgcn_mfma_f32_16x16x32_bf16(c0, w2f[nt][0], acc2[nt], 0, 0, 0);
        acc2[nt] = __builtin_amdgcn_mfma_f32_16x16x32_bf16(c1, w2f[nt][1], acc2[nt], 0, 0, 0);
    }
    if (gate == nullptr) {
        #pragma unroll
        for (int reg = 0; reg < 4; ++reg) {
            int gr = row0 + m0 + quad * 4 + reg;
            if (gr < N_NODES) {
                #pragma unroll
                for (int nt = 0; nt < 4; ++nt) {
                    int col = nt * 16 + lc;
                    float v = fmaxf(acc2[nt][reg] + b2[col], 0.f);
                    h2out[gr * 64 + col] = f2bf(v);
                }
            }
        }
    } else {
        float gb = gate_b[0];
        #pragma unroll
        for (int reg = 0; reg < 4; ++reg) {
            int gr = row0 + m0 + quad * 4 + reg;
            float p = 0.f;
            #pragma unroll
            for (int nt = 0; nt < 4; ++nt) {
                int col = nt * 16 + lc;
                float v = fmaxf(acc2[nt][reg] + b2[col], 0.f) * bnsc[col] + bnsh[col];
                p += v * gate_w[col];
                if (gr < N_NODES) h2out[gr * 64 + col] = f2bf(v);
            }
            p += __shfl_down(p, 8, 16);
            p += __shfl_down(p, 4, 16);
            p += __shfl_down(p, 2, 16);
            p += __shfl_down(p, 1, 16);
            if (lc == 0 && gr < N_NODES) gate[gr] = p + gb;
        }
    }
}

// ---- attention aggregation + readout head, one block per graph ----
__global__ __launch_bounds__(256) void k_att(const unsigned short* __restrict__ h2,
                                             const float* __restrict__ gate,
                                             const int* __restrict__ gptr,
                                             const float* __restrict__ hw1,
                                             const float* __restrict__ hb1,
                                             const float* __restrict__ hw2,
                                             const float* __restrict__ hb2,
                                             float* __restrict__ out) {
    __shared__ float red[4];
    __shared__ float acc_s[4][64];
    __shared__ float gvec[64];
    __shared__ float m_s, den_s;
    int t = threadIdx.x, g = blockIdx.x;
    int n0 = gptr[g], n1 = gptr[g + 1];
    float m = -INFINITY;
    for (int n = n0 + t; n < n1; n += 256) m = fmaxf(m, gate[n]);
    #pragma unroll
    for (int off = 32; off > 0; off >>= 1) m = fmaxf(m, __shfl_down(m, off, 64));
    if ((t & 63) == 0) red[t >> 6] = m;
    __syncthreads();
    if (t == 0) m_s = fmaxf(fmaxf(red[0], red[1]), fmaxf(red[2], red[3]));
    __syncthreads();
    m = m_s;
    float s = 0.f;
    for (int n = n0 + t; n < n1; n += 256) s += expf(gate[n] - m);
    #pragma unroll
    for (int off = 32; off > 0; off >>= 1) s += __shfl_down(s, off, 64);
    if ((t & 63) == 0) red[t >> 6] = s;
    __syncthreads();
    if (t == 0) den_s = red[0] + red[1] + red[2] + red[3] + 1e-16f;
    __syncthreads();
    float invden = 1.f / den_s;
    int c = t & 63, w = t >> 6;
    float acc = 0.f;
    for (int n = n0 + w; n < n1; n += 4) {
        float a = expf(gate[n] - m);
        acc += a * bf2f(h2[n * 64 + c]);
    }
    acc_s[w][c] = acc;
    __syncthreads();
    if (w == 0)
        gvec[c] = (acc_s[0][c] + acc_s[1][c] + acc_s[2][c] + acc_s[3][c]) * invden;
    __syncthreads();
    // head: hidden=128, threads 0..127
    float p = 0.f;
    if (t < 128) {
        float sh = hb1[t];
        const float* wr = hw1 + t * 64;
        #pragma unroll
        for (int k = 0; k < 64; ++k) sh += gvec[k] * wr[k];
        p = fmaxf(sh, 0.f) * hw2[t];
    }
    #pragma unroll
    for (int off = 32; off > 0; off >>= 1) p += __shfl_down(p, off, 64);
    if (t == 0) red[0] = p;
    if (t == 64) red[1] = p;
    __syncthreads();
    if (t == 0) out[g] = red[0] + red[1] + hb2[0];
}

extern "C" void kernel_launch(void* const* d_in, const int* in_sizes, int n_in,
                              void* d_out, int out_size, void* d_ws, size_t ws_size,
                              hipStream_t stream) {
    const int* x    = (const int*)d_in[0];
    const int* ei   = (const int*)d_in[1];
    const int* ea   = (const int*)d_in[2];
    const int* bat  = (const int*)d_in[3];
    const float* emb0 = (const float*)d_in[4];
    const float* emb1 = (const float*)d_in[5];
    const float* emb2 = (const float*)d_in[6];
    const float* emb3 = (const float*)d_in[7];
    const float* emb4 = (const float*)d_in[8];
    const float* proj_w = (const float*)d_in[9];
    const float* proj_b = (const float*)d_in[10];
    const float* bn_g  = (const float*)d_in[35];
    const float* bn_b  = (const float*)d_in[36];
    const float* bn_rm = (const float*)d_in[37];
    const float* bn_rv = (const float*)d_in[38];
    const float* gate_w = (const float*)d_in[39];
    const float* gate_b = (const float*)d_in[40];
    const float* head_w1 = (const float*)d_in[41];
    const float* head_b1 = (const float*)d_in[42];
    const float* head_w2 = (const float*)d_in[43];
    const float* head_b2 = (const float*)d_in[44];

    char* wsb = (char*)d_ws;
    size_t o = 0;
    auto alloc = [&](size_t bytes) -> void* {
        void* p = wsb + o;
        o += (bytes + 255) & ~(size_t)255;
        return p;
    };
    float* ptab   = (float*)alloc(144 * 64 * 4);
    float* elin   = (float*)alloc(3 * 16 * 64 * 4);
    float* bnsc   = (float*)alloc(64 * 4);
    float* bnsh   = (float*)alloc(64 * 4);
    int* cursor   = (int*)alloc(NBUCK * 4);
    int* bbase    = (int*)alloc((NBUCK + 1) * 4);
    int* gptr     = (int*)alloc((N_GRAPH + 1) * 4);
    int* rowptr   = (int*)alloc(((size_t)N_NODES + 1) * 4);
    int* binned   = (int*)alloc((size_t)NBUCK * BCAP * 4);
    int* epk      = (int*)alloc((size_t)N_EDGES * 4);
    unsigned short* h2a = (unsigned short*)alloc((size_t)N_NODES * 64 * 2);
    unsigned short* h2b = (unsigned short*)alloc((size_t)N_NODES * 64 * 2);
    float* gate   = (float*)alloc((size_t)N_NODES * 4);
    unsigned short* wbf = (unsigned short*)alloc(6 * 4096 * 2);

    k_pre<<<(PRE_JOBS + 255) / 256, 256, 0, stream>>>(
                                  emb0, emb1, emb2, emb3, emb4, proj_w,
                                  (const float*)d_in[11], (const float*)d_in[12], (const float*)d_in[13],
                                  (const float*)d_in[19], (const float*)d_in[20], (const float*)d_in[21],
                                  (const float*)d_in[27], (const float*)d_in[28], (const float*)d_in[29],
                                  bn_g, bn_b, bn_rm, bn_rv,
                                  (const float*)d_in[15], (const float*)d_in[17],
                                  (const float*)d_in[23], (const float*)d_in[25],
                                  (const float*)d_in[31], (const float*)d_in[33],
                                  ptab, elin, bnsc, bnsh, cursor, wbf);
    k_embed<<<(N_NODES * 64 + 255) / 256, 256, 0, stream>>>(x, ptab, proj_b, h2a);
    k_gptr<<<(N_NODES + 255) / 256, 256, 0, stream>>>(bat, gptr);
    k_bin<<<(N_EDGES + CHUNK - 1) / CHUNK, 256, 0, stream>>>(ei, ea, cursor, binned);
    k_bscan<<<1, 512, 0, stream>>>(cursor, bbase, rowptr);
    k_fin<<<NBUCK, 256, 0, stream>>>(binned, cursor, bbase, rowptr, epk);

    unsigned short* hin = h2a;
    unsigned short* hout = h2b;
    for (int L = 0; L < 3; ++L) {
        const float* epsp = (const float*)d_in[14 + L * 8];
        const float* b1   = (const float*)d_in[16 + L * 8];
        const float* b2   = (const float*)d_in[18 + L * 8];
        const unsigned short* wb1 = wbf + (L * 2 + 0) * 4096;
        const unsigned short* wb2 = wbf + (L * 2 + 1) * 4096;
        if (L < 2) {
            k_gmlp<<<(N_NODES + 63) / 64, 256, 0, stream>>>(hin, elin + L * 1024, rowptr, epk,
                                                            epsp, wb1, b1, wb2, b2, hout,
                                                            nullptr, nullptr, nullptr, nullptr,
                                                            nullptr);
        } else {
            k_gmlp<<<(N_NODES + 63) / 64, 256, 0, stream>>>(hin, elin + L * 1024, rowptr, epk,
                                                            epsp, wb1, b1, wb2, b2, hout,
                                                            bnsc, bnsh, gate_w, gate_b, gate);
        }
        unsigned short* tmp = hin; hin = hout; hout = tmp;
    }

    // after 3 swaps: hin points at the final (layer-3) output buffer
    k_att<<<N_GRAPH, 256, 0, stream>>>(hin, gate, gptr, head_w1, head_b1, head_w2, head_b2,
                                       (float*)d_out);
}